// Round 1
// baseline (919.418 us; speedup 1.0000x reference)
//
#include <hip/hip_runtime.h>
#include <math.h>

// ---------------- problem constants ----------------
#define NBATCH 16
#define NPTS   1024
#define NANG   12
#define NROTS  60
#define EPSV   1e-5f

// ---------------- workspace layout (float offsets) ----------------
#define PART0_OFF 0          // 16*64*12*16  = 196608
#define PART1_OFF 196608     // 16*128*12*16 = 393216
#define XCAT_OFF  589824     // 16*192*12    = 36864
#define XLIN_OFF  626688     // 16*256*12    = 49152
#define FPART_OFF 675840     // 2*16*512*60  = 983040
#define XF_OFF    1658880    // 16*512*60    = 491520
#define XM_OFF    2150400    // 16*512       = 8192
#define HRAW_OFF  2158592    // 16*128*60    = 122880
#define HACT_OFF  2281472
#define ARAW_OFF  2404352
#define AACT_OFF  2527232
#define OACT_OFF  2650112    // 16*512       = 8192
// total 2658304 floats = ~10.2 MB

// ---------------- output layout (float offsets) ----------------
#define OUT_XOUT 0       // (16,256)   = 4096
#define OUT_ATTN 4096    // (16,60)    = 960
#define OUT_PRED 5056    // (16,60,3,3)= 8640
#define OUT_REST 13696   // (16,60,3)  = 2880

// ---------------- block-wide mean/var helper ----------------
template<int NT>
__device__ __forceinline__ void block_stats(float v, float& m, float& var, float* sbuf){
  constexpr int NW = NT / 64;
  float s = v, s2 = v * v;
  #pragma unroll
  for (int off = 32; off; off >>= 1){
    s  += __shfl_xor(s,  off, 64);
    s2 += __shfl_xor(s2, off, 64);
  }
  const int w = threadIdx.x >> 6;
  if ((threadIdx.x & 63) == 0){ sbuf[w] = s; sbuf[NW + w] = s2; }
  __syncthreads();
  float ts = 0.f, ts2 = 0.f;
  #pragma unroll
  for (int i = 0; i < NW; i++){ ts += sbuf[i]; ts2 += sbuf[NW + i]; }
  m = ts / (float)NT;
  var = ts2 / (float)NT - m * m;
}

// ---------------- pointnet GEMM + max over points ----------------
// grid (pchunk=16, ochunk=C/32, b=16), block 256 = 64 p-lanes x 4 waves (8 o each)
// writes partial max per p-chunk: part[b][o][a][pchunk]
template<int C>
__global__ __launch_bounds__(256) void pn_gemm(
    const float* __restrict__ xyz, const float* __restrict__ feats,
    const float* __restrict__ W, float* __restrict__ part){
  const int pchunk = blockIdx.x, ochunk = blockIdx.y, b = blockIdx.z;
  const int tid  = threadIdx.x;
  const int lane = tid & 63, wave = tid >> 6;
  const int p     = pchunk * 64 + lane;
  const int obase = ochunk * 32 + wave * 8;
  const int CW = C + 3;

  __shared__ float fl[4 * 768];   // [cc][p_local*12 + a]

  const float x0 = xyz[(b * 3 + 0) * NPTS + p];
  const float x1 = xyz[(b * 3 + 1) * NPTS + p];
  const float x2 = xyz[(b * 3 + 2) * NPTS + p];

  float acc[8][12];
  #pragma unroll
  for (int i = 0; i < 8; i++){
    const float* wr = W + (size_t)(obase + i) * CW;
    const float d = wr[0] * x0 + wr[1] * x1 + wr[2] * x2;   // xyz part, same for all a
    #pragma unroll
    for (int a = 0; a < 12; a++) acc[i][a] = d;
  }

  const float* fb = feats + (size_t)b * C * NPTS * NANG + (size_t)pchunk * 64 * NANG;

  for (int cbase = 0; cbase < C; cbase += 4){
    __syncthreads();
    // stage 4 channels x 64 p x 12 a = 768 float4 cooperatively
    #pragma unroll
    for (int j = 0; j < 3; j++){
      const int idx = tid + 256 * j;        // 0..767
      const int cc  = idx / 192;
      const int rem = idx % 192;
      const float4 v = *(const float4*)(fb + (size_t)(cbase + cc) * NPTS * NANG + rem * 4);
      *(float4*)(&fl[cc * 768 + rem * 4]) = v;
    }
    __syncthreads();
    #pragma unroll
    for (int cc = 0; cc < 4; cc++){
      const float4* fp4 = (const float4*)&fl[cc * 768 + lane * 12];
      const float4 v0 = fp4[0], v1 = fp4[1], v2 = fp4[2];
      const float fa[12] = {v0.x,v0.y,v0.z,v0.w, v1.x,v1.y,v1.z,v1.w, v2.x,v2.y,v2.z,v2.w};
      const int c = cbase + cc;
      #pragma unroll
      for (int i = 0; i < 8; i++){
        const float w = W[(size_t)(obase + i) * CW + 3 + c];  // wave-uniform -> s_load
        #pragma unroll
        for (int a = 0; a < 12; a++) acc[i][a] = fmaf(w, fa[a], acc[i][a]);
      }
    }
  }

  // max over the 64 p's of this wave
  #pragma unroll
  for (int i = 0; i < 8; i++){
    #pragma unroll
    for (int a = 0; a < 12; a++){
      float v = acc[i][a];
      #pragma unroll
      for (int off = 32; off; off >>= 1) v = fmaxf(v, __shfl_xor(v, off, 64));
      if (lane == 0)
        part[(((size_t)b * C + obase + i) * 12 + a) * 16 + pchunk] = v;
    }
  }
}

// ---------------- reduce chunks + bias + BN + relu -> xcat (16,192,12) ----------------
// grid 192 (channel of concat), block 192 (b*12+a)
__global__ void pn_reduce_bn(const float* __restrict__ part0, const float* __restrict__ part1,
    const float* __restrict__ b0, const float* __restrict__ g0, const float* __restrict__ bb0,
    const float* __restrict__ b1, const float* __restrict__ g1, const float* __restrict__ bb1,
    float* __restrict__ xcat){
  const int ch = blockIdx.x, t = threadIdx.x;
  const int b = t / 12, a = t % 12;
  const float* part; const float *bias, *g, *bb; int o, Cl;
  if (ch < 64){ part = part0; bias = b0; g = g0; bb = bb0; o = ch;      Cl = 64;  }
  else        { part = part1; bias = b1; g = g1; bb = bb1; o = ch - 64; Cl = 128; }
  const float* pp = part + (((size_t)b * Cl + o) * 12 + a) * 16;
  float v = pp[0];
  #pragma unroll
  for (int k = 1; k < 16; k++) v = fmaxf(v, pp[k]);
  v += bias[o];
  __shared__ float sbuf[8];
  float m, var;
  block_stats<192>(v, m, var, sbuf);
  float xn = (v - m) * rsqrtf(var + EPSV) * g[o] + bb[o];
  xcat[((size_t)b * 192 + ch) * 12 + a] = fmaxf(xn, 0.f);
}

// ---------------- lin layer + BN (no relu) -> xlin (16,256,12) ----------------
// grid 256 (o), block 192 (b*12+a)
__global__ void lin_bn(const float* __restrict__ xcat, const float* __restrict__ W,
    const float* __restrict__ bias, const float* __restrict__ g, const float* __restrict__ bb,
    float* __restrict__ xlin){
  const int o = blockIdx.x, t = threadIdx.x;
  const int b = t / 12, a = t % 12;
  const float* xr = xcat + (size_t)b * 2304 + a;
  const float* wr = W + (size_t)o * 192;
  float v = bias[o];
  for (int c = 0; c < 192; c++) v = fmaf(wr[c], xr[(size_t)c * 12], v);
  __shared__ float sbuf[8];
  float m, var;
  block_stats<192>(v, m, var, sbuf);
  xlin[((size_t)b * 256 + o) * 12 + a] = (v - m) * rsqrtf(var + EPSV) * g[o] + bb[o];
}

// ---------------- feat layer with fused trace_idx gather (K split 2) ----------------
// grid (og=16, b=16, ks=2), block 256 = lanes(r) x 4 waves (8 o each)
// part[ks][b][o][r]
__global__ __launch_bounds__(256) void feat_gemm(
    const float* __restrict__ xlin, const int* __restrict__ trace,
    const float* __restrict__ W, float* __restrict__ part){
  const int og = blockIdx.x, b = blockIdx.y, ks = blockIdx.z;
  const int tid = threadIdx.x;
  const int lane = tid & 63, wave = tid >> 6;
  const int obase = og * 32 + wave * 8;
  const int rr = lane < 60 ? lane : 0;

  __shared__ float xl[1536];   // this K-half of xlin[b]: [c_local*12 + a]
  for (int idx = tid; idx < 384; idx += 256)
    *(float4*)(&xl[idx * 4]) = *(const float4*)(xlin + (size_t)b * 3072 + ks * 1536 + idx * 4);

  int gidx[12];
  #pragma unroll
  for (int a = 0; a < 12; a++) gidx[a] = trace[a * 60 + rr];  // values in [0,12)
  __syncthreads();

  float acc[8];
  #pragma unroll
  for (int i = 0; i < 8; i++) acc[i] = 0.f;

  for (int c = 0; c < 128; c++){
    float xv[12];
    #pragma unroll
    for (int a = 0; a < 12; a++) xv[a] = xl[c * 12 + gidx[a]];
    const float* wr = W + (size_t)obase * 3072 + (size_t)ks * 1536 + (size_t)c * 12;
    #pragma unroll
    for (int i = 0; i < 8; i++){
      float t = acc[i];
      #pragma unroll
      for (int a = 0; a < 12; a++) t = fmaf(wr[(size_t)i * 3072 + a], xv[a], t);
      acc[i] = t;
    }
  }
  if (lane < 60){
    #pragma unroll
    for (int i = 0; i < 8; i++)
      part[(((size_t)ks * NBATCH + b) * 512 + obase + i) * 60 + lane] = acc[i];
  }
}

// ---------------- feat: sum K-halves + bias + BN + relu + per-b max over r ----------------
// grid 512 (o), block 960 (b*60+r)
__global__ void feat_bn(const float* __restrict__ part, const float* __restrict__ bias,
    const float* __restrict__ g, const float* __restrict__ bb,
    float* __restrict__ xf, float* __restrict__ xm){
  const int o = blockIdx.x, t = threadIdx.x;
  const int b = t / 60, r = t % 60;
  const size_t i0 = ((size_t)b * 512 + o) * 60 + r;
  const size_t i1 = (((size_t)NBATCH + b) * 512 + o) * 60 + r;
  float v = part[i0] + part[i1] + bias[o];
  __shared__ float sbuf[32];
  float m, var;
  block_stats<960>(v, m, var, sbuf);
  const float xn = fmaxf((v - m) * rsqrtf(var + EPSV) * g[o] + bb[o], 0.f);
  xf[i0] = xn;
  __shared__ float red[960];
  red[t] = xn;
  __syncthreads();
  if (r == 0){
    float mx = red[t];
    for (int k = 1; k < 60; k++) mx = fmaxf(mx, red[t + k]);
    xm[(size_t)b * 512 + o] = mx;
  }
}

// ---------------- branch GEMM (reg_W1 / att_W1): (128,512) @ xf -> raw (+bias) ----------------
// grid (og=4, b=16), block 256 = lanes(r) x 4 waves (8 o each)
__global__ __launch_bounds__(256) void brgemm(const float* __restrict__ xf,
    const float* __restrict__ W, const float* __restrict__ bias, float* __restrict__ out){
  const int og = blockIdx.x, b = blockIdx.y;
  const int lane = threadIdx.x & 63, wave = threadIdx.x >> 6;
  const int obase = og * 32 + wave * 8;
  const int rr = lane < 60 ? lane : 0;
  float acc[8];
  #pragma unroll
  for (int i = 0; i < 8; i++) acc[i] = bias[obase + i];
  const float* xb = xf + (size_t)b * 512 * 60 + rr;
  for (int c = 0; c < 512; c++){
    const float x = xb[(size_t)c * 60];
    #pragma unroll
    for (int i = 0; i < 8; i++)
      acc[i] = fmaf(W[(size_t)(obase + i) * 512 + c], x, acc[i]);
  }
  if (lane < 60){
    #pragma unroll
    for (int i = 0; i < 8; i++)
      out[((size_t)b * 128 + obase + i) * 60 + lane] = acc[i];
  }
}

// ---------------- BN + relu over (b,r) for branch activations ----------------
// grid C (o), block 960
__global__ void bn960(const float* __restrict__ raw, const float* __restrict__ g,
    const float* __restrict__ bb, float* __restrict__ outp, int C){
  const int o = blockIdx.x, t = threadIdx.x;
  const int b = t / 60, r = t % 60;
  const size_t idx = ((size_t)b * C + o) * 60 + r;
  const float v = raw[idx];
  __shared__ float sbuf[32];
  float m, var;
  block_stats<960>(v, m, var, sbuf);
  outp[idx] = fmaxf((v - m) * rsqrtf(var + EPSV) * g[o] + bb[o], 0.f);
}

// ---------------- reg head: W2 @ h + geometry -> pred_R, res_T ----------------
// grid 16 (b), block 64 (lane=r)
__global__ void reg2_geom(const float* __restrict__ h, const float* __restrict__ W2,
    const float* __restrict__ b2, const float* __restrict__ anchors, float* __restrict__ out){
  const int b = blockIdx.x, lane = threadIdx.x;
  const int r = lane < 60 ? lane : 59;
  float res[7];
  #pragma unroll
  for (int j = 0; j < 7; j++){
    float acc = b2[j];
    for (int c = 0; c < 128; c++)
      acc = fmaf(W2[j * 128 + c], h[((size_t)b * 128 + c) * 60 + r], acc);
    res[j] = acc;
  }
  if (lane >= 60) return;
  const float n = sqrtf(res[0]*res[0] + res[1]*res[1] + res[2]*res[2]);
  const float invn = 1.f / n;
  const float Nv = (1.f / (1.f + expf(-res[3])) - 0.5f) * 3.14159265358979323846f / 5.f;
  const float v0 = res[0]*invn*Nv, v1 = res[1]*invn*Nv, v2 = res[2]*invn*Nv;
  const float th = sqrtf(v0*v0 + v1*v1 + v2*v2);
  const float invt = th < 1e-8f ? 1.f : 1.f / th;
  const float k0 = v0*invt, k1 = v1*invt, k2 = v2*invt;
  const float s = sinf(th), cc = 1.f - cosf(th);
  const float K[9] = {0.f, -k2, k1,  k2, 0.f, -k0,  -k1, k0, 0.f};
  float K2[9];
  #pragma unroll
  for (int ii = 0; ii < 3; ii++)
    #pragma unroll
    for (int jj = 0; jj < 3; jj++)
      K2[ii*3+jj] = K[ii*3+0]*K[0*3+jj] + K[ii*3+1]*K[1*3+jj] + K[ii*3+2]*K[2*3+jj];
  float R[9];
  #pragma unroll
  for (int ii = 0; ii < 3; ii++)
    #pragma unroll
    for (int jj = 0; jj < 3; jj++)
      R[ii*3+jj] = (ii == jj ? 1.f : 0.f) + s * K[ii*3+jj] + cc * K2[ii*3+jj];
  const float* A = anchors + (size_t)r * 9;
  #pragma unroll
  for (int ii = 0; ii < 3; ii++)
    #pragma unroll
    for (int kk = 0; kk < 3; kk++){
      const float pv = A[ii*3+0]*R[0*3+kk] + A[ii*3+1]*R[1*3+kk] + A[ii*3+2]*R[2*3+kk];
      out[OUT_PRED + ((size_t)b * 60 + r) * 9 + ii * 3 + kk] = pv;
    }
  #pragma unroll
  for (int k = 0; k < 3; k++)
    out[OUT_REST + ((size_t)b * 60 + r) * 3 + k] = res[4 + k];
}

// ---------------- att head: W2 @ a + softmax over r ----------------
// grid 16 (b), block 64 (lane=r)
__global__ void att2_softmax(const float* __restrict__ a, const float* __restrict__ W2,
    const float* __restrict__ b2, float* __restrict__ out){
  const int b = blockIdx.x, lane = threadIdx.x;
  const int r = lane < 60 ? lane : 59;
  float acc = b2[0];
  for (int c = 0; c < 128; c++)
    acc = fmaf(W2[c], a[((size_t)b * 128 + c) * 60 + r], acc);
  const float l = lane < 60 ? acc : -INFINITY;
  float mx = l;
  #pragma unroll
  for (int off = 32; off; off >>= 1) mx = fmaxf(mx, __shfl_xor(mx, off, 64));
  const float e = lane < 60 ? expf(l - mx) : 0.f;
  float ssum = e;
  #pragma unroll
  for (int off = 32; off; off >>= 1) ssum += __shfl_xor(ssum, off, 64);
  if (lane < 60) out[OUT_ATTN + (size_t)b * 60 + lane] = e / ssum;
}

// ---------------- out head 1: xm @ W1^T + BN(axis 0) + relu ----------------
// grid 64 (8 oc each), block 128 = 16 b x 8 oc
__global__ void out_head1(const float* __restrict__ xm, const float* __restrict__ W1,
    const float* __restrict__ b1, const float* __restrict__ g, const float* __restrict__ bb,
    float* __restrict__ o_act){
  const int t = threadIdx.x;
  const int b = t & 15, j = t >> 4;
  const int oc = blockIdx.x * 8 + j;
  float acc = b1[oc];
  const float* wr = W1 + (size_t)oc * 512;
  const float* xr = xm + (size_t)b * 512;
  for (int c = 0; c < 512; c++) acc = fmaf(wr[c], xr[c], acc);
  float s = acc, s2 = acc * acc;
  #pragma unroll
  for (int off = 8; off; off >>= 1){
    s  += __shfl_xor(s,  off, 16);
    s2 += __shfl_xor(s2, off, 16);
  }
  const float m = s * (1.f / 16.f);
  const float var = s2 * (1.f / 16.f) - m * m;
  o_act[(size_t)b * 512 + oc] = fmaxf((acc - m) * rsqrtf(var + EPSV) * g[oc] + bb[oc], 0.f);
}

// ---------------- out head 2: o @ W2^T -> x_out ----------------
// grid 16 (b), block 256 (j)
__global__ void out_head2(const float* __restrict__ o_act, const float* __restrict__ W2,
    const float* __restrict__ b2, float* __restrict__ out){
  const int b = blockIdx.x, j = threadIdx.x;
  const float* wr = W2 + (size_t)j * 512;
  const float* xr = o_act + (size_t)b * 512;
  float acc = b2[j];
  for (int c = 0; c < 512; c++) acc = fmaf(wr[c], xr[c], acc);
  out[OUT_XOUT + (size_t)b * 256 + j] = acc;
}

// ---------------- launch ----------------
extern "C" void kernel_launch(void* const* d_in, const int* in_sizes, int n_in,
                              void* d_out, int out_size, void* d_ws, size_t ws_size,
                              hipStream_t stream){
  const float* xyz0    = (const float*)d_in[0];
  const float* feats0  = (const float*)d_in[1];
  const float* xyz1    = (const float*)d_in[2];
  const float* feats1  = (const float*)d_in[3];
  const int*   trace   = (const int*)  d_in[4];
  const float* anchors = (const float*)d_in[5];
  const float* pn0_W  = (const float*)d_in[6];
  const float* pn0_b  = (const float*)d_in[7];
  const float* pn0_g  = (const float*)d_in[8];
  const float* pn0_bb = (const float*)d_in[9];
  const float* pn1_W  = (const float*)d_in[10];
  const float* pn1_b  = (const float*)d_in[11];
  const float* pn1_g  = (const float*)d_in[12];
  const float* pn1_bb = (const float*)d_in[13];
  const float* lin_W  = (const float*)d_in[14];
  const float* lin_b  = (const float*)d_in[15];
  const float* lin_g  = (const float*)d_in[16];
  const float* lin_bb = (const float*)d_in[17];
  const float* feat_W  = (const float*)d_in[18];
  const float* feat_b  = (const float*)d_in[19];
  const float* feat_g  = (const float*)d_in[20];
  const float* feat_bb = (const float*)d_in[21];
  const float* att_W1 = (const float*)d_in[22];
  const float* att_b1 = (const float*)d_in[23];
  const float* att_g  = (const float*)d_in[24];
  const float* att_bb = (const float*)d_in[25];
  const float* att_W2 = (const float*)d_in[26];
  const float* att_b2 = (const float*)d_in[27];
  const float* reg_W1 = (const float*)d_in[28];
  const float* reg_b1 = (const float*)d_in[29];
  const float* reg_g  = (const float*)d_in[30];
  const float* reg_bb = (const float*)d_in[31];
  const float* reg_W2 = (const float*)d_in[32];
  const float* reg_b2 = (const float*)d_in[33];
  const float* out_W1 = (const float*)d_in[34];
  const float* out_b1 = (const float*)d_in[35];
  const float* out_g  = (const float*)d_in[36];
  const float* out_bb = (const float*)d_in[37];
  const float* out_W2 = (const float*)d_in[38];
  const float* out_b2 = (const float*)d_in[39];

  float* ws  = (float*)d_ws;
  float* out = (float*)d_out;

  // pointnets (partial max per p-chunk)
  pn_gemm<64> <<<dim3(16, 2, 16), 256, 0, stream>>>(xyz0, feats0, pn0_W, ws + PART0_OFF);
  pn_gemm<128><<<dim3(16, 4, 16), 256, 0, stream>>>(xyz1, feats1, pn1_W, ws + PART1_OFF);

  // reduce + bias + BN + relu -> concat (16,192,12)
  pn_reduce_bn<<<192, 192, 0, stream>>>(ws + PART0_OFF, ws + PART1_OFF,
      pn0_b, pn0_g, pn0_bb, pn1_b, pn1_g, pn1_bb, ws + XCAT_OFF);

  // lin + BN (no relu) -> (16,256,12)
  lin_bn<<<256, 192, 0, stream>>>(ws + XCAT_OFF, lin_W, lin_b, lin_g, lin_bb, ws + XLIN_OFF);

  // feat (gather fused), K split 2
  feat_gemm<<<dim3(16, 16, 2), 256, 0, stream>>>(ws + XLIN_OFF, trace, feat_W, ws + FPART_OFF);
  feat_bn<<<512, 960, 0, stream>>>(ws + FPART_OFF, feat_b, feat_g, feat_bb,
                                   ws + XF_OFF, ws + XM_OFF);

  // reg / att branches
  brgemm<<<dim3(4, 16), 256, 0, stream>>>(ws + XF_OFF, reg_W1, reg_b1, ws + HRAW_OFF);
  bn960<<<128, 960, 0, stream>>>(ws + HRAW_OFF, reg_g, reg_bb, ws + HACT_OFF, 128);
  brgemm<<<dim3(4, 16), 256, 0, stream>>>(ws + XF_OFF, att_W1, att_b1, ws + ARAW_OFF);
  bn960<<<128, 960, 0, stream>>>(ws + ARAW_OFF, att_g, att_bb, ws + AACT_OFF, 128);

  // heads
  reg2_geom<<<16, 64, 0, stream>>>(ws + HACT_OFF, reg_W2, reg_b2, anchors, out);
  att2_softmax<<<16, 64, 0, stream>>>(ws + AACT_OFF, att_W2, att_b2, out);
  out_head1<<<64, 128, 0, stream>>>(ws + XM_OFF, out_W1, out_b1, out_g, out_bb, ws + OACT_OFF);
  out_head2<<<16, 256, 0, stream>>>(ws + OACT_OFF, out_W2, out_b2, out);
}

// Round 2
// 752.321 us; speedup vs baseline: 1.2221x; 1.2221x over previous
//
#include <hip/hip_runtime.h>
#include <math.h>

// ---------------- problem constants ----------------
#define NBATCH 16
#define NPTS   1024
#define NANG   12
#define NROTS  60
#define EPSV   1e-5f

// ---------------- workspace layout (float offsets) ----------------
// (regions aliased by lifetime; max extent ~9.8 MB)
#define WB0_OFF   0          // 64*96  bf16 = 3072 floats
#define WB1_OFF   3072       // 128*160 bf16 = 10240 floats
#define PART0_OFF 13312      // 16*64*12*64  = 786432
#define PART1_OFF 799744     // 16*128*12*64 = 1572864
#define XCAT_OFF  2372608    // 16*192*12 = 36864
#define XLIN_OFF  2409472    // 16*256*12 = 49152
#define FPART_OFF 0          // 2*16*512*60 = 983040 (aliases WB/PART0 — dead by then)
#define XF_OFF    983040     // 16*512*60 = 491520 (aliases PART1 — dead by then)
#define XM_OFF    1474560    // 16*512 = 8192
#define HRAW_OFF  1482752    // 16*128*60 = 122880
#define HACT_OFF  1605632
#define ARAW_OFF  1728512
#define AACT_OFF  1851392
#define OACT_OFF  1974272    // 16*512 = 8192
// max extent = 2458624 floats = 9.83 MB

// ---------------- output layout (float offsets) ----------------
#define OUT_XOUT 0       // (16,256)   = 4096
#define OUT_ATTN 4096    // (16,60)    = 960
#define OUT_PRED 5056    // (16,60,3,3)= 8640
#define OUT_REST 13696   // (16,60,3)  = 2880

typedef short  bf16x8 __attribute__((ext_vector_type(8)));
typedef float  f32x4  __attribute__((ext_vector_type(4)));

// fp32 -> bf16 RNE (for weights, done once in prep)
__device__ __forceinline__ unsigned short f2bf_rne(float x){
  unsigned int u = __float_as_uint(x);
  u += 0x7FFFu + ((u >> 16) & 1u);
  return (unsigned short)(u >> 16);
}

// pack 8 fp32 -> bf16x8 by truncation (one v_perm_b32 per pair)
__device__ __forceinline__ bf16x8 pack8(const float* f){
  union { unsigned int u[4]; bf16x8 v; } r;
  #pragma unroll
  for (int i = 0; i < 4; i++)
    r.u[i] = __builtin_amdgcn_perm(__float_as_uint(f[2*i+1]),
                                   __float_as_uint(f[2*i]), 0x07060302u);
  return r.v;
}

// ---------------- block-wide mean/var helper ----------------
template<int NT>
__device__ __forceinline__ void block_stats(float v, float& m, float& var, float* sbuf){
  constexpr int NW = NT / 64;
  float s = v, s2 = v * v;
  #pragma unroll
  for (int off = 32; off; off >>= 1){
    s  += __shfl_xor(s,  off, 64);
    s2 += __shfl_xor(s2, off, 64);
  }
  const int w = threadIdx.x >> 6;
  if ((threadIdx.x & 63) == 0){ sbuf[w] = s; sbuf[NW + w] = s2; }
  __syncthreads();
  float ts = 0.f, ts2 = 0.f;
  #pragma unroll
  for (int i = 0; i < NW; i++){ ts += sbuf[i]; ts2 += sbuf[NW + i]; }
  m = ts / (float)NT;
  var = ts2 / (float)NT - m * m;
}

// ---------------- prep: W (O x C+3) -> Wb (O x KPAD) bf16 ----------------
// Wb[o][k] = W[o][3+k] for k<C ; = W[o][k-C] for C<=k<C+3 ; = 0 beyond
template<int C>
__global__ void prep_wb(const float* __restrict__ W, unsigned short* __restrict__ Wb){
  constexpr int KPAD = C + 32;
  const int idx = blockIdx.x * 256 + threadIdx.x;
  if (idx >= C * KPAD) return;
  const int o = idx / KPAD, k = idx % KPAD;
  float v = 0.f;
  if (k < C)          v = W[(size_t)o * (C + 3) + 3 + k];
  else if (k < C + 3) v = W[(size_t)o * (C + 3) + (k - C)];
  Wb[idx] = f2bf_rne(v);
}

// ---------------- pointnet GEMM via bf16 MFMA + max over 16 points ----------------
// grid (nchunk=64, b=16), block 256 = 4 waves; each block: all C outputs,
// 192 n-cols (= 16 points x 12 angles). K = C (feats) + 3 (xyz) padded to C+32.
// writes partial max: part[b][o][a][nchunk]
template<int C>
__global__ __launch_bounds__(256) void pn_mfma(
    const float* __restrict__ xyz, const float* __restrict__ feats,
    const unsigned short* __restrict__ Wb, float* __restrict__ part){
  constexpr int KPAD = C + 32;
  constexpr int NK   = KPAD / 32;   // 5 (C=128) or 3 (C=64)
  constexpr int MT   = C / 16;      // m-tiles
  const int nchunk = blockIdx.x, b = blockIdx.y;
  const int tid  = threadIdx.x;
  const int lane = tid & 63, wave = tid >> 6;
  const int g = lane >> 4, l16 = lane & 15;
  const int colbase = wave * 48;
  const int nbase   = nchunk * 192;

  int nn[3], pp[3];
  #pragma unroll
  for (int t = 0; t < 3; t++){
    nn[t] = nbase + colbase + t * 16 + l16;
    pp[t] = nn[t] / 12;
  }

  f32x4 acc[MT][3];
  #pragma unroll
  for (int m = 0; m < MT; m++)
    #pragma unroll
    for (int t = 0; t < 3; t++)
      acc[m][t] = (f32x4){0.f, 0.f, 0.f, 0.f};

  const float* fB = feats + (size_t)b * C * (NPTS * NANG);

  // feats K-steps (k = 0 .. C-1)
  #pragma unroll
  for (int ks = 0; ks < NK - 1; ks++){
    const int kb = ks * 32;
    bf16x8 Bf[3];
    #pragma unroll
    for (int t = 0; t < 3; t++){
      const float* src = fB + (size_t)(kb + g * 8) * (NPTS * NANG) + nn[t];
      float f[8];
      #pragma unroll
      for (int j = 0; j < 8; j++) f[j] = src[(size_t)j * (NPTS * NANG)];
      Bf[t] = pack8(f);
    }
    #pragma unroll
    for (int m = 0; m < MT; m++){
      const bf16x8 Af = *(const bf16x8*)(Wb + (size_t)(m * 16 + l16) * KPAD + kb + g * 8);
      #pragma unroll
      for (int t = 0; t < 3; t++)
        acc[m][t] = __builtin_amdgcn_mfma_f32_16x16x32_bf16(Af, Bf[t], acc[m][t], 0, 0, 0);
    }
  }

  // xyz K-step (k = C .. C+2 non-zero, rest zero-padded)
  {
    const int kb = C;
    bf16x8 Bf[3];
    #pragma unroll
    for (int t = 0; t < 3; t++){
      float f[8];
      #pragma unroll
      for (int j = 0; j < 8; j++) f[j] = 0.f;
      if (g == 0){
        #pragma unroll
        for (int j = 0; j < 3; j++)
          f[j] = xyz[(size_t)(b * 3 + j) * NPTS + pp[t]];
      }
      Bf[t] = pack8(f);
    }
    #pragma unroll
    for (int m = 0; m < MT; m++){
      const bf16x8 Af = *(const bf16x8*)(Wb + (size_t)(m * 16 + l16) * KPAD + kb + g * 8);
      #pragma unroll
      for (int t = 0; t < 3; t++)
        acc[m][t] = __builtin_amdgcn_mfma_f32_16x16x32_bf16(Af, Bf[t], acc[m][t], 0, 0, 0);
    }
  }

  // reduce: per m-tile, stage 16 o x 192 n in LDS, max over the 16 points
  __shared__ float yb[16 * 192];
  #pragma unroll
  for (int m = 0; m < MT; m++){
    __syncthreads();
    #pragma unroll
    for (int t = 0; t < 3; t++)
      #pragma unroll
      for (int r = 0; r < 4; r++)
        yb[(g * 4 + r) * 192 + colbase + t * 16 + l16] = acc[m][t][r];
    __syncthreads();
    if (tid < 192){
      const int o_l = tid / 12, a = tid % 12;
      float mx = -3.4e38f;
      #pragma unroll
      for (int pl = 0; pl < 16; pl++)
        mx = fmaxf(mx, yb[o_l * 192 + pl * 12 + a]);
      part[(((size_t)b * C + m * 16 + o_l) * 12 + a) * 64 + nchunk] = mx;
    }
  }
}

// ---------------- reduce chunks + bias + BN + relu -> xcat (16,192,12) ----------------
// grid 192 (channel of concat), block 192 (b*12+a)
__global__ void pn_reduce_bn(const float* __restrict__ part0, const float* __restrict__ part1,
    const float* __restrict__ b0, const float* __restrict__ g0, const float* __restrict__ bb0,
    const float* __restrict__ b1, const float* __restrict__ g1, const float* __restrict__ bb1,
    float* __restrict__ xcat){
  const int ch = blockIdx.x, t = threadIdx.x;
  const int b = t / 12, a = t % 12;
  const float* part; const float *bias, *g, *bb; int o, Cl;
  if (ch < 64){ part = part0; bias = b0; g = g0; bb = bb0; o = ch;      Cl = 64;  }
  else        { part = part1; bias = b1; g = g1; bb = bb1; o = ch - 64; Cl = 128; }
  const float* pp = part + (((size_t)b * Cl + o) * 12 + a) * 64;
  float v = pp[0];
  for (int k = 1; k < 64; k++) v = fmaxf(v, pp[k]);
  v += bias[o];
  __shared__ float sbuf[8];
  float m, var;
  block_stats<192>(v, m, var, sbuf);
  float xn = (v - m) * rsqrtf(var + EPSV) * g[o] + bb[o];
  xcat[((size_t)b * 192 + ch) * 12 + a] = fmaxf(xn, 0.f);
}

// ---------------- lin layer + BN (no relu) -> xlin (16,256,12) ----------------
__global__ void lin_bn(const float* __restrict__ xcat, const float* __restrict__ W,
    const float* __restrict__ bias, const float* __restrict__ g, const float* __restrict__ bb,
    float* __restrict__ xlin){
  const int o = blockIdx.x, t = threadIdx.x;
  const int b = t / 12, a = t % 12;
  const float* xr = xcat + (size_t)b * 2304 + a;
  const float* wr = W + (size_t)o * 192;
  float v = bias[o];
  for (int c = 0; c < 192; c++) v = fmaf(wr[c], xr[(size_t)c * 12], v);
  __shared__ float sbuf[8];
  float m, var;
  block_stats<192>(v, m, var, sbuf);
  xlin[((size_t)b * 256 + o) * 12 + a] = (v - m) * rsqrtf(var + EPSV) * g[o] + bb[o];
}

// ---------------- feat layer with fused trace_idx gather (K split 2) ----------------
__global__ __launch_bounds__(256) void feat_gemm(
    const float* __restrict__ xlin, const int* __restrict__ trace,
    const float* __restrict__ W, float* __restrict__ part){
  const int og = blockIdx.x, b = blockIdx.y, ks = blockIdx.z;
  const int tid = threadIdx.x;
  const int lane = tid & 63, wave = tid >> 6;
  const int obase = og * 32 + wave * 8;
  const int rr = lane < 60 ? lane : 0;

  __shared__ float xl[1536];
  for (int idx = tid; idx < 384; idx += 256)
    *(float4*)(&xl[idx * 4]) = *(const float4*)(xlin + (size_t)b * 3072 + ks * 1536 + idx * 4);

  int gidx[12];
  #pragma unroll
  for (int a = 0; a < 12; a++) gidx[a] = trace[a * 60 + rr];
  __syncthreads();

  float acc[8];
  #pragma unroll
  for (int i = 0; i < 8; i++) acc[i] = 0.f;

  for (int c = 0; c < 128; c++){
    float xv[12];
    #pragma unroll
    for (int a = 0; a < 12; a++) xv[a] = xl[c * 12 + gidx[a]];
    const float* wr = W + (size_t)obase * 3072 + (size_t)ks * 1536 + (size_t)c * 12;
    #pragma unroll
    for (int i = 0; i < 8; i++){
      float t = acc[i];
      #pragma unroll
      for (int a = 0; a < 12; a++) t = fmaf(wr[(size_t)i * 3072 + a], xv[a], t);
      acc[i] = t;
    }
  }
  if (lane < 60){
    #pragma unroll
    for (int i = 0; i < 8; i++)
      part[(((size_t)ks * NBATCH + b) * 512 + obase + i) * 60 + lane] = acc[i];
  }
}

// ---------------- feat: sum K-halves + bias + BN + relu + per-b max over r ----------------
__global__ void feat_bn(const float* __restrict__ part, const float* __restrict__ bias,
    const float* __restrict__ g, const float* __restrict__ bb,
    float* __restrict__ xf, float* __restrict__ xm){
  const int o = blockIdx.x, t = threadIdx.x;
  const int b = t / 60, r = t % 60;
  const size_t i0 = ((size_t)b * 512 + o) * 60 + r;
  const size_t i1 = (((size_t)NBATCH + b) * 512 + o) * 60 + r;
  float v = part[i0] + part[i1] + bias[o];
  __shared__ float sbuf[32];
  float m, var;
  block_stats<960>(v, m, var, sbuf);
  const float xn = fmaxf((v - m) * rsqrtf(var + EPSV) * g[o] + bb[o], 0.f);
  xf[i0] = xn;
  __shared__ float red[960];
  red[t] = xn;
  __syncthreads();
  if (r == 0){
    float mx = red[t];
    for (int k = 1; k < 60; k++) mx = fmaxf(mx, red[t + k]);
    xm[(size_t)b * 512 + o] = mx;
  }
}

// ---------------- branch GEMM (reg_W1 / att_W1) ----------------
__global__ __launch_bounds__(256) void brgemm(const float* __restrict__ xf,
    const float* __restrict__ W, const float* __restrict__ bias, float* __restrict__ out){
  const int og = blockIdx.x, b = blockIdx.y;
  const int lane = threadIdx.x & 63, wave = threadIdx.x >> 6;
  const int obase = og * 32 + wave * 8;
  const int rr = lane < 60 ? lane : 0;
  float acc[8];
  #pragma unroll
  for (int i = 0; i < 8; i++) acc[i] = bias[obase + i];
  const float* xb = xf + (size_t)b * 512 * 60 + rr;
  for (int c = 0; c < 512; c++){
    const float x = xb[(size_t)c * 60];
    #pragma unroll
    for (int i = 0; i < 8; i++)
      acc[i] = fmaf(W[(size_t)(obase + i) * 512 + c], x, acc[i]);
  }
  if (lane < 60){
    #pragma unroll
    for (int i = 0; i < 8; i++)
      out[((size_t)b * 128 + obase + i) * 60 + lane] = acc[i];
  }
}

// ---------------- BN + relu over (b,r) ----------------
__global__ void bn960(const float* __restrict__ raw, const float* __restrict__ g,
    const float* __restrict__ bb, float* __restrict__ outp, int C){
  const int o = blockIdx.x, t = threadIdx.x;
  const int b = t / 60, r = t % 60;
  const size_t idx = ((size_t)b * C + o) * 60 + r;
  const float v = raw[idx];
  __shared__ float sbuf[32];
  float m, var;
  block_stats<960>(v, m, var, sbuf);
  outp[idx] = fmaxf((v - m) * rsqrtf(var + EPSV) * g[o] + bb[o], 0.f);
}

// ---------------- reg head ----------------
__global__ void reg2_geom(const float* __restrict__ h, const float* __restrict__ W2,
    const float* __restrict__ b2, const float* __restrict__ anchors, float* __restrict__ out){
  const int b = blockIdx.x, lane = threadIdx.x;
  const int r = lane < 60 ? lane : 59;
  float res[7];
  #pragma unroll
  for (int j = 0; j < 7; j++){
    float acc = b2[j];
    for (int c = 0; c < 128; c++)
      acc = fmaf(W2[j * 128 + c], h[((size_t)b * 128 + c) * 60 + r], acc);
    res[j] = acc;
  }
  if (lane >= 60) return;
  const float n = sqrtf(res[0]*res[0] + res[1]*res[1] + res[2]*res[2]);
  const float invn = 1.f / n;
  const float Nv = (1.f / (1.f + expf(-res[3])) - 0.5f) * 3.14159265358979323846f / 5.f;
  const float v0 = res[0]*invn*Nv, v1 = res[1]*invn*Nv, v2 = res[2]*invn*Nv;
  const float th = sqrtf(v0*v0 + v1*v1 + v2*v2);
  const float invt = th < 1e-8f ? 1.f : 1.f / th;
  const float k0 = v0*invt, k1 = v1*invt, k2 = v2*invt;
  const float s = sinf(th), cc = 1.f - cosf(th);
  const float K[9] = {0.f, -k2, k1,  k2, 0.f, -k0,  -k1, k0, 0.f};
  float K2[9];
  #pragma unroll
  for (int ii = 0; ii < 3; ii++)
    #pragma unroll
    for (int jj = 0; jj < 3; jj++)
      K2[ii*3+jj] = K[ii*3+0]*K[0*3+jj] + K[ii*3+1]*K[1*3+jj] + K[ii*3+2]*K[2*3+jj];
  float R[9];
  #pragma unroll
  for (int ii = 0; ii < 3; ii++)
    #pragma unroll
    for (int jj = 0; jj < 3; jj++)
      R[ii*3+jj] = (ii == jj ? 1.f : 0.f) + s * K[ii*3+jj] + cc * K2[ii*3+jj];
  const float* A = anchors + (size_t)r * 9;
  #pragma unroll
  for (int ii = 0; ii < 3; ii++)
    #pragma unroll
    for (int kk = 0; kk < 3; kk++){
      const float pv = A[ii*3+0]*R[0*3+kk] + A[ii*3+1]*R[1*3+kk] + A[ii*3+2]*R[2*3+kk];
      out[OUT_PRED + ((size_t)b * 60 + r) * 9 + ii * 3 + kk] = pv;
    }
  #pragma unroll
  for (int k = 0; k < 3; k++)
    out[OUT_REST + ((size_t)b * 60 + r) * 3 + k] = res[4 + k];
}

// ---------------- att head ----------------
__global__ void att2_softmax(const float* __restrict__ a, const float* __restrict__ W2,
    const float* __restrict__ b2, float* __restrict__ out){
  const int b = blockIdx.x, lane = threadIdx.x;
  const int r = lane < 60 ? lane : 59;
  float acc = b2[0];
  for (int c = 0; c < 128; c++)
    acc = fmaf(W2[c], a[((size_t)b * 128 + c) * 60 + r], acc);
  const float l = lane < 60 ? acc : -INFINITY;
  float mx = l;
  #pragma unroll
  for (int off = 32; off; off >>= 1) mx = fmaxf(mx, __shfl_xor(mx, off, 64));
  const float e = lane < 60 ? expf(l - mx) : 0.f;
  float ssum = e;
  #pragma unroll
  for (int off = 32; off; off >>= 1) ssum += __shfl_xor(ssum, off, 64);
  if (lane < 60) out[OUT_ATTN + (size_t)b * 60 + lane] = e / ssum;
}

// ---------------- out head 1 ----------------
__global__ void out_head1(const float* __restrict__ xm, const float* __restrict__ W1,
    const float* __restrict__ b1, const float* __restrict__ g, const float* __restrict__ bb,
    float* __restrict__ o_act){
  const int t = threadIdx.x;
  const int b = t & 15, j = t >> 4;
  const int oc = blockIdx.x * 8 + j;
  float acc = b1[oc];
  const float* wr = W1 + (size_t)oc * 512;
  const float* xr = xm + (size_t)b * 512;
  for (int c = 0; c < 512; c++) acc = fmaf(wr[c], xr[c], acc);
  float s = acc, s2 = acc * acc;
  #pragma unroll
  for (int off = 8; off; off >>= 1){
    s  += __shfl_xor(s,  off, 16);
    s2 += __shfl_xor(s2, off, 16);
  }
  const float m = s * (1.f / 16.f);
  const float var = s2 * (1.f / 16.f) - m * m;
  o_act[(size_t)b * 512 + oc] = fmaxf((acc - m) * rsqrtf(var + EPSV) * g[oc] + bb[oc], 0.f);
}

// ---------------- out head 2 ----------------
__global__ void out_head2(const float* __restrict__ o_act, const float* __restrict__ W2,
    const float* __restrict__ b2, float* __restrict__ out){
  const int b = blockIdx.x, j = threadIdx.x;
  const float* wr = W2 + (size_t)j * 512;
  const float* xr = o_act + (size_t)b * 512;
  float acc = b2[j];
  for (int c = 0; c < 512; c++) acc = fmaf(wr[c], xr[c], acc);
  out[OUT_XOUT + (size_t)b * 256 + j] = acc;
}

// ---------------- launch ----------------
extern "C" void kernel_launch(void* const* d_in, const int* in_sizes, int n_in,
                              void* d_out, int out_size, void* d_ws, size_t ws_size,
                              hipStream_t stream){
  const float* xyz0    = (const float*)d_in[0];
  const float* feats0  = (const float*)d_in[1];
  const float* xyz1    = (const float*)d_in[2];
  const float* feats1  = (const float*)d_in[3];
  const int*   trace   = (const int*)  d_in[4];
  const float* anchors = (const float*)d_in[5];
  const float* pn0_W  = (const float*)d_in[6];
  const float* pn0_b  = (const float*)d_in[7];
  const float* pn0_g  = (const float*)d_in[8];
  const float* pn0_bb = (const float*)d_in[9];
  const float* pn1_W  = (const float*)d_in[10];
  const float* pn1_b  = (const float*)d_in[11];
  const float* pn1_g  = (const float*)d_in[12];
  const float* pn1_bb = (const float*)d_in[13];
  const float* lin_W  = (const float*)d_in[14];
  const float* lin_b  = (const float*)d_in[15];
  const float* lin_g  = (const float*)d_in[16];
  const float* lin_bb = (const float*)d_in[17];
  const float* feat_W  = (const float*)d_in[18];
  const float* feat_b  = (const float*)d_in[19];
  const float* feat_g  = (const float*)d_in[20];
  const float* feat_bb = (const float*)d_in[21];
  const float* att_W1 = (const float*)d_in[22];
  const float* att_b1 = (const float*)d_in[23];
  const float* att_g  = (const float*)d_in[24];
  const float* att_bb = (const float*)d_in[25];
  const float* att_W2 = (const float*)d_in[26];
  const float* att_b2 = (const float*)d_in[27];
  const float* reg_W1 = (const float*)d_in[28];
  const float* reg_b1 = (const float*)d_in[29];
  const float* reg_g  = (const float*)d_in[30];
  const float* reg_bb = (const float*)d_in[31];
  const float* reg_W2 = (const float*)d_in[32];
  const float* reg_b2 = (const float*)d_in[33];
  const float* out_W1 = (const float*)d_in[34];
  const float* out_b1 = (const float*)d_in[35];
  const float* out_g  = (const float*)d_in[36];
  const float* out_bb = (const float*)d_in[37];
  const float* out_W2 = (const float*)d_in[38];
  const float* out_b2 = (const float*)d_in[39];

  float* ws  = (float*)d_ws;
  float* out = (float*)d_out;
  unsigned short* wb0 = (unsigned short*)(ws + WB0_OFF);
  unsigned short* wb1 = (unsigned short*)(ws + WB1_OFF);

  // weight prep (bf16, xyz rows folded at k=C..C+2, zero pad to C+32)
  prep_wb<64> <<<24, 256, 0, stream>>>(pn0_W, wb0);
  prep_wb<128><<<80, 256, 0, stream>>>(pn1_W, wb1);

  // pointnets via MFMA (partial max per 16-point chunk)
  pn_mfma<64> <<<dim3(64, 16), 256, 0, stream>>>(xyz0, feats0, wb0, ws + PART0_OFF);
  pn_mfma<128><<<dim3(64, 16), 256, 0, stream>>>(xyz1, feats1, wb1, ws + PART1_OFF);

  // reduce + bias + BN + relu -> concat (16,192,12)
  pn_reduce_bn<<<192, 192, 0, stream>>>(ws + PART0_OFF, ws + PART1_OFF,
      pn0_b, pn0_g, pn0_bb, pn1_b, pn1_g, pn1_bb, ws + XCAT_OFF);

  // lin + BN (no relu) -> (16,256,12)
  lin_bn<<<256, 192, 0, stream>>>(ws + XCAT_OFF, lin_W, lin_b, lin_g, lin_bb, ws + XLIN_OFF);

  // feat (gather fused), K split 2
  feat_gemm<<<dim3(16, 16, 2), 256, 0, stream>>>(ws + XLIN_OFF, trace, feat_W, ws + FPART_OFF);
  feat_bn<<<512, 960, 0, stream>>>(ws + FPART_OFF, feat_b, feat_g, feat_bb,
                                   ws + XF_OFF, ws + XM_OFF);

  // reg / att branches
  brgemm<<<dim3(4, 16), 256, 0, stream>>>(ws + XF_OFF, reg_W1, reg_b1, ws + HRAW_OFF);
  bn960<<<128, 960, 0, stream>>>(ws + HRAW_OFF, reg_g, reg_bb, ws + HACT_OFF, 128);
  brgemm<<<dim3(4, 16), 256, 0, stream>>>(ws + XF_OFF, att_W1, att_b1, ws + ARAW_OFF);
  bn960<<<128, 960, 0, stream>>>(ws + ARAW_OFF, att_g, att_bb, ws + AACT_OFF, 128);

  // heads
  reg2_geom<<<16, 64, 0, stream>>>(ws + HACT_OFF, reg_W2, reg_b2, anchors, out);
  att2_softmax<<<16, 64, 0, stream>>>(ws + AACT_OFF, att_W2, att_b2, out);
  out_head1<<<64, 128, 0, stream>>>(ws + XM_OFF, out_W1, out_b1, out_g, out_bb, ws + OACT_OFF);
  out_head2<<<16, 256, 0, stream>>>(ws + OACT_OFF, out_W2, out_b2, out);
}

// Round 3
// 685.186 us; speedup vs baseline: 1.3419x; 1.0980x over previous
//
#include <hip/hip_runtime.h>
#include <math.h>

// ---------------- problem constants ----------------
#define NBATCH 16
#define NPTS   1024
#define NANG   12
#define NROTS  60
#define EPSV   1e-5f

// ---------------- workspace layout (float offsets) ----------------
// lifetime-aliased; peak extent ~28.3 MB
#define WB0_OFF   0          // 64*96 bf16  = 3072 floats
#define WB1_OFF   3072       // 128*160 bf16 = 10240 floats
#define PART0_OFF 13312      // 16*64*12*64  = 786432
#define PART1_OFF 799744     // 16*128*12*64 = 1572864 (PART ends 2372608)
#define FEATW_OFF 13312      // 512*6144 bf16 = 1572864 floats (aliases PART; built after pn_reduce_bn)
#define XF_OFF    13312      // 16*512*60 = 491520 (aliases FEATW; written after feat_mfma)
#define XCAT_OFF  2372608    // 16*192*12 = 36864
#define XLIN_OFF  2409472    // 16*256*12 = 49152
#define XG_OFF    2458624    // 1024*6144 bf16 = 3145728 floats (ends 5604352)
#define FRAW_OFF  5604352    // 3*16*512*60 = 1474560 (ends 7078912)
#define HRAW_OFF  5604352    // aliases FRAW (dead after feat_bn)
#define HACT_OFF  5727232
#define ARAW_OFF  5850112
#define AACT_OFF  5972992
#define XM_OFF    2458624    // aliases XG (dead after feat_mfma)
#define OACT_OFF  2466816
// peak = 7078912 floats = 28.3 MB

// ---------------- output layout (float offsets) ----------------
#define OUT_XOUT 0       // (16,256)   = 4096
#define OUT_ATTN 4096    // (16,60)    = 960
#define OUT_PRED 5056    // (16,60,3,3)= 8640
#define OUT_REST 13696   // (16,60,3)  = 2880

typedef short  bf16x8 __attribute__((ext_vector_type(8)));
typedef float  f32x4  __attribute__((ext_vector_type(4)));

// fp32 -> bf16 RNE
__device__ __forceinline__ unsigned short f2bf_rne(float x){
  unsigned int u = __float_as_uint(x);
  u += 0x7FFFu + ((u >> 16) & 1u);
  return (unsigned short)(u >> 16);
}
__device__ __forceinline__ float bf2f(unsigned short h){
  return __uint_as_float(((unsigned int)h) << 16);
}

// pack 8 fp32 -> bf16x8 by truncation (one v_perm_b32 per pair)
__device__ __forceinline__ bf16x8 pack8(const float* f){
  union { unsigned int u[4]; bf16x8 v; } r;
  #pragma unroll
  for (int i = 0; i < 4; i++)
    r.u[i] = __builtin_amdgcn_perm(__float_as_uint(f[2*i+1]),
                                   __float_as_uint(f[2*i]), 0x07060302u);
  return r.v;
}

// ---------------- block-wide mean/var helper ----------------
template<int NT>
__device__ __forceinline__ void block_stats(float v, float& m, float& var, float* sbuf){
  constexpr int NW = NT / 64;
  float s = v, s2 = v * v;
  #pragma unroll
  for (int off = 32; off; off >>= 1){
    s  += __shfl_xor(s,  off, 64);
    s2 += __shfl_xor(s2, off, 64);
  }
  const int w = threadIdx.x >> 6;
  if ((threadIdx.x & 63) == 0){ sbuf[w] = s; sbuf[NW + w] = s2; }
  __syncthreads();
  float ts = 0.f, ts2 = 0.f;
  #pragma unroll
  for (int i = 0; i < NW; i++){ ts += sbuf[i]; ts2 += sbuf[NW + i]; }
  m = ts / (float)NT;
  var = ts2 / (float)NT - m * m;
}

// ---------------- prep: W (O x C+3) -> Wb (O x KPAD) bf16 ----------------
template<int C>
__global__ void prep_wb(const float* __restrict__ W, unsigned short* __restrict__ Wb){
  constexpr int KPAD = C + 32;
  const int idx = blockIdx.x * 256 + threadIdx.x;
  if (idx >= C * KPAD) return;
  const int o = idx / KPAD, k = idx % KPAD;
  float v = 0.f;
  if (k < C)          v = W[(size_t)o * (C + 3) + 3 + k];
  else if (k < C + 3) v = W[(size_t)o * (C + 3) + (k - C)];
  Wb[idx] = f2bf_rne(v);
}

// ---------------- pointnet GEMM via bf16 MFMA + max over 16 points ----------------
template<int C>
__global__ __launch_bounds__(256) void pn_mfma(
    const float* __restrict__ xyz, const float* __restrict__ feats,
    const unsigned short* __restrict__ Wb, float* __restrict__ part){
  constexpr int KPAD = C + 32;
  constexpr int NK   = KPAD / 32;
  constexpr int MT   = C / 16;
  const int nchunk = blockIdx.x, b = blockIdx.y;
  const int tid  = threadIdx.x;
  const int lane = tid & 63, wave = tid >> 6;
  const int g = lane >> 4, l16 = lane & 15;
  const int colbase = wave * 48;
  const int nbase   = nchunk * 192;

  int nn[3], pp[3];
  #pragma unroll
  for (int t = 0; t < 3; t++){
    nn[t] = nbase + colbase + t * 16 + l16;
    pp[t] = nn[t] / 12;
  }

  f32x4 acc[MT][3];
  #pragma unroll
  for (int m = 0; m < MT; m++)
    #pragma unroll
    for (int t = 0; t < 3; t++)
      acc[m][t] = (f32x4){0.f, 0.f, 0.f, 0.f};

  const float* fB = feats + (size_t)b * C * (NPTS * NANG);

  #pragma unroll
  for (int ks = 0; ks < NK - 1; ks++){
    const int kb = ks * 32;
    bf16x8 Bf[3];
    #pragma unroll
    for (int t = 0; t < 3; t++){
      const float* src = fB + (size_t)(kb + g * 8) * (NPTS * NANG) + nn[t];
      float f[8];
      #pragma unroll
      for (int j = 0; j < 8; j++) f[j] = src[(size_t)j * (NPTS * NANG)];
      Bf[t] = pack8(f);
    }
    #pragma unroll
    for (int m = 0; m < MT; m++){
      const bf16x8 Af = *(const bf16x8*)(Wb + (size_t)(m * 16 + l16) * KPAD + kb + g * 8);
      #pragma unroll
      for (int t = 0; t < 3; t++)
        acc[m][t] = __builtin_amdgcn_mfma_f32_16x16x32_bf16(Af, Bf[t], acc[m][t], 0, 0, 0);
    }
  }

  { // xyz K-step
    const int kb = C;
    bf16x8 Bf[3];
    #pragma unroll
    for (int t = 0; t < 3; t++){
      float f[8];
      #pragma unroll
      for (int j = 0; j < 8; j++) f[j] = 0.f;
      if (g == 0){
        #pragma unroll
        for (int j = 0; j < 3; j++)
          f[j] = xyz[(size_t)(b * 3 + j) * NPTS + pp[t]];
      }
      Bf[t] = pack8(f);
    }
    #pragma unroll
    for (int m = 0; m < MT; m++){
      const bf16x8 Af = *(const bf16x8*)(Wb + (size_t)(m * 16 + l16) * KPAD + kb + g * 8);
      #pragma unroll
      for (int t = 0; t < 3; t++)
        acc[m][t] = __builtin_amdgcn_mfma_f32_16x16x32_bf16(Af, Bf[t], acc[m][t], 0, 0, 0);
    }
  }

  __shared__ float yb[16 * 192];
  #pragma unroll
  for (int m = 0; m < MT; m++){
    __syncthreads();
    #pragma unroll
    for (int t = 0; t < 3; t++)
      #pragma unroll
      for (int r = 0; r < 4; r++)
        yb[(g * 4 + r) * 192 + colbase + t * 16 + l16] = acc[m][t][r];
    __syncthreads();
    if (tid < 192){
      const int o_l = tid / 12, a = tid % 12;
      float mx = -3.4e38f;
      #pragma unroll
      for (int pl = 0; pl < 16; pl++)
        mx = fmaxf(mx, yb[o_l * 192 + pl * 12 + a]);
      part[(((size_t)b * C + m * 16 + o_l) * 12 + a) * 64 + nchunk] = mx;
    }
  }
}

// ---------------- reduce chunks + bias + BN + relu -> xcat (16,192,12) ----------------
__global__ void pn_reduce_bn(const float* __restrict__ part0, const float* __restrict__ part1,
    const float* __restrict__ b0, const float* __restrict__ g0, const float* __restrict__ bb0,
    const float* __restrict__ b1, const float* __restrict__ g1, const float* __restrict__ bb1,
    float* __restrict__ xcat){
  const int ch = blockIdx.x, t = threadIdx.x;
  const int b = t / 12, a = t % 12;
  const float* part; const float *bias, *g, *bb; int o, Cl;
  if (ch < 64){ part = part0; bias = b0; g = g0; bb = bb0; o = ch;      Cl = 64;  }
  else        { part = part1; bias = b1; g = g1; bb = bb1; o = ch - 64; Cl = 128; }
  const float* pp = part + (((size_t)b * Cl + o) * 12 + a) * 64;
  float v = pp[0];
  for (int k = 1; k < 64; k++) v = fmaxf(v, pp[k]);
  v += bias[o];
  __shared__ float sbuf[8];
  float m, var;
  block_stats<192>(v, m, var, sbuf);
  float xn = (v - m) * rsqrtf(var + EPSV) * g[o] + bb[o];
  xcat[((size_t)b * 192 + ch) * 12 + a] = fmaxf(xn, 0.f);
}

// ---------------- lin layer + BN (no relu) -> xlin (16,256,12) ----------------
__global__ void lin_bn(const float* __restrict__ xcat, const float* __restrict__ W,
    const float* __restrict__ bias, const float* __restrict__ g, const float* __restrict__ bb,
    float* __restrict__ xlin){
  const int o = blockIdx.x, t = threadIdx.x;
  const int b = t / 12, a = t % 12;
  const float* xr = xcat + (size_t)b * 2304 + a;
  const float* wr = W + (size_t)o * 192;
  float v = bias[o];
  for (int c = 0; c < 192; c++) v = fmaf(wr[c], xr[(size_t)c * 12], v);
  __shared__ float sbuf[8];
  float m, var;
  block_stats<192>(v, m, var, sbuf);
  xlin[((size_t)b * 256 + o) * 12 + a] = (v - m) * rsqrtf(var + EPSV) * g[o] + bb[o];
}

// ---------------- prep: feat_W fp32 (512x3072) -> [hi | lo] bf16 (512x6144) ----------------
__global__ void prep_featw(const float* __restrict__ W, unsigned short* __restrict__ Wb2){
  const int idx = blockIdx.x * 256 + threadIdx.x;   // 512*3072
  if (idx >= 512 * 3072) return;
  const int o = idx / 3072, k = idx % 3072;
  const float x = W[idx];
  const unsigned short hi = f2bf_rne(x);
  const unsigned short lo = f2bf_rne(x - bf2f(hi));
  Wb2[(size_t)o * 6144 + k] = hi;
  Wb2[(size_t)o * 6144 + 3072 + k] = lo;
}

// ---------------- prep: gathered activations Xg [n=1024][hi(3072) | lo(3072)] bf16 ----------------
// n = b*64 + r (r<60 valid, else zeros). Xg[n][c*12+a] = xlin[b][c][trace[a][r]]
__global__ void prep_xg(const float* __restrict__ xlin, const int* __restrict__ trace,
                        unsigned short* __restrict__ Xg){
  const int n = blockIdx.x;
  const int r = n & 63, b = n >> 6;
  unsigned short* row = Xg + (size_t)n * 6144;
  if (r >= 60){
    for (int i = threadIdx.x; i < 3072; i += 256){ row[i] = 0; row[3072 + i] = 0; }
    return;
  }
  __shared__ int ta[12];
  if (threadIdx.x < 12) ta[threadIdx.x] = trace[threadIdx.x * 60 + r];
  __syncthreads();
  for (int i = threadIdx.x; i < 3072; i += 256){
    const int c = i / 12, a = i % 12;
    const float x = xlin[((size_t)b * 256 + c) * 12 + ta[a]];
    const unsigned short hi = f2bf_rne(x);
    const unsigned short lo = f2bf_rne(x - bf2f(hi));
    row[i] = hi;
    row[3072 + i] = lo;
  }
}

// ---------------- feat GEMM via MFMA, hi/lo 3-segment split ----------------
// grid (mblk=16, b=16, seg=3), block 256 = 4 waves; wave: 1 n-tile x 2 m-tiles.
// seg0: Whi*Xhi, seg1: Wlo*Xhi, seg2: Whi*Xlo -> fraw[seg][b][o][r]
__global__ __launch_bounds__(256) void feat_mfma(
    const unsigned short* __restrict__ Wb2, const unsigned short* __restrict__ Xg,
    float* __restrict__ fraw){
  const int mblk = blockIdx.x, b = blockIdx.y, seg = blockIdx.z;
  const int lane = threadIdx.x & 63, wave = threadIdx.x >> 6;
  const int g = lane >> 4, l16 = lane & 15;
  const int kA = (seg == 1) ? 3072 : 0;
  const int kB = (seg == 2) ? 3072 : 0;
  const unsigned short* A0p = Wb2 + (size_t)(mblk * 32 + l16) * 6144 + kA + g * 8;
  const unsigned short* A1p = A0p + (size_t)16 * 6144;
  const unsigned short* Bp  = Xg  + (size_t)(b * 64 + wave * 16 + l16) * 6144 + kB + g * 8;
  f32x4 acc0 = {0.f,0.f,0.f,0.f}, acc1 = {0.f,0.f,0.f,0.f};
  #pragma unroll 4
  for (int kb = 0; kb < 3072; kb += 32){
    const bf16x8 a0 = *(const bf16x8*)(A0p + kb);
    const bf16x8 a1 = *(const bf16x8*)(A1p + kb);
    const bf16x8 bf = *(const bf16x8*)(Bp  + kb);
    acc0 = __builtin_amdgcn_mfma_f32_16x16x32_bf16(a0, bf, acc0, 0, 0, 0);
    acc1 = __builtin_amdgcn_mfma_f32_16x16x32_bf16(a1, bf, acc1, 0, 0, 0);
  }
  const int r = wave * 16 + l16;
  if (r < 60){
    float* base = fraw + ((size_t)seg * NBATCH + b) * (512 * 60) + r;
    #pragma unroll
    for (int q = 0; q < 4; q++){
      const int oa = mblk * 32 + g * 4 + q;
      base[(size_t)oa * 60]        = acc0[q];
      base[(size_t)(oa + 16) * 60] = acc1[q];
    }
  }
}

// ---------------- feat: sum 3 segs + bias + BN + relu + per-b max over r ----------------
__global__ void feat_bn(const float* __restrict__ fraw, const float* __restrict__ bias,
    const float* __restrict__ g, const float* __restrict__ bb,
    float* __restrict__ xf, float* __restrict__ xm){
  const int o = blockIdx.x, t = threadIdx.x;
  const int b = t / 60, r = t % 60;
  const size_t i0 = ((size_t)b * 512 + o) * 60 + r;
  const size_t SS = (size_t)NBATCH * 512 * 60;
  float v = fraw[i0] + fraw[SS + i0] + fraw[2 * SS + i0] + bias[o];
  __shared__ float sbuf[32];
  float m, var;
  block_stats<960>(v, m, var, sbuf);
  const float xn = fmaxf((v - m) * rsqrtf(var + EPSV) * g[o] + bb[o], 0.f);
  xf[i0] = xn;
  __shared__ float red[960];
  red[t] = xn;
  __syncthreads();
  if (r == 0){
    float mx = red[t];
    for (int k = 1; k < 60; k++) mx = fmaxf(mx, red[t + k]);
    xm[(size_t)b * 512 + o] = mx;
  }
}

// ---------------- branch GEMM (reg_W1 / att_W1) ----------------
__global__ __launch_bounds__(256) void brgemm(const float* __restrict__ xf,
    const float* __restrict__ W, const float* __restrict__ bias, float* __restrict__ out){
  const int og = blockIdx.x, b = blockIdx.y;
  const int lane = threadIdx.x & 63, wave = threadIdx.x >> 6;
  const int obase = og * 32 + wave * 8;
  const int rr = lane < 60 ? lane : 0;
  float acc[8];
  #pragma unroll
  for (int i = 0; i < 8; i++) acc[i] = bias[obase + i];
  const float* xb = xf + (size_t)b * 512 * 60 + rr;
  for (int c = 0; c < 512; c++){
    const float x = xb[(size_t)c * 60];
    #pragma unroll
    for (int i = 0; i < 8; i++)
      acc[i] = fmaf(W[(size_t)(obase + i) * 512 + c], x, acc[i]);
  }
  if (lane < 60){
    #pragma unroll
    for (int i = 0; i < 8; i++)
      out[((size_t)b * 128 + obase + i) * 60 + lane] = acc[i];
  }
}

// ---------------- BN + relu over (b,r) ----------------
__global__ void bn960(const float* __restrict__ raw, const float* __restrict__ g,
    const float* __restrict__ bb, float* __restrict__ outp, int C){
  const int o = blockIdx.x, t = threadIdx.x;
  const int b = t / 60, r = t % 60;
  const size_t idx = ((size_t)b * C + o) * 60 + r;
  const float v = raw[idx];
  __shared__ float sbuf[32];
  float m, var;
  block_stats<960>(v, m, var, sbuf);
  outp[idx] = fmaxf((v - m) * rsqrtf(var + EPSV) * g[o] + bb[o], 0.f);
}

// ---------------- reg head ----------------
__global__ void reg2_geom(const float* __restrict__ h, const float* __restrict__ W2,
    const float* __restrict__ b2, const float* __restrict__ anchors, float* __restrict__ out){
  const int b = blockIdx.x, lane = threadIdx.x;
  const int r = lane < 60 ? lane : 59;
  float res[7];
  #pragma unroll
  for (int j = 0; j < 7; j++){
    float acc = b2[j];
    for (int c = 0; c < 128; c++)
      acc = fmaf(W2[j * 128 + c], h[((size_t)b * 128 + c) * 60 + r], acc);
    res[j] = acc;
  }
  if (lane >= 60) return;
  const float n = sqrtf(res[0]*res[0] + res[1]*res[1] + res[2]*res[2]);
  const float invn = 1.f / n;
  const float Nv = (1.f / (1.f + expf(-res[3])) - 0.5f) * 3.14159265358979323846f / 5.f;
  const float v0 = res[0]*invn*Nv, v1 = res[1]*invn*Nv, v2 = res[2]*invn*Nv;
  const float th = sqrtf(v0*v0 + v1*v1 + v2*v2);
  const float invt = th < 1e-8f ? 1.f : 1.f / th;
  const float k0 = v0*invt, k1 = v1*invt, k2 = v2*invt;
  const float s = sinf(th), cc = 1.f - cosf(th);
  const float K[9] = {0.f, -k2, k1,  k2, 0.f, -k0,  -k1, k0, 0.f};
  float K2[9];
  #pragma unroll
  for (int ii = 0; ii < 3; ii++)
    #pragma unroll
    for (int jj = 0; jj < 3; jj++)
      K2[ii*3+jj] = K[ii*3+0]*K[0*3+jj] + K[ii*3+1]*K[1*3+jj] + K[ii*3+2]*K[2*3+jj];
  float R[9];
  #pragma unroll
  for (int ii = 0; ii < 3; ii++)
    #pragma unroll
    for (int jj = 0; jj < 3; jj++)
      R[ii*3+jj] = (ii == jj ? 1.f : 0.f) + s * K[ii*3+jj] + cc * K2[ii*3+jj];
  const float* A = anchors + (size_t)r * 9;
  #pragma unroll
  for (int ii = 0; ii < 3; ii++)
    #pragma unroll
    for (int kk = 0; kk < 3; kk++){
      const float pv = A[ii*3+0]*R[0*3+kk] + A[ii*3+1]*R[1*3+kk] + A[ii*3+2]*R[2*3+kk];
      out[OUT_PRED + ((size_t)b * 60 + r) * 9 + ii * 3 + kk] = pv;
    }
  #pragma unroll
  for (int k = 0; k < 3; k++)
    out[OUT_REST + ((size_t)b * 60 + r) * 3 + k] = res[4 + k];
}

// ---------------- att head ----------------
__global__ void att2_softmax(const float* __restrict__ a, const float* __restrict__ W2,
    const float* __restrict__ b2, float* __restrict__ out){
  const int b = blockIdx.x, lane = threadIdx.x;
  const int r = lane < 60 ? lane : 59;
  float acc = b2[0];
  for (int c = 0; c < 128; c++)
    acc = fmaf(W2[c], a[((size_t)b * 128 + c) * 60 + r], acc);
  const float l = lane < 60 ? acc : -INFINITY;
  float mx = l;
  #pragma unroll
  for (int off = 32; off; off >>= 1) mx = fmaxf(mx, __shfl_xor(mx, off, 64));
  const float e = lane < 60 ? expf(l - mx) : 0.f;
  float ssum = e;
  #pragma unroll
  for (int off = 32; off; off >>= 1) ssum += __shfl_xor(ssum, off, 64);
  if (lane < 60) out[OUT_ATTN + (size_t)b * 60 + lane] = e / ssum;
}

// ---------------- out head 1 ----------------
__global__ void out_head1(const float* __restrict__ xm, const float* __restrict__ W1,
    const float* __restrict__ b1, const float* __restrict__ g, const float* __restrict__ bb,
    float* __restrict__ o_act){
  const int t = threadIdx.x;
  const int b = t & 15, j = t >> 4;
  const int oc = blockIdx.x * 8 + j;
  float acc = b1[oc];
  const float* wr = W1 + (size_t)oc * 512;
  const float* xr = xm + (size_t)b * 512;
  for (int c = 0; c < 512; c++) acc = fmaf(wr[c], xr[c], acc);
  float s = acc, s2 = acc * acc;
  #pragma unroll
  for (int off = 8; off; off >>= 1){
    s  += __shfl_xor(s,  off, 16);
    s2 += __shfl_xor(s2, off, 16);
  }
  const float m = s * (1.f / 16.f);
  const float var = s2 * (1.f / 16.f) - m * m;
  o_act[(size_t)b * 512 + oc] = fmaxf((acc - m) * rsqrtf(var + EPSV) * g[oc] + bb[oc], 0.f);
}

// ---------------- out head 2 ----------------
__global__ void out_head2(const float* __restrict__ o_act, const float* __restrict__ W2,
    const float* __restrict__ b2, float* __restrict__ out){
  const int b = blockIdx.x, j = threadIdx.x;
  const float* wr = W2 + (size_t)j * 512;
  const float* xr = o_act + (size_t)b * 512;
  float acc = b2[j];
  for (int c = 0; c < 512; c++) acc = fmaf(wr[c], xr[c], acc);
  out[OUT_XOUT + (size_t)b * 256 + j] = acc;
}

// ---------------- launch ----------------
extern "C" void kernel_launch(void* const* d_in, const int* in_sizes, int n_in,
                              void* d_out, int out_size, void* d_ws, size_t ws_size,
                              hipStream_t stream){
  const float* xyz0    = (const float*)d_in[0];
  const float* feats0  = (const float*)d_in[1];
  const float* xyz1    = (const float*)d_in[2];
  const float* feats1  = (const float*)d_in[3];
  const int*   trace   = (const int*)  d_in[4];
  const float* anchors = (const float*)d_in[5];
  const float* pn0_W  = (const float*)d_in[6];
  const float* pn0_b  = (const float*)d_in[7];
  const float* pn0_g  = (const float*)d_in[8];
  const float* pn0_bb = (const float*)d_in[9];
  const float* pn1_W  = (const float*)d_in[10];
  const float* pn1_b  = (const float*)d_in[11];
  const float* pn1_g  = (const float*)d_in[12];
  const float* pn1_bb = (const float*)d_in[13];
  const float* lin_W  = (const float*)d_in[14];
  const float* lin_b  = (const float*)d_in[15];
  const float* lin_g  = (const float*)d_in[16];
  const float* lin_bb = (const float*)d_in[17];
  const float* feat_W  = (const float*)d_in[18];
  const float* feat_b  = (const float*)d_in[19];
  const float* feat_g  = (const float*)d_in[20];
  const float* feat_bb = (const float*)d_in[21];
  const float* att_W1 = (const float*)d_in[22];
  const float* att_b1 = (const float*)d_in[23];
  const float* att_g  = (const float*)d_in[24];
  const float* att_bb = (const float*)d_in[25];
  const float* att_W2 = (const float*)d_in[26];
  const float* att_b2 = (const float*)d_in[27];
  const float* reg_W1 = (const float*)d_in[28];
  const float* reg_b1 = (const float*)d_in[29];
  const float* reg_g  = (const float*)d_in[30];
  const float* reg_bb = (const float*)d_in[31];
  const float* reg_W2 = (const float*)d_in[32];
  const float* reg_b2 = (const float*)d_in[33];
  const float* out_W1 = (const float*)d_in[34];
  const float* out_b1 = (const float*)d_in[35];
  const float* out_g  = (const float*)d_in[36];
  const float* out_bb = (const float*)d_in[37];
  const float* out_W2 = (const float*)d_in[38];
  const float* out_b2 = (const float*)d_in[39];

  float* ws  = (float*)d_ws;
  float* out = (float*)d_out;
  unsigned short* wb0 = (unsigned short*)(ws + WB0_OFF);
  unsigned short* wb1 = (unsigned short*)(ws + WB1_OFF);
  unsigned short* fw  = (unsigned short*)(ws + FEATW_OFF);
  unsigned short* xg  = (unsigned short*)(ws + XG_OFF);

  // pointnet weight prep
  prep_wb<64> <<<24, 256, 0, stream>>>(pn0_W, wb0);
  prep_wb<128><<<80, 256, 0, stream>>>(pn1_W, wb1);

  // pointnets via MFMA
  pn_mfma<64> <<<dim3(64, 16), 256, 0, stream>>>(xyz0, feats0, wb0, ws + PART0_OFF);
  pn_mfma<128><<<dim3(64, 16), 256, 0, stream>>>(xyz1, feats1, wb1, ws + PART1_OFF);

  // reduce + BN + relu -> concat
  pn_reduce_bn<<<192, 192, 0, stream>>>(ws + PART0_OFF, ws + PART1_OFF,
      pn0_b, pn0_g, pn0_bb, pn1_b, pn1_g, pn1_bb, ws + XCAT_OFF);

  // feat weight hi/lo prep (after pn_reduce_bn: aliases PART)
  prep_featw<<<6144, 256, 0, stream>>>(feat_W, fw);

  // lin + BN
  lin_bn<<<256, 192, 0, stream>>>(ws + XCAT_OFF, lin_W, lin_b, lin_g, lin_bb, ws + XLIN_OFF);

  // gathered activations hi/lo
  prep_xg<<<1024, 256, 0, stream>>>(ws + XLIN_OFF, trace, xg);

  // feat GEMM via MFMA (3 hi/lo segments)
  feat_mfma<<<dim3(16, 16, 3), 256, 0, stream>>>(fw, xg, ws + FRAW_OFF);
  feat_bn<<<512, 960, 0, stream>>>(ws + FRAW_OFF, feat_b, feat_g, feat_bb,
                                   ws + XF_OFF, ws + XM_OFF);

  // reg / att branches
  brgemm<<<dim3(4, 16), 256, 0, stream>>>(ws + XF_OFF, reg_W1, reg_b1, ws + HRAW_OFF);
  bn960<<<128, 960, 0, stream>>>(ws + HRAW_OFF, reg_g, reg_bb, ws + HACT_OFF, 128);
  brgemm<<<dim3(4, 16), 256, 0, stream>>>(ws + XF_OFF, att_W1, att_b1, ws + ARAW_OFF);
  bn960<<<128, 960, 0, stream>>>(ws + ARAW_OFF, att_g, att_bb, ws + AACT_OFF, 128);

  // heads
  reg2_geom<<<16, 64, 0, stream>>>(ws + HACT_OFF, reg_W2, reg_b2, anchors, out);
  att2_softmax<<<16, 64, 0, stream>>>(ws + AACT_OFF, att_W2, att_b2, out);
  out_head1<<<64, 128, 0, stream>>>(ws + XM_OFF, out_W1, out_b1, out_g, out_bb, ws + OACT_OFF);
  out_head2<<<16, 256, 0, stream>>>(ws + OACT_OFF, out_W2, out_b2, out);
}

// Round 4
// 674.714 us; speedup vs baseline: 1.3627x; 1.0155x over previous
//
#include <hip/hip_runtime.h>
#include <math.h>

// ---------------- problem constants ----------------
#define NBATCH 16
#define NPTS   1024
#define NANG   12
#define NROTS  60
#define EPSV   1e-5f

// ---------------- workspace layout (float offsets) ----------------
// lifetime-aliased; peak extent ~28.3 MB (known-safe from R2/R3)
#define WB0_OFF   0          // 64*96 bf16  = 3072 floats
#define WB1_OFF   3072       // 128*160 bf16 = 10240 floats
#define PART0_OFF 13312      // 16*64*12*64  = 786432
#define PART1_OFF 799744     // 16*128*12*64 = 1572864 (PART ends 2372608)
#define FEATW_OFF 13312      // 512*6144 bf16 = 1572864 floats (aliases PART)
#define XF_OFF    13312      // 16*512*60 = 491520 (aliases FEATW after feat_mfma)
#define XCAT_OFF  2372608    // 16*192*12 = 36864
#define XLIN_OFF  2409472    // 16*256*12 = 49152
#define XG_OFF    2458624    // 1024*6144 bf16 = 3145728 floats (ends 5604352)
#define FRAW_OFF  5604352    // 3*16*512*60 = 1474560 (ends 7078912)
#define HRAW_OFF  5604352    // aliases FRAW (dead after feat_bn)
#define HACT_OFF  5727232
#define ARAW_OFF  5850112
#define AACT_OFF  5972992
#define XM_OFF    2458624    // aliases XG (dead after feat_mfma)
#define OACT_OFF  2466816
// peak = 7078912 floats = 28.3 MB

// ---------------- output layout (float offsets) ----------------
#define OUT_XOUT 0       // (16,256)   = 4096
#define OUT_ATTN 4096    // (16,60)    = 960
#define OUT_PRED 5056    // (16,60,3,3)= 8640
#define OUT_REST 13696   // (16,60,3)  = 2880

typedef short  bf16x8 __attribute__((ext_vector_type(8)));
typedef float  f32x4  __attribute__((ext_vector_type(4)));

// fp32 -> bf16 RNE
__device__ __forceinline__ unsigned short f2bf_rne(float x){
  unsigned int u = __float_as_uint(x);
  u += 0x7FFFu + ((u >> 16) & 1u);
  return (unsigned short)(u >> 16);
}
__device__ __forceinline__ float bf2f(unsigned short h){
  return __uint_as_float(((unsigned int)h) << 16);
}

// pack 8 fp32 -> bf16x8 by truncation (one v_perm_b32 per pair)
__device__ __forceinline__ bf16x8 pack8(const float* f){
  union { unsigned int u[4]; bf16x8 v; } r;
  #pragma unroll
  for (int i = 0; i < 4; i++)
    r.u[i] = __builtin_amdgcn_perm(__float_as_uint(f[2*i+1]),
                                   __float_as_uint(f[2*i]), 0x07060302u);
  return r.v;
}

// ---------------- block-wide mean/var helper ----------------
template<int NT>
__device__ __forceinline__ void block_stats(float v, float& m, float& var, float* sbuf){
  constexpr int NW = NT / 64;
  float s = v, s2 = v * v;
  #pragma unroll
  for (int off = 32; off; off >>= 1){
    s  += __shfl_xor(s,  off, 64);
    s2 += __shfl_xor(s2, off, 64);
  }
  const int w = threadIdx.x >> 6;
  if ((threadIdx.x & 63) == 0){ sbuf[w] = s; sbuf[NW + w] = s2; }
  __syncthreads();
  float ts = 0.f, ts2 = 0.f;
  #pragma unroll
  for (int i = 0; i < NW; i++){ ts += sbuf[i]; ts2 += sbuf[NW + i]; }
  m = ts / (float)NT;
  var = ts2 / (float)NT - m * m;
}

// ---------------- prep: W (O x C+3) -> Wb (O x KPAD) bf16 ----------------
template<int C>
__global__ void prep_wb(const float* __restrict__ W, unsigned short* __restrict__ Wb){
  constexpr int KPAD = C + 32;
  const int idx = blockIdx.x * 256 + threadIdx.x;
  if (idx >= C * KPAD) return;
  const int o = idx / KPAD, k = idx % KPAD;
  float v = 0.f;
  if (k < C)          v = W[(size_t)o * (C + 3) + 3 + k];
  else if (k < C + 3) v = W[(size_t)o * (C + 3) + (k - C)];
  Wb[idx] = f2bf_rne(v);
}

// ---------------- pointnet GEMM via bf16 MFMA + max over 16 points ----------------
template<int C>
__global__ __launch_bounds__(256) void pn_mfma(
    const float* __restrict__ xyz, const float* __restrict__ feats,
    const unsigned short* __restrict__ Wb, float* __restrict__ part){
  constexpr int KPAD = C + 32;
  constexpr int NK   = KPAD / 32;
  constexpr int MT   = C / 16;
  const int nchunk = blockIdx.x, b = blockIdx.y;
  const int tid  = threadIdx.x;
  const int lane = tid & 63, wave = tid >> 6;
  const int g = lane >> 4, l16 = lane & 15;
  const int colbase = wave * 48;
  const int nbase   = nchunk * 192;

  int nn[3], pp[3];
  #pragma unroll
  for (int t = 0; t < 3; t++){
    nn[t] = nbase + colbase + t * 16 + l16;
    pp[t] = nn[t] / 12;
  }

  f32x4 acc[MT][3];
  #pragma unroll
  for (int m = 0; m < MT; m++)
    #pragma unroll
    for (int t = 0; t < 3; t++)
      acc[m][t] = (f32x4){0.f, 0.f, 0.f, 0.f};

  const float* fB = feats + (size_t)b * C * (NPTS * NANG);

  #pragma unroll
  for (int ks = 0; ks < NK - 1; ks++){
    const int kb = ks * 32;
    bf16x8 Bf[3];
    #pragma unroll
    for (int t = 0; t < 3; t++){
      const float* src = fB + (size_t)(kb + g * 8) * (NPTS * NANG) + nn[t];
      float f[8];
      #pragma unroll
      for (int j = 0; j < 8; j++) f[j] = src[(size_t)j * (NPTS * NANG)];
      Bf[t] = pack8(f);
    }
    #pragma unroll
    for (int m = 0; m < MT; m++){
      const bf16x8 Af = *(const bf16x8*)(Wb + (size_t)(m * 16 + l16) * KPAD + kb + g * 8);
      #pragma unroll
      for (int t = 0; t < 3; t++)
        acc[m][t] = __builtin_amdgcn_mfma_f32_16x16x32_bf16(Af, Bf[t], acc[m][t], 0, 0, 0);
    }
  }

  { // xyz K-step
    const int kb = C;
    bf16x8 Bf[3];
    #pragma unroll
    for (int t = 0; t < 3; t++){
      float f[8];
      #pragma unroll
      for (int j = 0; j < 8; j++) f[j] = 0.f;
      if (g == 0){
        #pragma unroll
        for (int j = 0; j < 3; j++)
          f[j] = xyz[(size_t)(b * 3 + j) * NPTS + pp[t]];
      }
      Bf[t] = pack8(f);
    }
    #pragma unroll
    for (int m = 0; m < MT; m++){
      const bf16x8 Af = *(const bf16x8*)(Wb + (size_t)(m * 16 + l16) * KPAD + kb + g * 8);
      #pragma unroll
      for (int t = 0; t < 3; t++)
        acc[m][t] = __builtin_amdgcn_mfma_f32_16x16x32_bf16(Af, Bf[t], acc[m][t], 0, 0, 0);
    }
  }

  __shared__ float yb[16 * 192];
  #pragma unroll
  for (int m = 0; m < MT; m++){
    __syncthreads();
    #pragma unroll
    for (int t = 0; t < 3; t++)
      #pragma unroll
      for (int r = 0; r < 4; r++)
        yb[(g * 4 + r) * 192 + colbase + t * 16 + l16] = acc[m][t][r];
    __syncthreads();
    if (tid < 192){
      const int o_l = tid / 12, a = tid % 12;
      float mx = -3.4e38f;
      #pragma unroll
      for (int pl = 0; pl < 16; pl++)
        mx = fmaxf(mx, yb[o_l * 192 + pl * 12 + a]);
      part[(((size_t)b * C + m * 16 + o_l) * 12 + a) * 64 + nchunk] = mx;
    }
  }
}

// ---------------- reduce chunks + bias + BN + relu -> xcat (16,192,12) ----------------
__global__ void pn_reduce_bn(const float* __restrict__ part0, const float* __restrict__ part1,
    const float* __restrict__ b0, const float* __restrict__ g0, const float* __restrict__ bb0,
    const float* __restrict__ b1, const float* __restrict__ g1, const float* __restrict__ bb1,
    float* __restrict__ xcat){
  const int ch = blockIdx.x, t = threadIdx.x;
  const int b = t / 12, a = t % 12;
  const float* part; const float *bias, *g, *bb; int o, Cl;
  if (ch < 64){ part = part0; bias = b0; g = g0; bb = bb0; o = ch;      Cl = 64;  }
  else        { part = part1; bias = b1; g = g1; bb = bb1; o = ch - 64; Cl = 128; }
  const float* pp = part + (((size_t)b * Cl + o) * 12 + a) * 64;
  float v = pp[0];
  for (int k = 1; k < 64; k++) v = fmaxf(v, pp[k]);
  v += bias[o];
  __shared__ float sbuf[8];
  float m, var;
  block_stats<192>(v, m, var, sbuf);
  float xn = (v - m) * rsqrtf(var + EPSV) * g[o] + bb[o];
  xcat[((size_t)b * 192 + ch) * 12 + a] = fmaxf(xn, 0.f);
}

// ---------------- lin layer + BN (no relu) -> xlin (16,256,12) ----------------
__global__ void lin_bn(const float* __restrict__ xcat, const float* __restrict__ W,
    const float* __restrict__ bias, const float* __restrict__ g, const float* __restrict__ bb,
    float* __restrict__ xlin){
  const int o = blockIdx.x, t = threadIdx.x;
  const int b = t / 12, a = t % 12;
  const float* xr = xcat + (size_t)b * 2304 + a;
  const float* wr = W + (size_t)o * 192;
  float v = bias[o];
  for (int c = 0; c < 192; c++) v = fmaf(wr[c], xr[(size_t)c * 12], v);
  __shared__ float sbuf[8];
  float m, var;
  block_stats<192>(v, m, var, sbuf);
  xlin[((size_t)b * 256 + o) * 12 + a] = (v - m) * rsqrtf(var + EPSV) * g[o] + bb[o];
}

// ---------------- prep: feat_W fp32 (512x3072) -> [hi | lo] bf16 (512x6144) ----------------
__global__ void prep_featw(const float* __restrict__ W, unsigned short* __restrict__ Wb2){
  const int idx = blockIdx.x * 256 + threadIdx.x;   // 512*3072
  if (idx >= 512 * 3072) return;
  const int o = idx / 3072, k = idx % 3072;
  const float x = W[idx];
  const unsigned short hi = f2bf_rne(x);
  const unsigned short lo = f2bf_rne(x - bf2f(hi));
  Wb2[(size_t)o * 6144 + k] = hi;
  Wb2[(size_t)o * 6144 + 3072 + k] = lo;
}

// ---------------- prep: gathered activations Xg [n=1024][hi(3072) | lo(3072)] bf16 ----------------
__global__ void prep_xg(const float* __restrict__ xlin, const int* __restrict__ trace,
                        unsigned short* __restrict__ Xg){
  const int n = blockIdx.x;
  const int r = n & 63, b = n >> 6;
  unsigned short* row = Xg + (size_t)n * 6144;
  if (r >= 60){
    for (int i = threadIdx.x; i < 3072; i += 256){ row[i] = 0; row[3072 + i] = 0; }
    return;
  }
  __shared__ int ta[12];
  if (threadIdx.x < 12) ta[threadIdx.x] = trace[threadIdx.x * 60 + r];
  __syncthreads();
  for (int i = threadIdx.x; i < 3072; i += 256){
    const int c = i / 12, a = i % 12;
    const float x = xlin[((size_t)b * 256 + c) * 12 + ta[a]];
    const unsigned short hi = f2bf_rne(x);
    const unsigned short lo = f2bf_rne(x - bf2f(hi));
    row[i] = hi;
    row[3072 + i] = lo;
  }
}

// ---------------- feat GEMM via MFMA, hi/lo 3-segment split ----------------
// grid (b=16, mblk=8, seg=3); block 256 = 4 waves in 2x2 tile arrangement.
// Wave (wm,wn) computes m-tiles {wm,wm+1} x n-tiles {wn,wn+1} (16x16 each).
// Explicit double-buffered fragment registers: load k+1 while MFMA k.
// gridDim.x = b so XCD = linear%8 = b%8 -> B slab L2-resident per XCD.
__global__ __launch_bounds__(256) void feat_mfma(
    const unsigned short* __restrict__ Wb2, const unsigned short* __restrict__ Xg,
    float* __restrict__ fraw){
  const int b = blockIdx.x, mblk = blockIdx.y, seg = blockIdx.z;
  const int lane = threadIdx.x & 63, wave = threadIdx.x >> 6;
  const int g = lane >> 4, l16 = lane & 15;
  const int kA = (seg == 1) ? 3072 : 0;
  const int kB = (seg == 2) ? 3072 : 0;
  const int wm = (wave >> 1) * 2;   // m-tile base (0 or 2)
  const int wn = (wave & 1) * 2;    // n-tile base (0 or 2)

  const unsigned short* A0p = Wb2 + (size_t)(mblk * 64 + (wm + 0) * 16 + l16) * 6144 + kA + g * 8;
  const unsigned short* A1p = Wb2 + (size_t)(mblk * 64 + (wm + 1) * 16 + l16) * 6144 + kA + g * 8;
  const unsigned short* B0p = Xg  + (size_t)(b * 64 + (wn + 0) * 16 + l16) * 6144 + kB + g * 8;
  const unsigned short* B1p = Xg  + (size_t)(b * 64 + (wn + 1) * 16 + l16) * 6144 + kB + g * 8;

  f32x4 acc00 = {0.f,0.f,0.f,0.f}, acc01 = {0.f,0.f,0.f,0.f};
  f32x4 acc10 = {0.f,0.f,0.f,0.f}, acc11 = {0.f,0.f,0.f,0.f};

  bf16x8 a0 = *(const bf16x8*)A0p, a1 = *(const bf16x8*)A1p;
  bf16x8 b0 = *(const bf16x8*)B0p, b1 = *(const bf16x8*)B1p;

  #pragma unroll 2
  for (int kb = 32; kb < 3072; kb += 32){
    const bf16x8 na0 = *(const bf16x8*)(A0p + kb);
    const bf16x8 na1 = *(const bf16x8*)(A1p + kb);
    const bf16x8 nb0 = *(const bf16x8*)(B0p + kb);
    const bf16x8 nb1 = *(const bf16x8*)(B1p + kb);
    acc00 = __builtin_amdgcn_mfma_f32_16x16x32_bf16(a0, b0, acc00, 0, 0, 0);
    acc01 = __builtin_amdgcn_mfma_f32_16x16x32_bf16(a0, b1, acc01, 0, 0, 0);
    acc10 = __builtin_amdgcn_mfma_f32_16x16x32_bf16(a1, b0, acc10, 0, 0, 0);
    acc11 = __builtin_amdgcn_mfma_f32_16x16x32_bf16(a1, b1, acc11, 0, 0, 0);
    a0 = na0; a1 = na1; b0 = nb0; b1 = nb1;
  }
  acc00 = __builtin_amdgcn_mfma_f32_16x16x32_bf16(a0, b0, acc00, 0, 0, 0);
  acc01 = __builtin_amdgcn_mfma_f32_16x16x32_bf16(a0, b1, acc01, 0, 0, 0);
  acc10 = __builtin_amdgcn_mfma_f32_16x16x32_bf16(a1, b0, acc10, 0, 0, 0);
  acc11 = __builtin_amdgcn_mfma_f32_16x16x32_bf16(a1, b1, acc11, 0, 0, 0);

  float* base = fraw + ((size_t)seg * NBATCH + b) * (512 * 60);
  const int r0 = (wn + 0) * 16 + l16;
  const int r1 = (wn + 1) * 16 + l16;
  #pragma unroll
  for (int q = 0; q < 4; q++){
    const int o0 = mblk * 64 + (wm + 0) * 16 + g * 4 + q;
    const int o1 = mblk * 64 + (wm + 1) * 16 + g * 4 + q;
    if (r0 < 60){
      base[(size_t)o0 * 60 + r0] = acc00[q];
      base[(size_t)o1 * 60 + r0] = acc10[q];
    }
    if (r1 < 60){
      base[(size_t)o0 * 60 + r1] = acc01[q];
      base[(size_t)o1 * 60 + r1] = acc11[q];
    }
  }
}

// ---------------- feat: sum 3 segs + bias + BN + relu + per-b max over r ----------------
__global__ void feat_bn(const float* __restrict__ fraw, const float* __restrict__ bias,
    const float* __restrict__ g, const float* __restrict__ bb,
    float* __restrict__ xf, float* __restrict__ xm){
  const int o = blockIdx.x, t = threadIdx.x;
  const int b = t / 60, r = t % 60;
  const size_t i0 = ((size_t)b * 512 + o) * 60 + r;
  const size_t SS = (size_t)NBATCH * 512 * 60;
  float v = fraw[i0] + fraw[SS + i0] + fraw[2 * SS + i0] + bias[o];
  __shared__ float sbuf[32];
  float m, var;
  block_stats<960>(v, m, var, sbuf);
  const float xn = fmaxf((v - m) * rsqrtf(var + EPSV) * g[o] + bb[o], 0.f);
  xf[i0] = xn;
  __shared__ float red[960];
  red[t] = xn;
  __syncthreads();
  if (r == 0){
    float mx = red[t];
    for (int k = 1; k < 60; k++) mx = fmaxf(mx, red[t + k]);
    xm[(size_t)b * 512 + o] = mx;
  }
}

// ---------------- branch GEMM (reg_W1 / att_W1) ----------------
__global__ __launch_bounds__(256) void brgemm(const float* __restrict__ xf,
    const float* __restrict__ W, const float* __restrict__ bias, float* __restrict__ out){
  const int og = blockIdx.x, b = blockIdx.y;
  const int lane = threadIdx.x & 63, wave = threadIdx.x >> 6;
  const int obase = og * 32 + wave * 8;
  const int rr = lane < 60 ? lane : 0;
  float acc[8];
  #pragma unroll
  for (int i = 0; i < 8; i++) acc[i] = bias[obase + i];
  const float* xb = xf + (size_t)b * 512 * 60 + rr;
  for (int c = 0; c < 512; c++){
    const float x = xb[(size_t)c * 60];
    #pragma unroll
    for (int i = 0; i < 8; i++)
      acc[i] = fmaf(W[(size_t)(obase + i) * 512 + c], x, acc[i]);
  }
  if (lane < 60){
    #pragma unroll
    for (int i = 0; i < 8; i++)
      out[((size_t)b * 128 + obase + i) * 60 + lane] = acc[i];
  }
}

// ---------------- BN + relu over (b,r) ----------------
__global__ void bn960(const float* __restrict__ raw, const float* __restrict__ g,
    const float* __restrict__ bb, float* __restrict__ outp, int C){
  const int o = blockIdx.x, t = threadIdx.x;
  const int b = t / 60, r = t % 60;
  const size_t idx = ((size_t)b * C + o) * 60 + r;
  const float v = raw[idx];
  __shared__ float sbuf[32];
  float m, var;
  block_stats<960>(v, m, var, sbuf);
  outp[idx] = fmaxf((v - m) * rsqrtf(var + EPSV) * g[o] + bb[o], 0.f);
}

// ---------------- reg head ----------------
__global__ void reg2_geom(const float* __restrict__ h, const float* __restrict__ W2,
    const float* __restrict__ b2, const float* __restrict__ anchors, float* __restrict__ out){
  const int b = blockIdx.x, lane = threadIdx.x;
  const int r = lane < 60 ? lane : 59;
  float res[7];
  #pragma unroll
  for (int j = 0; j < 7; j++){
    float acc = b2[j];
    for (int c = 0; c < 128; c++)
      acc = fmaf(W2[j * 128 + c], h[((size_t)b * 128 + c) * 60 + r], acc);
    res[j] = acc;
  }
  if (lane >= 60) return;
  const float n = sqrtf(res[0]*res[0] + res[1]*res[1] + res[2]*res[2]);
  const float invn = 1.f / n;
  const float Nv = (1.f / (1.f + expf(-res[3])) - 0.5f) * 3.14159265358979323846f / 5.f;
  const float v0 = res[0]*invn*Nv, v1 = res[1]*invn*Nv, v2 = res[2]*invn*Nv;
  const float th = sqrtf(v0*v0 + v1*v1 + v2*v2);
  const float invt = th < 1e-8f ? 1.f : 1.f / th;
  const float k0 = v0*invt, k1 = v1*invt, k2 = v2*invt;
  const float s = sinf(th), cc = 1.f - cosf(th);
  const float K[9] = {0.f, -k2, k1,  k2, 0.f, -k0,  -k1, k0, 0.f};
  float K2[9];
  #pragma unroll
  for (int ii = 0; ii < 3; ii++)
    #pragma unroll
    for (int jj = 0; jj < 3; jj++)
      K2[ii*3+jj] = K[ii*3+0]*K[0*3+jj] + K[ii*3+1]*K[1*3+jj] + K[ii*3+2]*K[2*3+jj];
  float R[9];
  #pragma unroll
  for (int ii = 0; ii < 3; ii++)
    #pragma unroll
    for (int jj = 0; jj < 3; jj++)
      R[ii*3+jj] = (ii == jj ? 1.f : 0.f) + s * K[ii*3+jj] + cc * K2[ii*3+jj];
  const float* A = anchors + (size_t)r * 9;
  #pragma unroll
  for (int ii = 0; ii < 3; ii++)
    #pragma unroll
    for (int kk = 0; kk < 3; kk++){
      const float pv = A[ii*3+0]*R[0*3+kk] + A[ii*3+1]*R[1*3+kk] + A[ii*3+2]*R[2*3+kk];
      out[OUT_PRED + ((size_t)b * 60 + r) * 9 + ii * 3 + kk] = pv;
    }
  #pragma unroll
  for (int k = 0; k < 3; k++)
    out[OUT_REST + ((size_t)b * 60 + r) * 3 + k] = res[4 + k];
}

// ---------------- att head ----------------
__global__ void att2_softmax(const float* __restrict__ a, const float* __restrict__ W2,
    const float* __restrict__ b2, float* __restrict__ out){
  const int b = blockIdx.x, lane = threadIdx.x;
  const int r = lane < 60 ? lane : 59;
  float acc = b2[0];
  for (int c = 0; c < 128; c++)
    acc = fmaf(W2[c], a[((size_t)b * 128 + c) * 60 + r], acc);
  const float l = lane < 60 ? acc : -INFINITY;
  float mx = l;
  #pragma unroll
  for (int off = 32; off; off >>= 1) mx = fmaxf(mx, __shfl_xor(mx, off, 64));
  const float e = lane < 60 ? expf(l - mx) : 0.f;
  float ssum = e;
  #pragma unroll
  for (int off = 32; off; off >>= 1) ssum += __shfl_xor(ssum, off, 64);
  if (lane < 60) out[OUT_ATTN + (size_t)b * 60 + lane] = e / ssum;
}

// ---------------- out head 1 ----------------
__global__ void out_head1(const float* __restrict__ xm, const float* __restrict__ W1,
    const float* __restrict__ b1, const float* __restrict__ g, const float* __restrict__ bb,
    float* __restrict__ o_act){
  const int t = threadIdx.x;
  const int b = t & 15, j = t >> 4;
  const int oc = blockIdx.x * 8 + j;
  float acc = b1[oc];
  const float* wr = W1 + (size_t)oc * 512;
  const float* xr = xm + (size_t)b * 512;
  for (int c = 0; c < 512; c++) acc = fmaf(wr[c], xr[c], acc);
  float s = acc, s2 = acc * acc;
  #pragma unroll
  for (int off = 8; off; off >>= 1){
    s  += __shfl_xor(s,  off, 16);
    s2 += __shfl_xor(s2, off, 16);
  }
  const float m = s * (1.f / 16.f);
  const float var = s2 * (1.f / 16.f) - m * m;
  o_act[(size_t)b * 512 + oc] = fmaxf((acc - m) * rsqrtf(var + EPSV) * g[oc] + bb[oc], 0.f);
}

// ---------------- out head 2 ----------------
__global__ void out_head2(const float* __restrict__ o_act, const float* __restrict__ W2,
    const float* __restrict__ b2, float* __restrict__ out){
  const int b = blockIdx.x, j = threadIdx.x;
  const float* wr = W2 + (size_t)j * 512;
  const float* xr = o_act + (size_t)b * 512;
  float acc = b2[j];
  for (int c = 0; c < 512; c++) acc = fmaf(wr[c], xr[c], acc);
  out[OUT_XOUT + (size_t)b * 256 + j] = acc;
}

// ---------------- launch ----------------
extern "C" void kernel_launch(void* const* d_in, const int* in_sizes, int n_in,
                              void* d_out, int out_size, void* d_ws, size_t ws_size,
                              hipStream_t stream){
  const float* xyz0    = (const float*)d_in[0];
  const float* feats0  = (const float*)d_in[1];
  const float* xyz1    = (const float*)d_in[2];
  const float* feats1  = (const float*)d_in[3];
  const int*   trace   = (const int*)  d_in[4];
  const float* anchors = (const float*)d_in[5];
  const float* pn0_W  = (const float*)d_in[6];
  const float* pn0_b  = (const float*)d_in[7];
  const float* pn0_g  = (const float*)d_in[8];
  const float* pn0_bb = (const float*)d_in[9];
  const float* pn1_W  = (const float*)d_in[10];
  const float* pn1_b  = (const float*)d_in[11];
  const float* pn1_g  = (const float*)d_in[12];
  const float* pn1_bb = (const float*)d_in[13];
  const float* lin_W  = (const float*)d_in[14];
  const float* lin_b  = (const float*)d_in[15];
  const float* lin_g  = (const float*)d_in[16];
  const float* lin_bb = (const float*)d_in[17];
  const float* feat_W  = (const float*)d_in[18];
  const float* feat_b  = (const float*)d_in[19];
  const float* feat_g  = (const float*)d_in[20];
  const float* feat_bb = (const float*)d_in[21];
  const float* att_W1 = (const float*)d_in[22];
  const float* att_b1 = (const float*)d_in[23];
  const float* att_g  = (const float*)d_in[24];
  const float* att_bb = (const float*)d_in[25];
  const float* att_W2 = (const float*)d_in[26];
  const float* att_b2 = (const float*)d_in[27];
  const float* reg_W1 = (const float*)d_in[28];
  const float* reg_b1 = (const float*)d_in[29];
  const float* reg_g  = (const float*)d_in[30];
  const float* reg_bb = (const float*)d_in[31];
  const float* reg_W2 = (const float*)d_in[32];
  const float* reg_b2 = (const float*)d_in[33];
  const float* out_W1 = (const float*)d_in[34];
  const float* out_b1 = (const float*)d_in[35];
  const float* out_g  = (const float*)d_in[36];
  const float* out_bb = (const float*)d_in[37];
  const float* out_W2 = (const float*)d_in[38];
  const float* out_b2 = (const float*)d_in[39];

  float* ws  = (float*)d_ws;
  float* out = (float*)d_out;
  unsigned short* wb0 = (unsigned short*)(ws + WB0_OFF);
  unsigned short* wb1 = (unsigned short*)(ws + WB1_OFF);
  unsigned short* fw  = (unsigned short*)(ws + FEATW_OFF);
  unsigned short* xg  = (unsigned short*)(ws + XG_OFF);

  // pointnet weight prep
  prep_wb<64> <<<24, 256, 0, stream>>>(pn0_W, wb0);
  prep_wb<128><<<80, 256, 0, stream>>>(pn1_W, wb1);

  // pointnets via MFMA
  pn_mfma<64> <<<dim3(64, 16), 256, 0, stream>>>(xyz0, feats0, wb0, ws + PART0_OFF);
  pn_mfma<128><<<dim3(64, 16), 256, 0, stream>>>(xyz1, feats1, wb1, ws + PART1_OFF);

  // reduce + BN + relu -> concat
  pn_reduce_bn<<<192, 192, 0, stream>>>(ws + PART0_OFF, ws + PART1_OFF,
      pn0_b, pn0_g, pn0_bb, pn1_b, pn1_g, pn1_bb, ws + XCAT_OFF);

  // feat weight hi/lo prep (after pn_reduce_bn: aliases PART)
  prep_featw<<<6144, 256, 0, stream>>>(feat_W, fw);

  // lin + BN
  lin_bn<<<256, 192, 0, stream>>>(ws + XCAT_OFF, lin_W, lin_b, lin_g, lin_bb, ws + XLIN_OFF);

  // gathered activations hi/lo
  prep_xg<<<1024, 256, 0, stream>>>(ws + XLIN_OFF, trace, xg);

  // feat GEMM via MFMA (3 hi/lo segments, 2x2 wave tiles, SW-pipelined)
  feat_mfma<<<dim3(16, 8, 3), 256, 0, stream>>>(fw, xg, ws + FRAW_OFF);
  feat_bn<<<512, 960, 0, stream>>>(ws + FRAW_OFF, feat_b, feat_g, feat_bb,
                                   ws + XF_OFF, ws + XM_OFF);

  // reg / att branches
  brgemm<<<dim3(4, 16), 256, 0, stream>>>(ws + XF_OFF, reg_W1, reg_b1, ws + HRAW_OFF);
  bn960<<<128, 960, 0, stream>>>(ws + HRAW_OFF, reg_g, reg_bb, ws + HACT_OFF, 128);
  brgemm<<<dim3(4, 16), 256, 0, stream>>>(ws + XF_OFF, att_W1, att_b1, ws + ARAW_OFF);
  bn960<<<128, 960, 0, stream>>>(ws + ARAW_OFF, att_g, att_bb, ws + AACT_OFF, 128);

  // heads
  reg2_geom<<<16, 64, 0, stream>>>(ws + HACT_OFF, reg_W2, reg_b2, anchors, out);
  att2_softmax<<<16, 64, 0, stream>>>(ws + AACT_OFF, att_W2, att_b2, out);
  out_head1<<<64, 128, 0, stream>>>(ws + XM_OFF, out_W1, out_b1, out_g, out_bb, ws + OACT_OFF);
  out_head2<<<16, 256, 0, stream>>>(ws + OACT_OFF, out_W2, out_b2, out);
}

// Round 5
// 521.004 us; speedup vs baseline: 1.7647x; 1.2950x over previous
//
#include <hip/hip_runtime.h>
#include <math.h>

// ---------------- problem constants ----------------
#define NBATCH 16
#define NPTS   1024
#define NANG   12
#define NROTS  60
#define EPSV   1e-5f

// ---------------- workspace layout (float offsets) ----------------
// lifetime-aliased; peak extent = 7570432 floats = 30.3 MB
#define WB0_OFF   0          // 64*96 bf16 = 3072 floats
#define WB1_OFF   3072       // 128*160 bf16 = 10240 floats (ends 13312)
#define PART0_OFF 13312      // 16*64*12*64  = 786432
#define PART1_OFF 799744     // 16*128*12*64 = 1572864 (ends 2372608)
#define FEATW_OFF 13312      // 512*6144 bf16 = 1572864 floats (aliases PART; dead PART)
#define XF_OFF    13312      // 16*512*60 = 491520 (aliases FEATW after feat_mfma)
#define XM_OFF    504832     // 16*512 = 8192 (after XF, still in old FEATW region)
#define OACT_OFF  513024     // 16*512 = 8192
#define XCAT_OFF  2372608    // 16*192*12 = 36864
#define XLIN_OFF  2409472    // 16*256*12 = 49152
#define XG_OFF    2458624    // 1024*6144 bf16 = 3145728 floats (ends 5604352)
#define BRP_OFF   2458624    // 16*16*128*60 = 1966080 (aliases XG; dead after feat_mfma)
#define HACT_OFF  4424704    // 16*128*60 = 122880
#define AACT_OFF  4547584    // 16*128*60 = 122880 (ends 4670464 < 5604352)
#define FRAW_OFF  5604352    // 4*16*512*60 = 1966080 (ends 7570432)
// peak = 7570432 floats = 30.3 MB

// ---------------- output layout (float offsets) ----------------
#define OUT_XOUT 0       // (16,256)   = 4096
#define OUT_ATTN 4096    // (16,60)    = 960
#define OUT_PRED 5056    // (16,60,3,3)= 8640
#define OUT_REST 13696   // (16,60,3)  = 2880

typedef short  bf16x8 __attribute__((ext_vector_type(8)));
typedef float  f32x4  __attribute__((ext_vector_type(4)));

// fp32 -> bf16 RNE
__device__ __forceinline__ unsigned short f2bf_rne(float x){
  unsigned int u = __float_as_uint(x);
  u += 0x7FFFu + ((u >> 16) & 1u);
  return (unsigned short)(u >> 16);
}
__device__ __forceinline__ float bf2f(unsigned short h){
  return __uint_as_float(((unsigned int)h) << 16);
}

// pack 8 fp32 -> bf16x8 by truncation (one v_perm_b32 per pair)
__device__ __forceinline__ bf16x8 pack8(const float* f){
  union { unsigned int u[4]; bf16x8 v; } r;
  #pragma unroll
  for (int i = 0; i < 4; i++)
    r.u[i] = __builtin_amdgcn_perm(__float_as_uint(f[2*i+1]),
                                   __float_as_uint(f[2*i]), 0x07060302u);
  return r.v;
}

// ---------------- block-wide mean/var helper ----------------
template<int NT>
__device__ __forceinline__ void block_stats(float v, float& m, float& var, float* sbuf){
  constexpr int NW = NT / 64;
  float s = v, s2 = v * v;
  #pragma unroll
  for (int off = 32; off; off >>= 1){
    s  += __shfl_xor(s,  off, 64);
    s2 += __shfl_xor(s2, off, 64);
  }
  const int w = threadIdx.x >> 6;
  if ((threadIdx.x & 63) == 0){ sbuf[w] = s; sbuf[NW + w] = s2; }
  __syncthreads();
  float ts = 0.f, ts2 = 0.f;
  #pragma unroll
  for (int i = 0; i < NW; i++){ ts += sbuf[i]; ts2 += sbuf[NW + i]; }
  m = ts / (float)NT;
  var = ts2 / (float)NT - m * m;
}

// ---------------- prep: W (O x C+3) -> Wb (O x KPAD) bf16 ----------------
template<int C>
__global__ void prep_wb(const float* __restrict__ W, unsigned short* __restrict__ Wb){
  constexpr int KPAD = C + 32;
  const int idx = blockIdx.x * 256 + threadIdx.x;
  if (idx >= C * KPAD) return;
  const int o = idx / KPAD, k = idx % KPAD;
  float v = 0.f;
  if (k < C)          v = W[(size_t)o * (C + 3) + 3 + k];
  else if (k < C + 3) v = W[(size_t)o * (C + 3) + (k - C)];
  Wb[idx] = f2bf_rne(v);
}

// ---------------- pointnet GEMM via bf16 MFMA + max over 16 points ----------------
template<int C>
__global__ __launch_bounds__(256) void pn_mfma(
    const float* __restrict__ xyz, const float* __restrict__ feats,
    const unsigned short* __restrict__ Wb, float* __restrict__ part){
  constexpr int KPAD = C + 32;
  constexpr int NK   = KPAD / 32;
  constexpr int MT   = C / 16;
  const int nchunk = blockIdx.x, b = blockIdx.y;
  const int tid  = threadIdx.x;
  const int lane = tid & 63, wave = tid >> 6;
  const int g = lane >> 4, l16 = lane & 15;
  const int colbase = wave * 48;
  const int nbase   = nchunk * 192;

  int nn[3], pp[3];
  #pragma unroll
  for (int t = 0; t < 3; t++){
    nn[t] = nbase + colbase + t * 16 + l16;
    pp[t] = nn[t] / 12;
  }

  f32x4 acc[MT][3];
  #pragma unroll
  for (int m = 0; m < MT; m++)
    #pragma unroll
    for (int t = 0; t < 3; t++)
      acc[m][t] = (f32x4){0.f, 0.f, 0.f, 0.f};

  const float* fB = feats + (size_t)b * C * (NPTS * NANG);

  #pragma unroll
  for (int ks = 0; ks < NK - 1; ks++){
    const int kb = ks * 32;
    bf16x8 Bf[3];
    #pragma unroll
    for (int t = 0; t < 3; t++){
      const float* src = fB + (size_t)(kb + g * 8) * (NPTS * NANG) + nn[t];
      float f[8];
      #pragma unroll
      for (int j = 0; j < 8; j++) f[j] = src[(size_t)j * (NPTS * NANG)];
      Bf[t] = pack8(f);
    }
    #pragma unroll
    for (int m = 0; m < MT; m++){
      const bf16x8 Af = *(const bf16x8*)(Wb + (size_t)(m * 16 + l16) * KPAD + kb + g * 8);
      #pragma unroll
      for (int t = 0; t < 3; t++)
        acc[m][t] = __builtin_amdgcn_mfma_f32_16x16x32_bf16(Af, Bf[t], acc[m][t], 0, 0, 0);
    }
  }

  { // xyz K-step
    const int kb = C;
    bf16x8 Bf[3];
    #pragma unroll
    for (int t = 0; t < 3; t++){
      float f[8];
      #pragma unroll
      for (int j = 0; j < 8; j++) f[j] = 0.f;
      if (g == 0){
        #pragma unroll
        for (int j = 0; j < 3; j++)
          f[j] = xyz[(size_t)(b * 3 + j) * NPTS + pp[t]];
      }
      Bf[t] = pack8(f);
    }
    #pragma unroll
    for (int m = 0; m < MT; m++){
      const bf16x8 Af = *(const bf16x8*)(Wb + (size_t)(m * 16 + l16) * KPAD + kb + g * 8);
      #pragma unroll
      for (int t = 0; t < 3; t++)
        acc[m][t] = __builtin_amdgcn_mfma_f32_16x16x32_bf16(Af, Bf[t], acc[m][t], 0, 0, 0);
    }
  }

  __shared__ float yb[16 * 192];
  #pragma unroll
  for (int m = 0; m < MT; m++){
    __syncthreads();
    #pragma unroll
    for (int t = 0; t < 3; t++)
      #pragma unroll
      for (int r = 0; r < 4; r++)
        yb[(g * 4 + r) * 192 + colbase + t * 16 + l16] = acc[m][t][r];
    __syncthreads();
    if (tid < 192){
      const int o_l = tid / 12, a = tid % 12;
      float mx = -3.4e38f;
      #pragma unroll
      for (int pl = 0; pl < 16; pl++)
        mx = fmaxf(mx, yb[o_l * 192 + pl * 12 + a]);
      part[(((size_t)b * C + m * 16 + o_l) * 12 + a) * 64 + nchunk] = mx;
    }
  }
}

// ---------------- reduce chunks + bias + BN + relu -> xcat (16,192,12) ----------------
__global__ void pn_reduce_bn(const float* __restrict__ part0, const float* __restrict__ part1,
    const float* __restrict__ b0, const float* __restrict__ g0, const float* __restrict__ bb0,
    const float* __restrict__ b1, const float* __restrict__ g1, const float* __restrict__ bb1,
    float* __restrict__ xcat){
  const int ch = blockIdx.x, t = threadIdx.x;
  const int b = t / 12, a = t % 12;
  const float* part; const float *bias, *g, *bb; int o, Cl;
  if (ch < 64){ part = part0; bias = b0; g = g0; bb = bb0; o = ch;      Cl = 64;  }
  else        { part = part1; bias = b1; g = g1; bb = bb1; o = ch - 64; Cl = 128; }
  const float* pp = part + (((size_t)b * Cl + o) * 12 + a) * 64;
  float v = pp[0];
  for (int k = 1; k < 64; k++) v = fmaxf(v, pp[k]);
  v += bias[o];
  __shared__ float sbuf[8];
  float m, var;
  block_stats<192>(v, m, var, sbuf);
  float xn = (v - m) * rsqrtf(var + EPSV) * g[o] + bb[o];
  xcat[((size_t)b * 192 + ch) * 12 + a] = fmaxf(xn, 0.f);
}

// ---------------- lin layer + BN (no relu) -> xlin (16,256,12) ----------------
__global__ void lin_bn(const float* __restrict__ xcat, const float* __restrict__ W,
    const float* __restrict__ bias, const float* __restrict__ g, const float* __restrict__ bb,
    float* __restrict__ xlin){
  const int o = blockIdx.x, t = threadIdx.x;
  const int b = t / 12, a = t % 12;
  const float* xr = xcat + (size_t)b * 2304 + a;
  const float* wr = W + (size_t)o * 192;
  float v = bias[o];
  for (int c = 0; c < 192; c++) v = fmaf(wr[c], xr[(size_t)c * 12], v);
  __shared__ float sbuf[8];
  float m, var;
  block_stats<192>(v, m, var, sbuf);
  xlin[((size_t)b * 256 + o) * 12 + a] = (v - m) * rsqrtf(var + EPSV) * g[o] + bb[o];
}

// ---------------- prep: feat_W fp32 (512x3072) -> [hi | lo] bf16 (512x6144) ----------------
__global__ void prep_featw(const float* __restrict__ W, unsigned short* __restrict__ Wb2){
  const int idx = blockIdx.x * 256 + threadIdx.x;   // 512*3072
  if (idx >= 512 * 3072) return;
  const int o = idx / 3072, k = idx % 3072;
  const float x = W[idx];
  const unsigned short hi = f2bf_rne(x);
  const unsigned short lo = f2bf_rne(x - bf2f(hi));
  Wb2[(size_t)o * 6144 + k] = hi;
  Wb2[(size_t)o * 6144 + 3072 + k] = lo;
}

// ---------------- prep: gathered activations Xg [n=1024][hi(3072) | lo(3072)] bf16 ----------------
__global__ void prep_xg(const float* __restrict__ xlin, const int* __restrict__ trace,
                        unsigned short* __restrict__ Xg){
  const int n = blockIdx.x;
  const int r = n & 63, b = n >> 6;
  unsigned short* row = Xg + (size_t)n * 6144;
  if (r >= 60){
    for (int i = threadIdx.x; i < 3072; i += 256){ row[i] = 0; row[3072 + i] = 0; }
    return;
  }
  __shared__ int ta[12];
  if (threadIdx.x < 12) ta[threadIdx.x] = trace[threadIdx.x * 60 + r];
  __syncthreads();
  for (int i = threadIdx.x; i < 3072; i += 256){
    const int c = i / 12, a = i % 12;
    const float x = xlin[((size_t)b * 256 + c) * 12 + ta[a]];
    const unsigned short hi = f2bf_rne(x);
    const unsigned short lo = f2bf_rne(x - bf2f(hi));
    row[i] = hi;
    row[3072 + i] = lo;
  }
}

// ---------------- feat GEMM via MFMA, hi/lo split, 4 K-jobs ----------------
// grid (b=16, mblk=8, job=4); block 256 = 4 waves, 2x2 tiles (16x16 each).
// job0: Whi*Xhi k<1536 ; job1: Whi*Xhi k>=1536 ;
// job2: (Wlo*Xhi + Whi*Xlo) k<1536 ; job3: same k>=1536.  Sum of 4 slabs = full.
__global__ __launch_bounds__(256) void feat_mfma(
    const unsigned short* __restrict__ Wb2, const unsigned short* __restrict__ Xg,
    float* __restrict__ fraw){
  const int b = blockIdx.x, mblk = blockIdx.y, job = blockIdx.z;
  const int lane = threadIdx.x & 63, wave = threadIdx.x >> 6;
  const int g = lane >> 4, l16 = lane & 15;
  const int wm = (wave >> 1) * 2;
  const int wn = (wave & 1) * 2;
  const int koff  = (job & 1) * 1536;
  const int npass = (job >> 1) + 1;

  const size_t rowA0 = (size_t)(mblk * 64 + (wm + 0) * 16 + l16) * 6144;
  const size_t rowA1 = (size_t)(mblk * 64 + (wm + 1) * 16 + l16) * 6144;
  const size_t rowB0 = (size_t)(b * 64 + (wn + 0) * 16 + l16) * 6144;
  const size_t rowB1 = (size_t)(b * 64 + (wn + 1) * 16 + l16) * 6144;

  f32x4 acc00 = {0.f,0.f,0.f,0.f}, acc01 = {0.f,0.f,0.f,0.f};
  f32x4 acc10 = {0.f,0.f,0.f,0.f}, acc11 = {0.f,0.f,0.f,0.f};

  for (int p = 0; p < npass; p++){
    int kA = 0, kB = 0;
    if (npass == 2){ if (p == 0) kA = 3072; else kB = 3072; }
    const unsigned short* A0p = Wb2 + rowA0 + kA + koff + g * 8;
    const unsigned short* A1p = Wb2 + rowA1 + kA + koff + g * 8;
    const unsigned short* B0p = Xg  + rowB0 + kB + koff + g * 8;
    const unsigned short* B1p = Xg  + rowB1 + kB + koff + g * 8;

    bf16x8 a0 = *(const bf16x8*)A0p, a1 = *(const bf16x8*)A1p;
    bf16x8 b0 = *(const bf16x8*)B0p, b1 = *(const bf16x8*)B1p;

    #pragma unroll 4
    for (int kb = 32; kb < 1536; kb += 32){
      const bf16x8 na0 = *(const bf16x8*)(A0p + kb);
      const bf16x8 na1 = *(const bf16x8*)(A1p + kb);
      const bf16x8 nb0 = *(const bf16x8*)(B0p + kb);
      const bf16x8 nb1 = *(const bf16x8*)(B1p + kb);
      acc00 = __builtin_amdgcn_mfma_f32_16x16x32_bf16(a0, b0, acc00, 0, 0, 0);
      acc01 = __builtin_amdgcn_mfma_f32_16x16x32_bf16(a0, b1, acc01, 0, 0, 0);
      acc10 = __builtin_amdgcn_mfma_f32_16x16x32_bf16(a1, b0, acc10, 0, 0, 0);
      acc11 = __builtin_amdgcn_mfma_f32_16x16x32_bf16(a1, b1, acc11, 0, 0, 0);
      a0 = na0; a1 = na1; b0 = nb0; b1 = nb1;
    }
    acc00 = __builtin_amdgcn_mfma_f32_16x16x32_bf16(a0, b0, acc00, 0, 0, 0);
    acc01 = __builtin_amdgcn_mfma_f32_16x16x32_bf16(a0, b1, acc01, 0, 0, 0);
    acc10 = __builtin_amdgcn_mfma_f32_16x16x32_bf16(a1, b0, acc10, 0, 0, 0);
    acc11 = __builtin_amdgcn_mfma_f32_16x16x32_bf16(a1, b1, acc11, 0, 0, 0);
  }

  float* base = fraw + ((size_t)job * NBATCH + b) * (512 * 60);
  const int r0 = (wn + 0) * 16 + l16;
  const int r1 = (wn + 1) * 16 + l16;
  #pragma unroll
  for (int q = 0; q < 4; q++){
    const int o0 = mblk * 64 + (wm + 0) * 16 + g * 4 + q;
    const int o1 = mblk * 64 + (wm + 1) * 16 + g * 4 + q;
    if (r0 < 60){
      base[(size_t)o0 * 60 + r0] = acc00[q];
      base[(size_t)o1 * 60 + r0] = acc10[q];
    }
    if (r1 < 60){
      base[(size_t)o0 * 60 + r1] = acc01[q];
      base[(size_t)o1 * 60 + r1] = acc11[q];
    }
  }
}

// ---------------- feat: sum 4 slabs + bias + BN + relu + per-b max over r ----------------
__global__ void feat_bn(const float* __restrict__ fraw, const float* __restrict__ bias,
    const float* __restrict__ g, const float* __restrict__ bb,
    float* __restrict__ xf, float* __restrict__ xm){
  const int o = blockIdx.x, t = threadIdx.x;
  const int b = t / 60, r = t % 60;
  const size_t i0 = ((size_t)b * 512 + o) * 60 + r;
  const size_t SS = (size_t)NBATCH * 512 * 60;
  float v = fraw[i0] + fraw[SS + i0] + fraw[2 * SS + i0] + fraw[3 * SS + i0] + bias[o];
  __shared__ float sbuf[32];
  float m, var;
  block_stats<960>(v, m, var, sbuf);
  const float xn = fmaxf((v - m) * rsqrtf(var + EPSV) * g[o] + bb[o], 0.f);
  xf[i0] = xn;
  __shared__ float red[960];
  red[t] = xn;
  __syncthreads();
  if (r == 0){
    float mx = red[t];
    for (int k = 1; k < 60; k++) mx = fmaxf(mx, red[t + k]);
    xm[(size_t)b * 512 + o] = mx;
  }
}

// ---------------- branch GEMMs fused (reg_W1 & att_W1), K split 8 ----------------
// grid (og=4, b=16, z=16): z = br*8+ks. block 256 = 4 waves x 8 o, lanes = r.
// brp[z][b][o][r] partials; 4-deep x pipeline; W loads wave-uniform (s_load).
__global__ __launch_bounds__(256) void brgemm2(const float* __restrict__ xf,
    const float* __restrict__ Wr, const float* __restrict__ Wa,
    float* __restrict__ brp){
  const int og = blockIdx.x, b = blockIdx.y, z = blockIdx.z;
  const int br = z >> 3, ks = z & 7;
  const float* W = br ? Wa : Wr;
  const int lane = threadIdx.x & 63, wave = threadIdx.x >> 6;
  const int obase = og * 32 + wave * 8;
  const int rr = lane < 60 ? lane : 0;
  const float* xb = xf + ((size_t)b * 512 + ks * 64) * 60 + rr;
  const float* wr = W + (size_t)obase * 512 + ks * 64;

  float acc[8];
  #pragma unroll
  for (int i = 0; i < 8; i++) acc[i] = 0.f;

  float cur[4], nxt[4];
  #pragma unroll
  for (int j = 0; j < 4; j++) cur[j] = xb[(size_t)j * 60];

  for (int c0 = 0; c0 < 64; c0 += 4){
    #pragma unroll
    for (int j = 0; j < 4; j++){
      int cc = c0 + 4 + j; if (cc > 63) cc = 63;   // clamp (tail values unused)
      nxt[j] = xb[(size_t)cc * 60];
    }
    #pragma unroll
    for (int j = 0; j < 4; j++)
      #pragma unroll
      for (int i = 0; i < 8; i++)
        acc[i] = fmaf(wr[(size_t)i * 512 + c0 + j], cur[j], acc[i]);
    #pragma unroll
    for (int j = 0; j < 4; j++) cur[j] = nxt[j];
  }

  if (lane < 60){
    #pragma unroll
    for (int i = 0; i < 8; i++)
      brp[(((size_t)z * NBATCH + b) * 128 + obase + i) * 60 + lane] = acc[i];
  }
}

// ---------------- branch: sum 8 K-slabs + bias + BN + relu ----------------
// grid (o=128, br=2), block 960 (b*60+r)
__global__ void br_bn(const float* __restrict__ brp,
    const float* __restrict__ biasR, const float* __restrict__ gR, const float* __restrict__ bbR,
    const float* __restrict__ biasA, const float* __restrict__ gA, const float* __restrict__ bbA,
    float* __restrict__ hact, float* __restrict__ aact){
  const int o = blockIdx.x, br = blockIdx.y, t = threadIdx.x;
  const int b = t / 60, r = t % 60;
  const float* bias = br ? biasA : biasR;
  const float* g    = br ? gA    : gR;
  const float* bb   = br ? bbA   : bbR;
  float v = bias[o];
  #pragma unroll
  for (int ks = 0; ks < 8; ks++)
    v += brp[((((size_t)br * 8 + ks) * NBATCH + b) * 128 + o) * 60 + r];
  __shared__ float sbuf[32];
  float m, var;
  block_stats<960>(v, m, var, sbuf);
  float* outp = br ? aact : hact;
  outp[((size_t)b * 128 + o) * 60 + r] =
      fmaxf((v - m) * rsqrtf(var + EPSV) * g[o] + bb[o], 0.f);
}

// ---------------- reg head ----------------
__global__ void reg2_geom(const float* __restrict__ h, const float* __restrict__ W2,
    const float* __restrict__ b2, const float* __restrict__ anchors, float* __restrict__ out){
  const int b = blockIdx.x, lane = threadIdx.x;
  const int r = lane < 60 ? lane : 59;
  float res[7];
  #pragma unroll
  for (int j = 0; j < 7; j++){
    float acc = b2[j];
    for (int c = 0; c < 128; c++)
      acc = fmaf(W2[j * 128 + c], h[((size_t)b * 128 + c) * 60 + r], acc);
    res[j] = acc;
  }
  if (lane >= 60) return;
  const float n = sqrtf(res[0]*res[0] + res[1]*res[1] + res[2]*res[2]);
  const float invn = 1.f / n;
  const float Nv = (1.f / (1.f + expf(-res[3])) - 0.5f) * 3.14159265358979323846f / 5.f;
  const float v0 = res[0]*invn*Nv, v1 = res[1]*invn*Nv, v2 = res[2]*invn*Nv;
  const float th = sqrtf(v0*v0 + v1*v1 + v2*v2);
  const float invt = th < 1e-8f ? 1.f : 1.f / th;
  const float k0 = v0*invt, k1 = v1*invt, k2 = v2*invt;
  const float s = sinf(th), cc = 1.f - cosf(th);
  const float K[9] = {0.f, -k2, k1,  k2, 0.f, -k0,  -k1, k0, 0.f};
  float K2[9];
  #pragma unroll
  for (int ii = 0; ii < 3; ii++)
    #pragma unroll
    for (int jj = 0; jj < 3; jj++)
      K2[ii*3+jj] = K[ii*3+0]*K[0*3+jj] + K[ii*3+1]*K[1*3+jj] + K[ii*3+2]*K[2*3+jj];
  float R[9];
  #pragma unroll
  for (int ii = 0; ii < 3; ii++)
    #pragma unroll
    for (int jj = 0; jj < 3; jj++)
      R[ii*3+jj] = (ii == jj ? 1.f : 0.f) + s * K[ii*3+jj] + cc * K2[ii*3+jj];
  const float* A = anchors + (size_t)r * 9;
  #pragma unroll
  for (int ii = 0; ii < 3; ii++)
    #pragma unroll
    for (int kk = 0; kk < 3; kk++){
      const float pv = A[ii*3+0]*R[0*3+kk] + A[ii*3+1]*R[1*3+kk] + A[ii*3+2]*R[2*3+kk];
      out[OUT_PRED + ((size_t)b * 60 + r) * 9 + ii * 3 + kk] = pv;
    }
  #pragma unroll
  for (int k = 0; k < 3; k++)
    out[OUT_REST + ((size_t)b * 60 + r) * 3 + k] = res[4 + k];
}

// ---------------- att head ----------------
__global__ void att2_softmax(const float* __restrict__ a, const float* __restrict__ W2,
    const float* __restrict__ b2, float* __restrict__ out){
  const int b = blockIdx.x, lane = threadIdx.x;
  const int r = lane < 60 ? lane : 59;
  float acc = b2[0];
  for (int c = 0; c < 128; c++)
    acc = fmaf(W2[c], a[((size_t)b * 128 + c) * 60 + r], acc);
  const float l = lane < 60 ? acc : -INFINITY;
  float mx = l;
  #pragma unroll
  for (int off = 32; off; off >>= 1) mx = fmaxf(mx, __shfl_xor(mx, off, 64));
  const float e = lane < 60 ? expf(l - mx) : 0.f;
  float ssum = e;
  #pragma unroll
  for (int off = 32; off; off >>= 1) ssum += __shfl_xor(ssum, off, 64);
  if (lane < 60) out[OUT_ATTN + (size_t)b * 60 + lane] = e / ssum;
}

// ---------------- out head 1 ----------------
__global__ void out_head1(const float* __restrict__ xm, const float* __restrict__ W1,
    const float* __restrict__ b1, const float* __restrict__ g, const float* __restrict__ bb,
    float* __restrict__ o_act){
  const int t = threadIdx.x;
  const int b = t & 15, j = t >> 4;
  const int oc = blockIdx.x * 8 + j;
  float acc = b1[oc];
  const float* wr = W1 + (size_t)oc * 512;
  const float* xr = xm + (size_t)b * 512;
  for (int c = 0; c < 512; c++) acc = fmaf(wr[c], xr[c], acc);
  float s = acc, s2 = acc * acc;
  #pragma unroll
  for (int off = 8; off; off >>= 1){
    s  += __shfl_xor(s,  off, 16);
    s2 += __shfl_xor(s2, off, 16);
  }
  const float m = s * (1.f / 16.f);
  const float var = s2 * (1.f / 16.f) - m * m;
  o_act[(size_t)b * 512 + oc] = fmaxf((acc - m) * rsqrtf(var + EPSV) * g[oc] + bb[oc], 0.f);
}

// ---------------- out head 2 ----------------
__global__ void out_head2(const float* __restrict__ o_act, const float* __restrict__ W2,
    const float* __restrict__ b2, float* __restrict__ out){
  const int b = blockIdx.x, j = threadIdx.x;
  const float* wr = W2 + (size_t)j * 512;
  const float* xr = o_act + (size_t)b * 512;
  float acc = b2[j];
  for (int c = 0; c < 512; c++) acc = fmaf(wr[c], xr[c], acc);
  out[OUT_XOUT + (size_t)b * 256 + j] = acc;
}

// ---------------- launch ----------------
extern "C" void kernel_launch(void* const* d_in, const int* in_sizes, int n_in,
                              void* d_out, int out_size, void* d_ws, size_t ws_size,
                              hipStream_t stream){
  const float* xyz0    = (const float*)d_in[0];
  const float* feats0  = (const float*)d_in[1];
  const float* xyz1    = (const float*)d_in[2];
  const float* feats1  = (const float*)d_in[3];
  const int*   trace   = (const int*)  d_in[4];
  const float* anchors = (const float*)d_in[5];
  const float* pn0_W  = (const float*)d_in[6];
  const float* pn0_b  = (const float*)d_in[7];
  const float* pn0_g  = (const float*)d_in[8];
  const float* pn0_bb = (const float*)d_in[9];
  const float* pn1_W  = (const float*)d_in[10];
  const float* pn1_b  = (const float*)d_in[11];
  const float* pn1_g  = (const float*)d_in[12];
  const float* pn1_bb = (const float*)d_in[13];
  const float* lin_W  = (const float*)d_in[14];
  const float* lin_b  = (const float*)d_in[15];
  const float* lin_g  = (const float*)d_in[16];
  const float* lin_bb = (const float*)d_in[17];
  const float* feat_W  = (const float*)d_in[18];
  const float* feat_b  = (const float*)d_in[19];
  const float* feat_g  = (const float*)d_in[20];
  const float* feat_bb = (const float*)d_in[21];
  const float* att_W1 = (const float*)d_in[22];
  const float* att_b1 = (const float*)d_in[23];
  const float* att_g  = (const float*)d_in[24];
  const float* att_bb = (const float*)d_in[25];
  const float* att_W2 = (const float*)d_in[26];
  const float* att_b2 = (const float*)d_in[27];
  const float* reg_W1 = (const float*)d_in[28];
  const float* reg_b1 = (const float*)d_in[29];
  const float* reg_g  = (const float*)d_in[30];
  const float* reg_bb = (const float*)d_in[31];
  const float* reg_W2 = (const float*)d_in[32];
  const float* reg_b2 = (const float*)d_in[33];
  const float* out_W1 = (const float*)d_in[34];
  const float* out_b1 = (const float*)d_in[35];
  const float* out_g  = (const float*)d_in[36];
  const float* out_bb = (const float*)d_in[37];
  const float* out_W2 = (const float*)d_in[38];
  const float* out_b2 = (const float*)d_in[39];

  float* ws  = (float*)d_ws;
  float* out = (float*)d_out;
  unsigned short* wb0 = (unsigned short*)(ws + WB0_OFF);
  unsigned short* wb1 = (unsigned short*)(ws + WB1_OFF);
  unsigned short* fw  = (unsigned short*)(ws + FEATW_OFF);
  unsigned short* xg  = (unsigned short*)(ws + XG_OFF);

  // pointnet weight prep
  prep_wb<64> <<<24, 256, 0, stream>>>(pn0_W, wb0);
  prep_wb<128><<<80, 256, 0, stream>>>(pn1_W, wb1);

  // pointnets via MFMA
  pn_mfma<64> <<<dim3(64, 16), 256, 0, stream>>>(xyz0, feats0, wb0, ws + PART0_OFF);
  pn_mfma<128><<<dim3(64, 16), 256, 0, stream>>>(xyz1, feats1, wb1, ws + PART1_OFF);

  // reduce + BN + relu -> concat
  pn_reduce_bn<<<192, 192, 0, stream>>>(ws + PART0_OFF, ws + PART1_OFF,
      pn0_b, pn0_g, pn0_bb, pn1_b, pn1_g, pn1_bb, ws + XCAT_OFF);

  // feat weight hi/lo prep (aliases dead PART region)
  prep_featw<<<6144, 256, 0, stream>>>(feat_W, fw);

  // lin + BN
  lin_bn<<<256, 192, 0, stream>>>(ws + XCAT_OFF, lin_W, lin_b, lin_g, lin_bb, ws + XLIN_OFF);

  // gathered activations hi/lo
  prep_xg<<<1024, 256, 0, stream>>>(ws + XLIN_OFF, trace, xg);

  // feat GEMM via MFMA (4 K-jobs, 2x2 wave tiles, SW-pipelined)
  feat_mfma<<<dim3(16, 8, 4), 256, 0, stream>>>(fw, xg, ws + FRAW_OFF);
  feat_bn<<<512, 960, 0, stream>>>(ws + FRAW_OFF, feat_b, feat_g, feat_bb,
                                   ws + XF_OFF, ws + XM_OFF);

  // reg / att branches: fused GEMM (K split 8) + fused BN
  brgemm2<<<dim3(4, 16, 16), 256, 0, stream>>>(ws + XF_OFF, reg_W1, att_W1, ws + BRP_OFF);
  br_bn<<<dim3(128, 2), 960, 0, stream>>>(ws + BRP_OFF,
      reg_b1, reg_g, reg_bb, att_b1, att_g, att_bb,
      ws + HACT_OFF, ws + AACT_OFF);

  // heads
  reg2_geom<<<16, 64, 0, stream>>>(ws + HACT_OFF, reg_W2, reg_b2, anchors, out);
  att2_softmax<<<16, 64, 0, stream>>>(ws + AACT_OFF, att_W2, att_b2, out);
  out_head1<<<64, 128, 0, stream>>>(ws + XM_OFF, out_W1, out_b1, out_g, out_bb, ws + OACT_OFF);
  out_head2<<<16, 256, 0, stream>>>(ws + OACT_OFF, out_W2, out_b2, out);
}

// Round 6
// 496.687 us; speedup vs baseline: 1.8511x; 1.0490x over previous
//
#include <hip/hip_runtime.h>
#include <math.h>

// ---------------- problem constants ----------------
#define NBATCH 16
#define NPTS   1024
#define NANG   12
#define NROTS  60
#define EPSV   1e-5f

// ---------------- workspace layout (float offsets) ----------------
// lifetime-aliased; peak extent = 6882304 floats = 27.5 MB (< proven 30.3 MB)
#define WB0_OFF   0          // 64*96 bf16 = 3072 floats
#define WB1_OFF   3072       // 128*160 bf16 = 10240 floats (ends 13312)
#define PART0_OFF 13312      // 16*64*12*64  = 786432
#define PART1_OFF 799744     // 16*128*12*64 = 1572864 (ends 2372608)
#define FEATW_OFF 13312      // 512*6144 bf16 = 1572864 floats (aliases dead PART)
#define XF_OFF    13312      // 16*512*60 = 491520 (aliases FEATW after feat_mfma)
#define XM_OFF    504832     // 16*512 = 8192
#define OACT_OFF  513024     // 16*512 = 8192 (ends 521216)
#define XCAT_OFF  2372608    // 16*192*12 = 36864
#define XLIN_OFF  2409472    // 16*256*12 = 49152 (ends 2458624)
#define XG_OFF    2458624    // 960*6144 bf16 = 2949120 floats (ends 5407744)
#define BRP_OFF   2458624    // 16*16*128*60 = 1966080 (aliases XG; XG dead by then)
#define HACT_OFF  4424704    // 16*128*60 = 122880
#define AACT_OFF  4547584    // 16*128*60 = 122880 (ends 4670464)
#define FRAW_OFF  5407744    // 3*512*960 = 1474560 (ends 6882304)

// ---------------- output layout (float offsets) ----------------
#define OUT_XOUT 0       // (16,256)   = 4096
#define OUT_ATTN 4096    // (16,60)    = 960
#define OUT_PRED 5056    // (16,60,3,3)= 8640
#define OUT_REST 13696   // (16,60,3)  = 2880

typedef short  bf16x8 __attribute__((ext_vector_type(8)));
typedef float  f32x4  __attribute__((ext_vector_type(4)));

// fp32 -> bf16 RNE
__device__ __forceinline__ unsigned short f2bf_rne(float x){
  unsigned int u = __float_as_uint(x);
  u += 0x7FFFu + ((u >> 16) & 1u);
  return (unsigned short)(u >> 16);
}
__device__ __forceinline__ float bf2f(unsigned short h){
  return __uint_as_float(((unsigned int)h) << 16);
}

// pack 8 fp32 -> bf16x8 by truncation (one v_perm_b32 per pair)
__device__ __forceinline__ bf16x8 pack8(const float* f){
  union { unsigned int u[4]; bf16x8 v; } r;
  #pragma unroll
  for (int i = 0; i < 4; i++)
    r.u[i] = __builtin_amdgcn_perm(__float_as_uint(f[2*i+1]),
                                   __float_as_uint(f[2*i]), 0x07060302u);
  return r.v;
}

// async global->LDS 16B (lds base must be wave-uniform; HW adds lane*16)
__device__ __forceinline__ void stage16(const unsigned short* g, unsigned short* l){
  __builtin_amdgcn_global_load_lds((const __attribute__((address_space(1))) void*)g,
                                   (__attribute__((address_space(3))) void*)l, 16, 0, 0);
}

// ---------------- block-wide mean/var helper ----------------
template<int NT>
__device__ __forceinline__ void block_stats(float v, float& m, float& var, float* sbuf){
  constexpr int NW = NT / 64;
  float s = v, s2 = v * v;
  #pragma unroll
  for (int off = 32; off; off >>= 1){
    s  += __shfl_xor(s,  off, 64);
    s2 += __shfl_xor(s2, off, 64);
  }
  const int w = threadIdx.x >> 6;
  if ((threadIdx.x & 63) == 0){ sbuf[w] = s; sbuf[NW + w] = s2; }
  __syncthreads();
  float ts = 0.f, ts2 = 0.f;
  #pragma unroll
  for (int i = 0; i < NW; i++){ ts += sbuf[i]; ts2 += sbuf[NW + i]; }
  m = ts / (float)NT;
  var = ts2 / (float)NT - m * m;
}

// ---------------- prep: W (O x C+3) -> Wb (O x KPAD) bf16 ----------------
template<int C>
__global__ void prep_wb(const float* __restrict__ W, unsigned short* __restrict__ Wb){
  constexpr int KPAD = C + 32;
  const int idx = blockIdx.x * 256 + threadIdx.x;
  if (idx >= C * KPAD) return;
  const int o = idx / KPAD, k = idx % KPAD;
  float v = 0.f;
  if (k < C)          v = W[(size_t)o * (C + 3) + 3 + k];
  else if (k < C + 3) v = W[(size_t)o * (C + 3) + (k - C)];
  Wb[idx] = f2bf_rne(v);
}

// ---------------- pointnet GEMM via bf16 MFMA + max over 16 points ----------------
template<int C>
__global__ __launch_bounds__(256) void pn_mfma(
    const float* __restrict__ xyz, const float* __restrict__ feats,
    const unsigned short* __restrict__ Wb, float* __restrict__ part){
  constexpr int KPAD = C + 32;
  constexpr int NK   = KPAD / 32;
  constexpr int MT   = C / 16;
  const int nchunk = blockIdx.x, b = blockIdx.y;
  const int tid  = threadIdx.x;
  const int lane = tid & 63, wave = tid >> 6;
  const int g = lane >> 4, l16 = lane & 15;
  const int colbase = wave * 48;
  const int nbase   = nchunk * 192;

  int nn[3], pp[3];
  #pragma unroll
  for (int t = 0; t < 3; t++){
    nn[t] = nbase + colbase + t * 16 + l16;
    pp[t] = nn[t] / 12;
  }

  f32x4 acc[MT][3];
  #pragma unroll
  for (int m = 0; m < MT; m++)
    #pragma unroll
    for (int t = 0; t < 3; t++)
      acc[m][t] = (f32x4){0.f, 0.f, 0.f, 0.f};

  const float* fB = feats + (size_t)b * C * (NPTS * NANG);

  #pragma unroll
  for (int ks = 0; ks < NK - 1; ks++){
    const int kb = ks * 32;
    bf16x8 Bf[3];
    #pragma unroll
    for (int t = 0; t < 3; t++){
      const float* src = fB + (size_t)(kb + g * 8) * (NPTS * NANG) + nn[t];
      float f[8];
      #pragma unroll
      for (int j = 0; j < 8; j++) f[j] = src[(size_t)j * (NPTS * NANG)];
      Bf[t] = pack8(f);
    }
    #pragma unroll
    for (int m = 0; m < MT; m++){
      const bf16x8 Af = *(const bf16x8*)(Wb + (size_t)(m * 16 + l16) * KPAD + kb + g * 8);
      #pragma unroll
      for (int t = 0; t < 3; t++)
        acc[m][t] = __builtin_amdgcn_mfma_f32_16x16x32_bf16(Af, Bf[t], acc[m][t], 0, 0, 0);
    }
  }

  { // xyz K-step
    const int kb = C;
    bf16x8 Bf[3];
    #pragma unroll
    for (int t = 0; t < 3; t++){
      float f[8];
      #pragma unroll
      for (int j = 0; j < 8; j++) f[j] = 0.f;
      if (g == 0){
        #pragma unroll
        for (int j = 0; j < 3; j++)
          f[j] = xyz[(size_t)(b * 3 + j) * NPTS + pp[t]];
      }
      Bf[t] = pack8(f);
    }
    #pragma unroll
    for (int m = 0; m < MT; m++){
      const bf16x8 Af = *(const bf16x8*)(Wb + (size_t)(m * 16 + l16) * KPAD + kb + g * 8);
      #pragma unroll
      for (int t = 0; t < 3; t++)
        acc[m][t] = __builtin_amdgcn_mfma_f32_16x16x32_bf16(Af, Bf[t], acc[m][t], 0, 0, 0);
    }
  }

  __shared__ float yb[16 * 192];
  #pragma unroll
  for (int m = 0; m < MT; m++){
    __syncthreads();
    #pragma unroll
    for (int t = 0; t < 3; t++)
      #pragma unroll
      for (int r = 0; r < 4; r++)
        yb[(g * 4 + r) * 192 + colbase + t * 16 + l16] = acc[m][t][r];
    __syncthreads();
    if (tid < 192){
      const int o_l = tid / 12, a = tid % 12;
      float mx = -3.4e38f;
      #pragma unroll
      for (int pl = 0; pl < 16; pl++)
        mx = fmaxf(mx, yb[o_l * 192 + pl * 12 + a]);
      part[(((size_t)b * C + m * 16 + o_l) * 12 + a) * 64 + nchunk] = mx;
    }
  }
}

// ---------------- reduce chunks + bias + BN + relu -> xcat (16,192,12) ----------------
__global__ void pn_reduce_bn(const float* __restrict__ part0, const float* __restrict__ part1,
    const float* __restrict__ b0, const float* __restrict__ g0, const float* __restrict__ bb0,
    const float* __restrict__ b1, const float* __restrict__ g1, const float* __restrict__ bb1,
    float* __restrict__ xcat){
  const int ch = blockIdx.x, t = threadIdx.x;
  const int b = t / 12, a = t % 12;
  const float* part; const float *bias, *g, *bb; int o, Cl;
  if (ch < 64){ part = part0; bias = b0; g = g0; bb = bb0; o = ch;      Cl = 64;  }
  else        { part = part1; bias = b1; g = g1; bb = bb1; o = ch - 64; Cl = 128; }
  const float* pp = part + (((size_t)b * Cl + o) * 12 + a) * 64;
  float v = pp[0];
  for (int k = 1; k < 64; k++) v = fmaxf(v, pp[k]);
  v += bias[o];
  __shared__ float sbuf[8];
  float m, var;
  block_stats<192>(v, m, var, sbuf);
  float xn = (v - m) * rsqrtf(var + EPSV) * g[o] + bb[o];
  xcat[((size_t)b * 192 + ch) * 12 + a] = fmaxf(xn, 0.f);
}

// ---------------- lin layer + BN (no relu) -> xlin (16,256,12) ----------------
__global__ void lin_bn(const float* __restrict__ xcat, const float* __restrict__ W,
    const float* __restrict__ bias, const float* __restrict__ g, const float* __restrict__ bb,
    float* __restrict__ xlin){
  const int o = blockIdx.x, t = threadIdx.x;
  const int b = t / 12, a = t % 12;
  const float* xr = xcat + (size_t)b * 2304 + a;
  const float* wr = W + (size_t)o * 192;
  float v = bias[o];
  for (int c = 0; c < 192; c++) v = fmaf(wr[c], xr[(size_t)c * 12], v);
  __shared__ float sbuf[8];
  float m, var;
  block_stats<192>(v, m, var, sbuf);
  xlin[((size_t)b * 256 + o) * 12 + a] = (v - m) * rsqrtf(var + EPSV) * g[o] + bb[o];
}

// ---------------- prep: feat_W fp32 (512x3072) -> [hi | lo] bf16 (512x6144) ----------------
__global__ void prep_featw(const float* __restrict__ W, unsigned short* __restrict__ Wb2){
  const int idx = blockIdx.x * 256 + threadIdx.x;   // 512*3072
  if (idx >= 512 * 3072) return;
  const int o = idx / 3072, k = idx % 3072;
  const float x = W[idx];
  const unsigned short hi = f2bf_rne(x);
  const unsigned short lo = f2bf_rne(x - bf2f(hi));
  Wb2[(size_t)o * 6144 + k] = hi;
  Wb2[(size_t)o * 6144 + 3072 + k] = lo;
}

// ---------------- prep: gathered activations Xg [n=960][hi(3072) | lo(3072)] bf16 ----------------
// n = b*60 + r. Xg[n][c*12+a] = xlin[b][c][trace[a][r]]
__global__ void prep_xg(const float* __restrict__ xlin, const int* __restrict__ trace,
                        unsigned short* __restrict__ Xg){
  const int n = blockIdx.x;           // 0..959
  const int b = n / 60, r = n % 60;
  unsigned short* row = Xg + (size_t)n * 6144;
  __shared__ int ta[12];
  if (threadIdx.x < 12) ta[threadIdx.x] = trace[threadIdx.x * 60 + r];
  __syncthreads();
  for (int i = threadIdx.x; i < 3072; i += 256){
    const int c = i / 12, a = i % 12;
    const float x = xlin[((size_t)b * 256 + c) * 12 + ta[a]];
    const unsigned short hi = f2bf_rne(x);
    const unsigned short lo = f2bf_rne(x - bf2f(hi));
    row[i] = hi;
    row[3072 + i] = lo;
  }
}

// ---------------- feat GEMM: LDS-staged MFMA (m97 pattern), XOR-swizzled chunks ----------------
// One GEMM: C[512,960] = W x Xg^T, 3 hi/lo segments (K=3072 each).
// grid (nblk=15, mblk=8, seg=3); block 256 = 4 waves, wave = 32x32 (2x2 MFMA tiles).
// BK=64 double-buffered (32 KB LDS), global_load_lds width-16.
// LDS chunk swizzle: chunk c16s holds global chunk c16s ^ (row&7) -> ds_read_b128
// fragment reads land 2 lanes/bank (free) instead of 16-way conflicts.
__global__ __launch_bounds__(256) void feat_mfma(
    const unsigned short* __restrict__ Wb2, const unsigned short* __restrict__ Xg,
    float* __restrict__ fraw){
  const int nblk = blockIdx.x, mblk = blockIdx.y, seg = blockIdx.z;
  const int tid = threadIdx.x;
  const int lane = tid & 63, wave = tid >> 6;
  const int g = lane >> 4, l16 = lane & 15;
  const int kA = (seg == 1) ? 3072 : 0;
  const int kB = (seg == 2) ? 3072 : 0;
  const int sw = l16 & 7;
  const int wm = wave >> 1, wn = wave & 1;

  __shared__ unsigned short As[2][64 * 64];
  __shared__ unsigned short Bs[2][64 * 64];

  // staging geometry: 512 chunks of 16B per tile; thread handles 2 per tile
  int rowj[2], colj[2], ldsoff[2];
  #pragma unroll
  for (int j = 0; j < 2; j++){
    const int idx = j * 256 + wave * 64 + lane;
    rowj[j]   = idx >> 3;
    colj[j]   = ((idx & 7) ^ (rowj[j] & 7)) * 8;   // swizzled global col (elements)
    ldsoff[j] = (j * 256 + wave * 64) * 8;         // wave-uniform LDS base (elements)
  }
  const unsigned short* Agb = Wb2 + (size_t)mblk * 64 * 6144 + kA;
  const unsigned short* Bgb = Xg  + (size_t)nblk * 64 * 6144 + kB;

  f32x4 acc[2][2];
  #pragma unroll
  for (int i = 0; i < 2; i++)
    #pragma unroll
    for (int j = 0; j < 2; j++)
      acc[i][j] = (f32x4){0.f, 0.f, 0.f, 0.f};

  // preload kc=0 into buf 0
  #pragma unroll
  for (int j = 0; j < 2; j++){
    stage16(Agb + (size_t)rowj[j] * 6144 + colj[j], &As[0][ldsoff[j]]);
    stage16(Bgb + (size_t)rowj[j] * 6144 + colj[j], &Bs[0][ldsoff[j]]);
  }
  __syncthreads();

  for (int kc = 0; kc < 3072; kc += 64){
    const int buf = (kc >> 6) & 1;
    if (kc + 64 < 3072){
      const int kn = kc + 64;
      #pragma unroll
      for (int j = 0; j < 2; j++){
        stage16(Agb + (size_t)rowj[j] * 6144 + kn + colj[j], &As[buf ^ 1][ldsoff[j]]);
        stage16(Bgb + (size_t)rowj[j] * 6144 + kn + colj[j], &Bs[buf ^ 1][ldsoff[j]]);
      }
    }
    #pragma unroll
    for (int kc2 = 0; kc2 < 64; kc2 += 32){
      const int c0 = kc2 >> 3;                     // chunk base (0 or 4)
      bf16x8 af[2], bfr[2];
      #pragma unroll
      for (int i = 0; i < 2; i++)
        af[i]  = *(const bf16x8*)&As[buf][(wm * 32 + i * 16 + l16) * 64 + ((c0 + g) ^ sw) * 8];
      #pragma unroll
      for (int i = 0; i < 2; i++)
        bfr[i] = *(const bf16x8*)&Bs[buf][(wn * 32 + i * 16 + l16) * 64 + ((c0 + g) ^ sw) * 8];
      #pragma unroll
      for (int i = 0; i < 2; i++)
        #pragma unroll
        for (int j = 0; j < 2; j++)
          acc[i][j] = __builtin_amdgcn_mfma_f32_16x16x32_bf16(af[i], bfr[j], acc[i][j], 0, 0, 0);
    }
    __syncthreads();   // compiler drains vmcnt before barrier -> buf^1 staged; buf reads done
  }

  float* base = fraw + (size_t)seg * (512 * 960);
  #pragma unroll
  for (int i = 0; i < 2; i++)
    #pragma unroll
    for (int j = 0; j < 2; j++){
      const int n = nblk * 64 + wn * 32 + j * 16 + l16;
      #pragma unroll
      for (int q = 0; q < 4; q++){
        const int m = mblk * 64 + wm * 32 + i * 16 + g * 4 + q;
        base[(size_t)m * 960 + n] = acc[i][j][q];
      }
    }
}

// ---------------- feat: sum 3 segs + bias + BN + relu + per-b max over r ----------------
// grid 512 (o), block 960 (t = n = b*60+r)
__global__ void feat_bn(const float* __restrict__ fraw, const float* __restrict__ bias,
    const float* __restrict__ g, const float* __restrict__ bb,
    float* __restrict__ xf, float* __restrict__ xm){
  const int o = blockIdx.x, t = threadIdx.x;
  const int b = t / 60, r = t % 60;
  const size_t SS = (size_t)512 * 960;
  const size_t in = (size_t)o * 960 + t;
  float v = fraw[in] + fraw[SS + in] + fraw[2 * SS + in] + bias[o];
  __shared__ float sbuf[32];
  float m, var;
  block_stats<960>(v, m, var, sbuf);
  const float xn = fmaxf((v - m) * rsqrtf(var + EPSV) * g[o] + bb[o], 0.f);
  xf[((size_t)b * 512 + o) * 60 + r] = xn;
  __shared__ float red[960];
  red[t] = xn;
  __syncthreads();
  if (r == 0){
    float mx = red[t];
    for (int k = 1; k < 60; k++) mx = fmaxf(mx, red[t + k]);
    xm[(size_t)b * 512 + o] = mx;
  }
}

// ---------------- branch GEMMs fused (reg_W1 & att_W1), K split 8 ----------------
__global__ __launch_bounds__(256) void brgemm2(const float* __restrict__ xf,
    const float* __restrict__ Wr, const float* __restrict__ Wa,
    float* __restrict__ brp){
  const int og = blockIdx.x, b = blockIdx.y, z = blockIdx.z;
  const int br = z >> 3, ks = z & 7;
  const float* W = br ? Wa : Wr;
  const int lane = threadIdx.x & 63, wave = threadIdx.x >> 6;
  const int obase = og * 32 + wave * 8;
  const int rr = lane < 60 ? lane : 0;
  const float* xb = xf + ((size_t)b * 512 + ks * 64) * 60 + rr;
  const float* wr = W + (size_t)obase * 512 + ks * 64;

  float acc[8];
  #pragma unroll
  for (int i = 0; i < 8; i++) acc[i] = 0.f;

  float cur[4], nxt[4];
  #pragma unroll
  for (int j = 0; j < 4; j++) cur[j] = xb[(size_t)j * 60];

  for (int c0 = 0; c0 < 64; c0 += 4){
    #pragma unroll
    for (int j = 0; j < 4; j++){
      int cc = c0 + 4 + j; if (cc > 63) cc = 63;
      nxt[j] = xb[(size_t)cc * 60];
    }
    #pragma unroll
    for (int j = 0; j < 4; j++)
      #pragma unroll
      for (int i = 0; i < 8; i++)
        acc[i] = fmaf(wr[(size_t)i * 512 + c0 + j], cur[j], acc[i]);
    #pragma unroll
    for (int j = 0; j < 4; j++) cur[j] = nxt[j];
  }

  if (lane < 60){
    #pragma unroll
    for (int i = 0; i < 8; i++)
      brp[(((size_t)z * NBATCH + b) * 128 + obase + i) * 60 + lane] = acc[i];
  }
}

// ---------------- branch: sum 8 K-slabs + bias + BN + relu ----------------
__global__ void br_bn(const float* __restrict__ brp,
    const float* __restrict__ biasR, const float* __restrict__ gR, const float* __restrict__ bbR,
    const float* __restrict__ biasA, const float* __restrict__ gA, const float* __restrict__ bbA,
    float* __restrict__ hact, float* __restrict__ aact){
  const int o = blockIdx.x, br = blockIdx.y, t = threadIdx.x;
  const int b = t / 60, r = t % 60;
  const float* bias = br ? biasA : biasR;
  const float* g    = br ? gA    : gR;
  const float* bb   = br ? bbA   : bbR;
  float v = bias[o];
  #pragma unroll
  for (int ks = 0; ks < 8; ks++)
    v += brp[((((size_t)br * 8 + ks) * NBATCH + b) * 128 + o) * 60 + r];
  __shared__ float sbuf[32];
  float m, var;
  block_stats<960>(v, m, var, sbuf);
  float* outp = br ? aact : hact;
  outp[((size_t)b * 128 + o) * 60 + r] =
      fmaxf((v - m) * rsqrtf(var + EPSV) * g[o] + bb[o], 0.f);
}

// ---------------- reg head ----------------
__global__ void reg2_geom(const float* __restrict__ h, const float* __restrict__ W2,
    const float* __restrict__ b2, const float* __restrict__ anchors, float* __restrict__ out){
  const int b = blockIdx.x, lane = threadIdx.x;
  const int r = lane < 60 ? lane : 59;
  float res[7];
  #pragma unroll
  for (int j = 0; j < 7; j++){
    float acc = b2[j];
    for (int c = 0; c < 128; c++)
      acc = fmaf(W2[j * 128 + c], h[((size_t)b * 128 + c) * 60 + r], acc);
    res[j] = acc;
  }
  if (lane >= 60) return;
  const float n = sqrtf(res[0]*res[0] + res[1]*res[1] + res[2]*res[2]);
  const float invn = 1.f / n;
  const float Nv = (1.f / (1.f + expf(-res[3])) - 0.5f) * 3.14159265358979323846f / 5.f;
  const float v0 = res[0]*invn*Nv, v1 = res[1]*invn*Nv, v2 = res[2]*invn*Nv;
  const float th = sqrtf(v0*v0 + v1*v1 + v2*v2);
  const float invt = th < 1e-8f ? 1.f : 1.f / th;
  const float k0 = v0*invt, k1 = v1*invt, k2 = v2*invt;
  const float s = sinf(th), cc = 1.f - cosf(th);
  const float K[9] = {0.f, -k2, k1,  k2, 0.f, -k0,  -k1, k0, 0.f};
  float K2[9];
  #pragma unroll
  for (int ii = 0; ii < 3; ii++)
    #pragma unroll
    for (int jj = 0; jj < 3; jj++)
      K2[ii*3+jj] = K[ii*3+0]*K[0*3+jj] + K[ii*3+1]*K[1*3+jj] + K[ii*3+2]*K[2*3+jj];
  float R[9];
  #pragma unroll
  for (int ii = 0; ii < 3; ii++)
    #pragma unroll
    for (int jj = 0; jj < 3; jj++)
      R[ii*3+jj] = (ii == jj ? 1.f : 0.f) + s * K[ii*3+jj] + cc * K2[ii*3+jj];
  const float* A = anchors + (size_t)r * 9;
  #pragma unroll
  for (int ii = 0; ii < 3; ii++)
    #pragma unroll
    for (int kk = 0; kk < 3; kk++){
      const float pv = A[ii*3+0]*R[0*3+kk] + A[ii*3+1]*R[1*3+kk] + A[ii*3+2]*R[2*3+kk];
      out[OUT_PRED + ((size_t)b * 60 + r) * 9 + ii * 3 + kk] = pv;
    }
  #pragma unroll
  for (int k = 0; k < 3; k++)
    out[OUT_REST + ((size_t)b * 60 + r) * 3 + k] = res[4 + k];
}

// ---------------- att head ----------------
__global__ void att2_softmax(const float* __restrict__ a, const float* __restrict__ W2,
    const float* __restrict__ b2, float* __restrict__ out){
  const int b = blockIdx.x, lane = threadIdx.x;
  const int r = lane < 60 ? lane : 59;
  float acc = b2[0];
  for (int c = 0; c < 128; c++)
    acc = fmaf(W2[c], a[((size_t)b * 128 + c) * 60 + r], acc);
  const float l = lane < 60 ? acc : -INFINITY;
  float mx = l;
  #pragma unroll
  for (int off = 32; off; off >>= 1) mx = fmaxf(mx, __shfl_xor(mx, off, 64));
  const float e = lane < 60 ? expf(l - mx) : 0.f;
  float ssum = e;
  #pragma unroll
  for (int off = 32; off; off >>= 1) ssum += __shfl_xor(ssum, off, 64);
  if (lane < 60) out[OUT_ATTN + (size_t)b * 60 + lane] = e / ssum;
}

// ---------------- out head 1 ----------------
__global__ void out_head1(const float* __restrict__ xm, const float* __restrict__ W1,
    const float* __restrict__ b1, const float* __restrict__ g, const float* __restrict__ bb,
    float* __restrict__ o_act){
  const int t = threadIdx.x;
  const int b = t & 15, j = t >> 4;
  const int oc = blockIdx.x * 8 + j;
  float acc = b1[oc];
  const float* wr = W1 + (size_t)oc * 512;
  const float* xr = xm + (size_t)b * 512;
  for (int c = 0; c < 512; c++) acc = fmaf(wr[c], xr[c], acc);
  float s = acc, s2 = acc * acc;
  #pragma unroll
  for (int off = 8; off; off >>= 1){
    s  += __shfl_xor(s,  off, 16);
    s2 += __shfl_xor(s2, off, 16);
  }
  const float m = s * (1.f / 16.f);
  const float var = s2 * (1.f / 16.f) - m * m;
  o_act[(size_t)b * 512 + oc] = fmaxf((acc - m) * rsqrtf(var + EPSV) * g[oc] + bb[oc], 0.f);
}

// ---------------- out head 2 ----------------
__global__ void out_head2(const float* __restrict__ o_act, const float* __restrict__ W2,
    const float* __restrict__ b2, float* __restrict__ out){
  const int b = blockIdx.x, j = threadIdx.x;
  const float* wr = W2 + (size_t)j * 512;
  const float* xr = o_act + (size_t)b * 512;
  float acc = b2[j];
  for (int c = 0; c < 512; c++) acc = fmaf(wr[c], xr[c], acc);
  out[OUT_XOUT + (size_t)b * 256 + j] = acc;
}

// ---------------- launch ----------------
extern "C" void kernel_launch(void* const* d_in, const int* in_sizes, int n_in,
                              void* d_out, int out_size, void* d_ws, size_t ws_size,
                              hipStream_t stream){
  const float* xyz0    = (const float*)d_in[0];
  const float* feats0  = (const float*)d_in[1];
  const float* xyz1    = (const float*)d_in[2];
  const float* feats1  = (const float*)d_in[3];
  const int*   trace   = (const int*)  d_in[4];
  const float* anchors = (const float*)d_in[5];
  const float* pn0_W  = (const float*)d_in[6];
  const float* pn0_b  = (const float*)d_in[7];
  const float* pn0_g  = (const float*)d_in[8];
  const float* pn0_bb = (const float*)d_in[9];
  const float* pn1_W  = (const float*)d_in[10];
  const float* pn1_b  = (const float*)d_in[11];
  const float* pn1_g  = (const float*)d_in[12];
  const float* pn1_bb = (const float*)d_in[13];
  const float* lin_W  = (const float*)d_in[14];
  const float* lin_b  = (const float*)d_in[15];
  const float* lin_g  = (const float*)d_in[16];
  const float* lin_bb = (const float*)d_in[17];
  const float* feat_W  = (const float*)d_in[18];
  const float* feat_b  = (const float*)d_in[19];
  const float* feat_g  = (const float*)d_in[20];
  const float* feat_bb = (const float*)d_in[21];
  const float* att_W1 = (const float*)d_in[22];
  const float* att_b1 = (const float*)d_in[23];
  const float* att_g  = (const float*)d_in[24];
  const float* att_bb = (const float*)d_in[25];
  const float* att_W2 = (const float*)d_in[26];
  const float* att_b2 = (const float*)d_in[27];
  const float* reg_W1 = (const float*)d_in[28];
  const float* reg_b1 = (const float*)d_in[29];
  const float* reg_g  = (const float*)d_in[30];
  const float* reg_bb = (const float*)d_in[31];
  const float* reg_W2 = (const float*)d_in[32];
  const float* reg_b2 = (const float*)d_in[33];
  const float* out_W1 = (const float*)d_in[34];
  const float* out_b1 = (const float*)d_in[35];
  const float* out_g  = (const float*)d_in[36];
  const float* out_bb = (const float*)d_in[37];
  const float* out_W2 = (const float*)d_in[38];
  const float* out_b2 = (const float*)d_in[39];

  float* ws  = (float*)d_ws;
  float* out = (float*)d_out;
  unsigned short* wb0 = (unsigned short*)(ws + WB0_OFF);
  unsigned short* wb1 = (unsigned short*)(ws + WB1_OFF);
  unsigned short* fw  = (unsigned short*)(ws + FEATW_OFF);
  unsigned short* xg  = (unsigned short*)(ws + XG_OFF);

  // pointnet weight prep
  prep_wb<64> <<<24, 256, 0, stream>>>(pn0_W, wb0);
  prep_wb<128><<<80, 256, 0, stream>>>(pn1_W, wb1);

  // pointnets via MFMA
  pn_mfma<64> <<<dim3(64, 16), 256, 0, stream>>>(xyz0, feats0, wb0, ws + PART0_OFF);
  pn_mfma<128><<<dim3(64, 16), 256, 0, stream>>>(xyz1, feats1, wb1, ws + PART1_OFF);

  // reduce + BN + relu -> concat
  pn_reduce_bn<<<192, 192, 0, stream>>>(ws + PART0_OFF, ws + PART1_OFF,
      pn0_b, pn0_g, pn0_bb, pn1_b, pn1_g, pn1_bb, ws + XCAT_OFF);

  // feat weight hi/lo prep (aliases dead PART region)
  prep_featw<<<6144, 256, 0, stream>>>(feat_W, fw);

  // lin + BN
  lin_bn<<<256, 192, 0, stream>>>(ws + XCAT_OFF, lin_W, lin_b, lin_g, lin_bb, ws + XLIN_OFF);

  // gathered activations hi/lo (N=960, no padding)
  prep_xg<<<960, 256, 0, stream>>>(ws + XLIN_OFF, trace, xg);

  // feat GEMM via LDS-staged MFMA (3 segments)
  feat_mfma<<<dim3(15, 8, 3), 256, 0, stream>>>(fw, xg, ws + FRAW_OFF);
  feat_bn<<<512, 960, 0, stream>>>(ws + FRAW_OFF, feat_b, feat_g, feat_bb,
                                   ws + XF_OFF, ws + XM_OFF);

  // reg / att branches: fused GEMM (K split 8) + fused BN
  brgemm2<<<dim3(4, 16, 16), 256, 0, stream>>>(ws + XF_OFF, reg_W1, att_W1, ws + BRP_OFF);
  br_bn<<<dim3(128, 2), 960, 0, stream>>>(ws + BRP_OFF,
      reg_b1, reg_g, reg_bb, att_b1, att_g, att_bb,
      ws + HACT_OFF, ws + AACT_OFF);

  // heads
  reg2_geom<<<16, 64, 0, stream>>>(ws + HACT_OFF, reg_W2, reg_b2, anchors, out);
  att2_softmax<<<16, 64, 0, stream>>>(ws + AACT_OFF, att_W2, att_b2, out);
  out_head1<<<64, 128, 0, stream>>>(ws + XM_OFF, out_W1, out_b1, out_g, out_bb, ws + OACT_OFF);
  out_head2<<<16, 256, 0, stream>>>(ws + OACT_OFF, out_W2, out_b2, out);
}

// Round 7
// 480.688 us; speedup vs baseline: 1.9127x; 1.0333x over previous
//
#include <hip/hip_runtime.h>
#include <math.h>

// ---------------- problem constants ----------------
#define NBATCH 16
#define NPTS   1024
#define NANG   12
#define NROTS  60
#define EPSV   1e-5f

// ---------------- workspace layout (float offsets) ----------------
// lifetime-aliased; peak extent = 6882304 floats = 27.5 MB
#define WB0_OFF   0          // 64*96 bf16 = 3072 floats
#define WB1_OFF   3072       // 128*160 bf16 = 10240 floats (ends 13312)
#define PART0_OFF 13312      // 16*64*64*12  = 786432
#define PART1_OFF 799744     // 16*64*128*12 = 1572864 (ends 2372608)
#define FEATW_OFF 13312      // 512*6144 bf16 = 1572864 floats (aliases dead PART)
#define XF_OFF    13312      // 16*512*60 = 491520 (aliases FEATW after feat_mfma)
#define XM_OFF    504832     // 16*512 = 8192
#define OACT_OFF  513024     // 16*512 = 8192 (ends 521216)
#define XCAT_OFF  2372608    // 16*192*12 = 36864
#define XLIN_OFF  2409472    // 16*256*12 = 49152 (ends 2458624)
#define XG_OFF    2458624    // 960*6144 bf16 = 2949120 floats (ends 5407744)
#define BRP_OFF   2458624    // 16*16*128*60 = 1966080 (aliases XG; XG dead by then)
#define HACT_OFF  4424704    // 16*128*60 = 122880
#define AACT_OFF  4547584    // 16*128*60 = 122880 (ends 4670464)
#define FRAW_OFF  5407744    // 3*512*960 = 1474560 (ends 6882304)

// ---------------- output layout (float offsets) ----------------
#define OUT_XOUT 0       // (16,256)   = 4096
#define OUT_ATTN 4096    // (16,60)    = 960
#define OUT_PRED 5056    // (16,60,3,3)= 8640
#define OUT_REST 13696   // (16,60,3)  = 2880

typedef short  bf16x8 __attribute__((ext_vector_type(8)));
typedef float  f32x4  __attribute__((ext_vector_type(4)));

// fp32 -> bf16 RNE
__device__ __forceinline__ unsigned short f2bf_rne(float x){
  unsigned int u = __float_as_uint(x);
  u += 0x7FFFu + ((u >> 16) & 1u);
  return (unsigned short)(u >> 16);
}
__device__ __forceinline__ float bf2f(unsigned short h){
  return __uint_as_float(((unsigned int)h) << 16);
}

// pack 8 fp32 -> bf16x8 by truncation (one v_perm_b32 per pair)
__device__ __forceinline__ bf16x8 pack8(const float* f){
  union { unsigned int u[4]; bf16x8 v; } r;
  #pragma unroll
  for (int i = 0; i < 4; i++)
    r.u[i] = __builtin_amdgcn_perm(__float_as_uint(f[2*i+1]),
                                   __float_as_uint(f[2*i]), 0x07060302u);
  return r.v;
}

// async global->LDS 16B (lds base must be wave-uniform; HW adds lane*16)
__device__ __forceinline__ void stage16(const unsigned short* g, unsigned short* l){
  __builtin_amdgcn_global_load_lds((const __attribute__((address_space(1))) void*)g,
                                   (__attribute__((address_space(3))) void*)l, 16, 0, 0);
}

// ---------------- block-wide mean/var helper ----------------
template<int NT>
__device__ __forceinline__ void block_stats(float v, float& m, float& var, float* sbuf){
  constexpr int NW = NT / 64;
  float s = v, s2 = v * v;
  #pragma unroll
  for (int off = 32; off; off >>= 1){
    s  += __shfl_xor(s,  off, 64);
    s2 += __shfl_xor(s2, off, 64);
  }
  const int w = threadIdx.x >> 6;
  if ((threadIdx.x & 63) == 0){ sbuf[w] = s; sbuf[NW + w] = s2; }
  __syncthreads();
  float ts = 0.f, ts2 = 0.f;
  #pragma unroll
  for (int i = 0; i < NW; i++){ ts += sbuf[i]; ts2 += sbuf[NW + i]; }
  m = ts / (float)NT;
  var = ts2 / (float)NT - m * m;
}

// ---------------- prep: W (O x C+3) -> Wb (O x KPAD) bf16 ----------------
template<int C>
__global__ void prep_wb(const float* __restrict__ W, unsigned short* __restrict__ Wb){
  constexpr int KPAD = C + 32;
  const int idx = blockIdx.x * 256 + threadIdx.x;
  if (idx >= C * KPAD) return;
  const int o = idx / KPAD, k = idx % KPAD;
  float v = 0.f;
  if (k < C)          v = W[(size_t)o * (C + 3) + 3 + k];
  else if (k < C + 3) v = W[(size_t)o * (C + 3) + (k - C)];
  Wb[idx] = f2bf_rne(v);
}

// ---------------- pointnet GEMM via bf16 MFMA, LDS-staged B, + max over 16 points ----------
// grid (nchunk=64, b=16), block 256 = 4 waves. Per block: all C outputs x 192 n
// (16 points x 12 angles). B tile (32 k x 192 n fp32) double-buffered in LDS.
// LDS row slot sigma(r) = (r&7)*4 + (r>>3), stride 196 (16B-aligned, ==4 mod 32):
// fragment reads (rows 4 apart across g after sigma) spread banks -> ~2-way (free).
// part layout: [b][nchunk][o][a] -> contiguous 768B stores per m-tile.
template<int C>
__global__ __launch_bounds__(256) void pn_mfma(
    const float* __restrict__ xyz, const float* __restrict__ feats,
    const unsigned short* __restrict__ Wb, float* __restrict__ part){
  constexpr int KPAD = C + 32;
  constexpr int NFK  = C / 32;      // staged feats K-steps
  constexpr int MT   = C / 16;      // m-tiles
  constexpr int SROW = 196;         // LDS row stride (floats)
  const int nchunk = blockIdx.x, b = blockIdx.y;
  const int tid  = threadIdx.x;
  const int lane = tid & 63, wave = tid >> 6;
  const int g = lane >> 4, l16 = lane & 15;
  const int colbase = wave * 48;
  const int nbase   = nchunk * 192;

  __shared__ float Bs[2][32 * SROW];   // 2 x 25.1 KB

  int nn[3], pp[3];
  #pragma unroll
  for (int t = 0; t < 3; t++){
    nn[t] = colbase + t * 16 + l16;          // local n in [0,192)
    pp[t] = (nbase + nn[t]) / 12;            // global point index
  }

  f32x4 acc[MT][3];
  #pragma unroll
  for (int m = 0; m < MT; m++)
    #pragma unroll
    for (int t = 0; t < 3; t++)
      acc[m][t] = (f32x4){0.f, 0.f, 0.f, 0.f};

  const float* fB = feats + (size_t)b * C * (NPTS * NANG) + nbase;

  // staging geometry: 32 rows x 48 float4 chunks = 1536; 6 per thread
  int srow[6], scol[6], sslot[6];
  #pragma unroll
  for (int jj = 0; jj < 6; jj++){
    const int idx = tid + 256 * jj;
    srow[jj]  = idx / 48;
    scol[jj]  = (idx % 48) * 4;
    sslot[jj] = (srow[jj] & 7) * 4 + (srow[jj] >> 3);
  }

  // prologue: stage ks=0 into buf 0
  {
    float4 v[6];
    #pragma unroll
    for (int jj = 0; jj < 6; jj++)
      v[jj] = *(const float4*)(fB + (size_t)srow[jj] * (NPTS * NANG) + scol[jj]);
    #pragma unroll
    for (int jj = 0; jj < 6; jj++)
      *(float4*)(&Bs[0][sslot[jj] * SROW + scol[jj]]) = v[jj];
  }
  __syncthreads();

  #pragma unroll
  for (int ks = 0; ks < NFK; ks++){
    const int buf = ks & 1;
    float4 v[6];
    if (ks + 1 < NFK){
      const int kb = (ks + 1) * 32;
      #pragma unroll
      for (int jj = 0; jj < 6; jj++)
        v[jj] = *(const float4*)(fB + (size_t)(kb + srow[jj]) * (NPTS * NANG) + scol[jj]);
    }
    // compute on buf (k = ks*32 .. +31)
    const int kb = ks * 32;
    bf16x8 Bf[3];
    #pragma unroll
    for (int t = 0; t < 3; t++){
      float f[8];
      #pragma unroll
      for (int j = 0; j < 8; j++)
        f[j] = Bs[buf][(j * 4 + g) * SROW + nn[t]];   // slot(g*8+j) = j*4+g
      Bf[t] = pack8(f);
    }
    #pragma unroll
    for (int m = 0; m < MT; m++){
      const bf16x8 Af = *(const bf16x8*)(Wb + (size_t)(m * 16 + l16) * KPAD + kb + g * 8);
      #pragma unroll
      for (int t = 0; t < 3; t++)
        acc[m][t] = __builtin_amdgcn_mfma_f32_16x16x32_bf16(Af, Bf[t], acc[m][t], 0, 0, 0);
    }
    if (ks + 1 < NFK){
      #pragma unroll
      for (int jj = 0; jj < 6; jj++)
        *(float4*)(&Bs[buf ^ 1][sslot[jj] * SROW + scol[jj]]) = v[jj];
    }
    __syncthreads();
  }

  { // xyz K-step (k = C..C+2 non-zero), register B
    const int kb = C;
    bf16x8 Bf[3];
    #pragma unroll
    for (int t = 0; t < 3; t++){
      float f[8];
      #pragma unroll
      for (int j = 0; j < 8; j++) f[j] = 0.f;
      if (g == 0){
        #pragma unroll
        for (int j = 0; j < 3; j++)
          f[j] = xyz[(size_t)(b * 3 + j) * NPTS + pp[t]];
      }
      Bf[t] = pack8(f);
    }
    #pragma unroll
    for (int m = 0; m < MT; m++){
      const bf16x8 Af = *(const bf16x8*)(Wb + (size_t)(m * 16 + l16) * KPAD + kb + g * 8);
      #pragma unroll
      for (int t = 0; t < 3; t++)
        acc[m][t] = __builtin_amdgcn_mfma_f32_16x16x32_bf16(Af, Bf[t], acc[m][t], 0, 0, 0);
    }
  }

  // reduce: per m-tile, stage 16 o x 192 n in LDS (alias Bs[0]), max over 16 points
  float* yb = &Bs[0][0];   // 16*196 = 3136 floats <= 6272
  #pragma unroll
  for (int m = 0; m < MT; m++){
    __syncthreads();
    #pragma unroll
    for (int t = 0; t < 3; t++)
      #pragma unroll
      for (int r = 0; r < 4; r++)
        yb[(g * 4 + r) * SROW + nn[t]] = acc[m][t][r];
    __syncthreads();
    if (tid < 192){
      const int o_l = tid / 12, a = tid % 12;
      float mx = -3.4e38f;
      #pragma unroll
      for (int pl = 0; pl < 16; pl++)
        mx = fmaxf(mx, yb[o_l * SROW + pl * 12 + a]);
      // part[b][nchunk][m*16+o_l][a]  (contiguous: base + m*192 + tid)
      part[((size_t)(b * 64 + nchunk) * C + m * 16 + o_l) * 12 + a] = mx;
    }
  }
}

// ---------------- reduce chunks + bias + BN + relu -> xcat (16,192,12) ----------------
// part layout: [b][k=64][o][a]
__global__ void pn_reduce_bn(const float* __restrict__ part0, const float* __restrict__ part1,
    const float* __restrict__ b0, const float* __restrict__ g0, const float* __restrict__ bb0,
    const float* __restrict__ b1, const float* __restrict__ g1, const float* __restrict__ bb1,
    float* __restrict__ xcat){
  const int ch = blockIdx.x, t = threadIdx.x;
  const int b = t / 12, a = t % 12;
  const float* part; const float *bias, *g, *bb; int o, Cl;
  if (ch < 64){ part = part0; bias = b0; g = g0; bb = bb0; o = ch;      Cl = 64;  }
  else        { part = part1; bias = b1; g = g1; bb = bb1; o = ch - 64; Cl = 128; }
  const float* pp = part + ((size_t)(b * 64) * Cl + o) * 12 + a;
  const size_t kstride = (size_t)Cl * 12;
  float v = pp[0];
  for (int k = 1; k < 64; k++) v = fmaxf(v, pp[(size_t)k * kstride]);
  v += bias[o];
  __shared__ float sbuf[8];
  float m, var;
  block_stats<192>(v, m, var, sbuf);
  float xn = (v - m) * rsqrtf(var + EPSV) * g[o] + bb[o];
  xcat[((size_t)b * 192 + ch) * 12 + a] = fmaxf(xn, 0.f);
}

// ---------------- lin layer + BN (no relu) -> xlin (16,256,12) ----------------
__global__ void lin_bn(const float* __restrict__ xcat, const float* __restrict__ W,
    const float* __restrict__ bias, const float* __restrict__ g, const float* __restrict__ bb,
    float* __restrict__ xlin){
  const int o = blockIdx.x, t = threadIdx.x;
  const int b = t / 12, a = t % 12;
  const float* xr = xcat + (size_t)b * 2304 + a;
  const float* wr = W + (size_t)o * 192;
  float v = bias[o];
  for (int c = 0; c < 192; c++) v = fmaf(wr[c], xr[(size_t)c * 12], v);
  __shared__ float sbuf[8];
  float m, var;
  block_stats<192>(v, m, var, sbuf);
  xlin[((size_t)b * 256 + o) * 12 + a] = (v - m) * rsqrtf(var + EPSV) * g[o] + bb[o];
}

// ---------------- prep: feat_W fp32 (512x3072) -> [hi | lo] bf16 (512x6144) ----------------
__global__ void prep_featw(const float* __restrict__ W, unsigned short* __restrict__ Wb2){
  const int idx = blockIdx.x * 256 + threadIdx.x;   // 512*3072
  if (idx >= 512 * 3072) return;
  const int o = idx / 3072, k = idx % 3072;
  const float x = W[idx];
  const unsigned short hi = f2bf_rne(x);
  const unsigned short lo = f2bf_rne(x - bf2f(hi));
  Wb2[(size_t)o * 6144 + k] = hi;
  Wb2[(size_t)o * 6144 + 3072 + k] = lo;
}

// ---------------- prep: gathered activations Xg [n=960][hi(3072) | lo(3072)] bf16 ----------------
// n = b*60 + r. Xg[n][c*12+a] = xlin[b][c][trace[a][r]]
__global__ void prep_xg(const float* __restrict__ xlin, const int* __restrict__ trace,
                        unsigned short* __restrict__ Xg){
  const int n = blockIdx.x;           // 0..959
  const int b = n / 60, r = n % 60;
  unsigned short* row = Xg + (size_t)n * 6144;
  __shared__ int ta[12];
  if (threadIdx.x < 12) ta[threadIdx.x] = trace[threadIdx.x * 60 + r];
  __syncthreads();
  for (int i = threadIdx.x; i < 3072; i += 256){
    const int c = i / 12, a = i % 12;
    const float x = xlin[((size_t)b * 256 + c) * 12 + ta[a]];
    const unsigned short hi = f2bf_rne(x);
    const unsigned short lo = f2bf_rne(x - bf2f(hi));
    row[i] = hi;
    row[3072 + i] = lo;
  }
}

// ---------------- feat GEMM: LDS-staged MFMA (m97 pattern), XOR-swizzled chunks ----------------
// C[512,960] = W x Xg^T, 3 hi/lo segments (K=3072 each).
// grid (nblk=15, mblk=8, seg=3); block 256 = 4 waves, wave = 32x32 (2x2 MFMA tiles).
__global__ __launch_bounds__(256) void feat_mfma(
    const unsigned short* __restrict__ Wb2, const unsigned short* __restrict__ Xg,
    float* __restrict__ fraw){
  const int nblk = blockIdx.x, mblk = blockIdx.y, seg = blockIdx.z;
  const int tid = threadIdx.x;
  const int lane = tid & 63, wave = tid >> 6;
  const int g = lane >> 4, l16 = lane & 15;
  const int kA = (seg == 1) ? 3072 : 0;
  const int kB = (seg == 2) ? 3072 : 0;
  const int sw = l16 & 7;
  const int wm = wave >> 1, wn = wave & 1;

  __shared__ unsigned short As[2][64 * 64];
  __shared__ unsigned short Bs[2][64 * 64];

  int rowj[2], colj[2], ldsoff[2];
  #pragma unroll
  for (int j = 0; j < 2; j++){
    const int idx = j * 256 + wave * 64 + lane;
    rowj[j]   = idx >> 3;
    colj[j]   = ((idx & 7) ^ (rowj[j] & 7)) * 8;
    ldsoff[j] = (j * 256 + wave * 64) * 8;
  }
  const unsigned short* Agb = Wb2 + (size_t)mblk * 64 * 6144 + kA;
  const unsigned short* Bgb = Xg  + (size_t)nblk * 64 * 6144 + kB;

  f32x4 acc[2][2];
  #pragma unroll
  for (int i = 0; i < 2; i++)
    #pragma unroll
    for (int j = 0; j < 2; j++)
      acc[i][j] = (f32x4){0.f, 0.f, 0.f, 0.f};

  #pragma unroll
  for (int j = 0; j < 2; j++){
    stage16(Agb + (size_t)rowj[j] * 6144 + colj[j], &As[0][ldsoff[j]]);
    stage16(Bgb + (size_t)rowj[j] * 6144 + colj[j], &Bs[0][ldsoff[j]]);
  }
  __syncthreads();

  for (int kc = 0; kc < 3072; kc += 64){
    const int buf = (kc >> 6) & 1;
    if (kc + 64 < 3072){
      const int kn = kc + 64;
      #pragma unroll
      for (int j = 0; j < 2; j++){
        stage16(Agb + (size_t)rowj[j] * 6144 + kn + colj[j], &As[buf ^ 1][ldsoff[j]]);
        stage16(Bgb + (size_t)rowj[j] * 6144 + kn + colj[j], &Bs[buf ^ 1][ldsoff[j]]);
      }
    }
    #pragma unroll
    for (int kc2 = 0; kc2 < 64; kc2 += 32){
      const int c0 = kc2 >> 3;
      bf16x8 af[2], bfr[2];
      #pragma unroll
      for (int i = 0; i < 2; i++)
        af[i]  = *(const bf16x8*)&As[buf][(wm * 32 + i * 16 + l16) * 64 + ((c0 + g) ^ sw) * 8];
      #pragma unroll
      for (int i = 0; i < 2; i++)
        bfr[i] = *(const bf16x8*)&Bs[buf][(wn * 32 + i * 16 + l16) * 64 + ((c0 + g) ^ sw) * 8];
      #pragma unroll
      for (int i = 0; i < 2; i++)
        #pragma unroll
        for (int j = 0; j < 2; j++)
          acc[i][j] = __builtin_amdgcn_mfma_f32_16x16x32_bf16(af[i], bfr[j], acc[i][j], 0, 0, 0);
    }
    __syncthreads();
  }

  float* base = fraw + (size_t)seg * (512 * 960);
  #pragma unroll
  for (int i = 0; i < 2; i++)
    #pragma unroll
    for (int j = 0; j < 2; j++){
      const int n = nblk * 64 + wn * 32 + j * 16 + l16;
      #pragma unroll
      for (int q = 0; q < 4; q++){
        const int m = mblk * 64 + wm * 32 + i * 16 + g * 4 + q;
        base[(size_t)m * 960 + n] = acc[i][j][q];
      }
    }
}

// ---------------- feat: sum 3 segs + bias + BN + relu + per-b max over r ----------------
__global__ void feat_bn(const float* __restrict__ fraw, const float* __restrict__ bias,
    const float* __restrict__ g, const float* __restrict__ bb,
    float* __restrict__ xf, float* __restrict__ xm){
  const int o = blockIdx.x, t = threadIdx.x;
  const int b = t / 60, r = t % 60;
  const size_t SS = (size_t)512 * 960;
  const size_t in = (size_t)o * 960 + t;
  float v = fraw[in] + fraw[SS + in] + fraw[2 * SS + in] + bias[o];
  __shared__ float sbuf[32];
  float m, var;
  block_stats<960>(v, m, var, sbuf);
  const float xn = fmaxf((v - m) * rsqrtf(var + EPSV) * g[o] + bb[o], 0.f);
  xf[((size_t)b * 512 + o) * 60 + r] = xn;
  __shared__ float red[960];
  red[t] = xn;
  __syncthreads();
  if (r == 0){
    float mx = red[t];
    for (int k = 1; k < 60; k++) mx = fmaxf(mx, red[t + k]);
    xm[(size_t)b * 512 + o] = mx;
  }
}

// ---------------- branch GEMMs fused (reg_W1 & att_W1), K split 8 ----------------
__global__ __launch_bounds__(256) void brgemm2(const float* __restrict__ xf,
    const float* __restrict__ Wr, const float* __restrict__ Wa,
    float* __restrict__ brp){
  const int og = blockIdx.x, b = blockIdx.y, z = blockIdx.z;
  const int br = z >> 3, ks = z & 7;
  const float* W = br ? Wa : Wr;
  const int lane = threadIdx.x & 63, wave = threadIdx.x >> 6;
  const int obase = og * 32 + wave * 8;
  const int rr = lane < 60 ? lane : 0;
  const float* xb = xf + ((size_t)b * 512 + ks * 64) * 60 + rr;
  const float* wr = W + (size_t)obase * 512 + ks * 64;

  float acc[8];
  #pragma unroll
  for (int i = 0; i < 8; i++) acc[i] = 0.f;

  float cur[4], nxt[4];
  #pragma unroll
  for (int j = 0; j < 4; j++) cur[j] = xb[(size_t)j * 60];

  for (int c0 = 0; c0 < 64; c0 += 4){
    #pragma unroll
    for (int j = 0; j < 4; j++){
      int cc = c0 + 4 + j; if (cc > 63) cc = 63;
      nxt[j] = xb[(size_t)cc * 60];
    }
    #pragma unroll
    for (int j = 0; j < 4; j++)
      #pragma unroll
      for (int i = 0; i < 8; i++)
        acc[i] = fmaf(wr[(size_t)i * 512 + c0 + j], cur[j], acc[i]);
    #pragma unroll
    for (int j = 0; j < 4; j++) cur[j] = nxt[j];
  }

  if (lane < 60){
    #pragma unroll
    for (int i = 0; i < 8; i++)
      brp[(((size_t)z * NBATCH + b) * 128 + obase + i) * 60 + lane] = acc[i];
  }
}

// ---------------- branch: sum 8 K-slabs + bias + BN + relu ----------------
__global__ void br_bn(const float* __restrict__ brp,
    const float* __restrict__ biasR, const float* __restrict__ gR, const float* __restrict__ bbR,
    const float* __restrict__ biasA, const float* __restrict__ gA, const float* __restrict__ bbA,
    float* __restrict__ hact, float* __restrict__ aact){
  const int o = blockIdx.x, br = blockIdx.y, t = threadIdx.x;
  const int b = t / 60, r = t % 60;
  const float* bias = br ? biasA : biasR;
  const float* g    = br ? gA    : gR;
  const float* bb   = br ? bbA   : bbR;
  float v = bias[o];
  #pragma unroll
  for (int ks = 0; ks < 8; ks++)
    v += brp[((((size_t)br * 8 + ks) * NBATCH + b) * 128 + o) * 60 + r];
  __shared__ float sbuf[32];
  float m, var;
  block_stats<960>(v, m, var, sbuf);
  float* outp = br ? aact : hact;
  outp[((size_t)b * 128 + o) * 60 + r] =
      fmaxf((v - m) * rsqrtf(var + EPSV) * g[o] + bb[o], 0.f);
}

// ---------------- reg head ----------------
__global__ void reg2_geom(const float* __restrict__ h, const float* __restrict__ W2,
    const float* __restrict__ b2, const float* __restrict__ anchors, float* __restrict__ out){
  const int b = blockIdx.x, lane = threadIdx.x;
  const int r = lane < 60 ? lane : 59;
  float res[7];
  #pragma unroll
  for (int j = 0; j < 7; j++){
    float acc = b2[j];
    for (int c = 0; c < 128; c++)
      acc = fmaf(W2[j * 128 + c], h[((size_t)b * 128 + c) * 60 + r], acc);
    res[j] = acc;
  }
  if (lane >= 60) return;
  const float n = sqrtf(res[0]*res[0] + res[1]*res[1] + res[2]*res[2]);
  const float invn = 1.f / n;
  const float Nv = (1.f / (1.f + expf(-res[3])) - 0.5f) * 3.14159265358979323846f / 5.f;
  const float v0 = res[0]*invn*Nv, v1 = res[1]*invn*Nv, v2 = res[2]*invn*Nv;
  const float th = sqrtf(v0*v0 + v1*v1 + v2*v2);
  const float invt = th < 1e-8f ? 1.f : 1.f / th;
  const float k0 = v0*invt, k1 = v1*invt, k2 = v2*invt;
  const float s = sinf(th), cc = 1.f - cosf(th);
  const float K[9] = {0.f, -k2, k1,  k2, 0.f, -k0,  -k1, k0, 0.f};
  float K2[9];
  #pragma unroll
  for (int ii = 0; ii < 3; ii++)
    #pragma unroll
    for (int jj = 0; jj < 3; jj++)
      K2[ii*3+jj] = K[ii*3+0]*K[0*3+jj] + K[ii*3+1]*K[1*3+jj] + K[ii*3+2]*K[2*3+jj];
  float R[9];
  #pragma unroll
  for (int ii = 0; ii < 3; ii++)
    #pragma unroll
    for (int jj = 0; jj < 3; jj++)
      R[ii*3+jj] = (ii == jj ? 1.f : 0.f) + s * K[ii*3+jj] + cc * K2[ii*3+jj];
  const float* A = anchors + (size_t)r * 9;
  #pragma unroll
  for (int ii = 0; ii < 3; ii++)
    #pragma unroll
    for (int kk = 0; kk < 3; kk++){
      const float pv = A[ii*3+0]*R[0*3+kk] + A[ii*3+1]*R[1*3+kk] + A[ii*3+2]*R[2*3+kk];
      out[OUT_PRED + ((size_t)b * 60 + r) * 9 + ii * 3 + kk] = pv;
    }
  #pragma unroll
  for (int k = 0; k < 3; k++)
    out[OUT_REST + ((size_t)b * 60 + r) * 3 + k] = res[4 + k];
}

// ---------------- att head ----------------
__global__ void att2_softmax(const float* __restrict__ a, const float* __restrict__ W2,
    const float* __restrict__ b2, float* __restrict__ out){
  const int b = blockIdx.x, lane = threadIdx.x;
  const int r = lane < 60 ? lane : 59;
  float acc = b2[0];
  for (int c = 0; c < 128; c++)
    acc = fmaf(W2[c], a[((size_t)b * 128 + c) * 60 + r], acc);
  const float l = lane < 60 ? acc : -INFINITY;
  float mx = l;
  #pragma unroll
  for (int off = 32; off; off >>= 1) mx = fmaxf(mx, __shfl_xor(mx, off, 64));
  const float e = lane < 60 ? expf(l - mx) : 0.f;
  float ssum = e;
  #pragma unroll
  for (int off = 32; off; off >>= 1) ssum += __shfl_xor(ssum, off, 64);
  if (lane < 60) out[OUT_ATTN + (size_t)b * 60 + lane] = e / ssum;
}

// ---------------- out head 1 ----------------
__global__ void out_head1(const float* __restrict__ xm, const float* __restrict__ W1,
    const float* __restrict__ b1, const float* __restrict__ g, const float* __restrict__ bb,
    float* __restrict__ o_act){
  const int t = threadIdx.x;
  const int b = t & 15, j = t >> 4;
  const int oc = blockIdx.x * 8 + j;
  float acc = b1[oc];
  const float* wr = W1 + (size_t)oc * 512;
  const float* xr = xm + (size_t)b * 512;
  for (int c = 0; c < 512; c++) acc = fmaf(wr[c], xr[c], acc);
  float s = acc, s2 = acc * acc;
  #pragma unroll
  for (int off = 8; off; off >>= 1){
    s  += __shfl_xor(s,  off, 16);
    s2 += __shfl_xor(s2, off, 16);
  }
  const float m = s * (1.f / 16.f);
  const float var = s2 * (1.f / 16.f) - m * m;
  o_act[(size_t)b * 512 + oc] = fmaxf((acc - m) * rsqrtf(var + EPSV) * g[oc] + bb[oc], 0.f);
}

// ---------------- out head 2 ----------------
__global__ void out_head2(const float* __restrict__ o_act, const float* __restrict__ W2,
    const float* __restrict__ b2, float* __restrict__ out){
  const int b = blockIdx.x, j = threadIdx.x;
  const float* wr = W2 + (size_t)j * 512;
  const float* xr = o_act + (size_t)b * 512;
  float acc = b2[j];
  for (int c = 0; c < 512; c++) acc = fmaf(wr[c], xr[c], acc);
  out[OUT_XOUT + (size_t)b * 256 + j] = acc;
}

// ---------------- launch ----------------
extern "C" void kernel_launch(void* const* d_in, const int* in_sizes, int n_in,
                              void* d_out, int out_size, void* d_ws, size_t ws_size,
                              hipStream_t stream){
  const float* xyz0    = (const float*)d_in[0];
  const float* feats0  = (const float*)d_in[1];
  const float* xyz1    = (const float*)d_in[2];
  const float* feats1  = (const float*)d_in[3];
  const int*   trace   = (const int*)  d_in[4];
  const float* anchors = (const float*)d_in[5];
  const float* pn0_W  = (const float*)d_in[6];
  const float* pn0_b  = (const float*)d_in[7];
  const float* pn0_g  = (const float*)d_in[8];
  const float* pn0_bb = (const float*)d_in[9];
  const float* pn1_W  = (const float*)d_in[10];
  const float* pn1_b  = (const float*)d_in[11];
  const float* pn1_g  = (const float*)d_in[12];
  const float* pn1_bb = (const float*)d_in[13];
  const float* lin_W  = (const float*)d_in[14];
  const float* lin_b  = (const float*)d_in[15];
  const float* lin_g  = (const float*)d_in[16];
  const float* lin_bb = (const float*)d_in[17];
  const float* feat_W  = (const float*)d_in[18];
  const float* feat_b  = (const float*)d_in[19];
  const float* feat_g  = (const float*)d_in[20];
  const float* feat_bb = (const float*)d_in[21];
  const float* att_W1 = (const float*)d_in[22];
  const float* att_b1 = (const float*)d_in[23];
  const float* att_g  = (const float*)d_in[24];
  const float* att_bb = (const float*)d_in[25];
  const float* att_W2 = (const float*)d_in[26];
  const float* att_b2 = (const float*)d_in[27];
  const float* reg_W1 = (const float*)d_in[28];
  const float* reg_b1 = (const float*)d_in[29];
  const float* reg_g  = (const float*)d_in[30];
  const float* reg_bb = (const float*)d_in[31];
  const float* reg_W2 = (const float*)d_in[32];
  const float* reg_b2 = (const float*)d_in[33];
  const float* out_W1 = (const float*)d_in[34];
  const float* out_b1 = (const float*)d_in[35];
  const float* out_g  = (const float*)d_in[36];
  const float* out_bb = (const float*)d_in[37];
  const float* out_W2 = (const float*)d_in[38];
  const float* out_b2 = (const float*)d_in[39];

  float* ws  = (float*)d_ws;
  float* out = (float*)d_out;
  unsigned short* wb0 = (unsigned short*)(ws + WB0_OFF);
  unsigned short* wb1 = (unsigned short*)(ws + WB1_OFF);
  unsigned short* fw  = (unsigned short*)(ws + FEATW_OFF);
  unsigned short* xg  = (unsigned short*)(ws + XG_OFF);

  // pointnet weight prep
  prep_wb<64> <<<24, 256, 0, stream>>>(pn0_W, wb0);
  prep_wb<128><<<80, 256, 0, stream>>>(pn1_W, wb1);

  // pointnets via MFMA (LDS-staged B, coalesced part writes)
  pn_mfma<64> <<<dim3(64, 16), 256, 0, stream>>>(xyz0, feats0, wb0, ws + PART0_OFF);
  pn_mfma<128><<<dim3(64, 16), 256, 0, stream>>>(xyz1, feats1, wb1, ws + PART1_OFF);

  // reduce + BN + relu -> concat
  pn_reduce_bn<<<192, 192, 0, stream>>>(ws + PART0_OFF, ws + PART1_OFF,
      pn0_b, pn0_g, pn0_bb, pn1_b, pn1_g, pn1_bb, ws + XCAT_OFF);

  // feat weight hi/lo prep (aliases dead PART region)
  prep_featw<<<6144, 256, 0, stream>>>(feat_W, fw);

  // lin + BN
  lin_bn<<<256, 192, 0, stream>>>(ws + XCAT_OFF, lin_W, lin_b, lin_g, lin_bb, ws + XLIN_OFF);

  // gathered activations hi/lo (N=960, no padding)
  prep_xg<<<960, 256, 0, stream>>>(ws + XLIN_OFF, trace, xg);

  // feat GEMM via LDS-staged MFMA (3 segments)
  feat_mfma<<<dim3(15, 8, 3), 256, 0, stream>>>(fw, xg, ws + FRAW_OFF);
  feat_bn<<<512, 960, 0, stream>>>(ws + FRAW_OFF, feat_b, feat_g, feat_bb,
                                   ws + XF_OFF, ws + XM_OFF);

  // reg / att branches: fused GEMM (K split 8) + fused BN
  brgemm2<<<dim3(4, 16, 16), 256, 0, stream>>>(ws + XF_OFF, reg_W1, att_W1, ws + BRP_OFF);
  br_bn<<<dim3(128, 2), 960, 0, stream>>>(ws + BRP_OFF,
      reg_b1, reg_g, reg_bb, att_b1, att_g, att_bb,
      ws + HACT_OFF, ws + AACT_OFF);

  // heads
  reg2_geom<<<16, 64, 0, stream>>>(ws + HACT_OFF, reg_W2, reg_b2, anchors, out);
  att2_softmax<<<16, 64, 0, stream>>>(ws + AACT_OFF, att_W2, att_b2, out);
  out_head1<<<64, 128, 0, stream>>>(ws + XM_OFF, out_W1, out_b1, out_g, out_bb, ws + OACT_OFF);
  out_head2<<<16, 256, 0, stream>>>(ws + OACT_OFF, out_W2, out_b2, out);
}